// Round 3
// baseline (559.769 us; speedup 1.0000x reference)
//
#include <hip/hip_runtime.h>
#include <hip/hip_bf16.h>

#define N_NODES 30000
#define N_REL   8
#define N_EDGES 131072
#define FEAT    512
#define KTOT    4608   // 8*512 + 512
#define CAP     32

typedef __attribute__((ext_vector_type(8))) __bf16 v8bf;
typedef __attribute__((ext_vector_type(4))) __bf16 v4bf;
typedef __attribute__((ext_vector_type(4))) float  v4f;
typedef __attribute__((ext_vector_type(4))) int    v4i;
typedef __attribute__((ext_vector_type(8))) unsigned short u16x8;

// ---------- async global->LDS (16B per lane, wave-uniform LDS base) ----------
static __device__ __forceinline__ void load_lds16(const void* g, void* l) {
  __builtin_amdgcn_global_load_lds(
      (const __attribute__((address_space(1))) void*)g,
      (__attribute__((address_space(3))) void*)l, 16, 0, 0);
}

// ---------- fused prep: convert x, transpose W, build buckets ----------
// Streams with no reuse carry nt hints so they don't evict the reuse set
// (xbf, Wt, slots) from L2/Infinity Cache.
#define CONV_BLOCKS 15000
#define TR_BLOCKS   2304
#define CNT_BLOCKS  512
__global__ __launch_bounds__(256)
void k_prep(const float* __restrict__ x, const float* __restrict__ w,
            const float* __restrict__ lw, const int* __restrict__ src,
            const int* __restrict__ dst, __bf16* __restrict__ xbf,
            __bf16* __restrict__ Wt, int* __restrict__ cnt,
            unsigned short* __restrict__ slots) {
  __shared__ float t[32][33];
  const int b = blockIdx.x, tid = threadIdx.x;
  if (b < CONV_BLOCKS) {
    int i = b * 256 + tid;                          // 4 elems each
    v4f v = __builtin_nontemporal_load((const v4f*)x + i);   // read-once stream
    v4bf o;
    o[0] = (__bf16)v[0]; o[1] = (__bf16)v[1]; o[2] = (__bf16)v[2]; o[3] = (__bf16)v[3];
    ((v4bf*)xbf)[i] = o;                            // cached: aggregate re-reads
  } else if (b < CONV_BLOCKS + TR_BLOCKS) {
    int tb = b - CONV_BLOCKS;
    int k0 = (tb % 144) * 32, n0 = (tb / 144) * 32;
    int tx = tid & 31, ty = tid >> 5;               // 32 x 8
    #pragma unroll
    for (int q = 0; q < 4; ++q) {
      int k = k0 + ty + q * 8, n = n0 + tx;
      float v = (k < 4096) ? __builtin_nontemporal_load(w + (size_t)k * 512 + n)
                           : __builtin_nontemporal_load(lw + (size_t)(k - 4096) * 512 + n);
      t[ty + q * 8][tx] = v;
    }
    __syncthreads();
    #pragma unroll
    for (int q = 0; q < 4; ++q) {
      int n = n0 + ty + q * 8, k = k0 + tx;
      Wt[(size_t)n * KTOT + k] = (__bf16)t[tx][ty + q * 8];  // cached: GEMM reads
    }
  } else {
    int cb  = b - CONV_BLOCKS - TR_BLOCKS;          // 0..511
    int rel = cb & 7;                               // XCD-affine rel
    int q   = cb >> 3;                              // 0..63 within rel
    int e0  = rel * N_EDGES + (q * 256 + tid) * 8;  // 8 edges, same rel
    v4i sa = __builtin_nontemporal_load((const v4i*)(src + e0));
    v4i sb = __builtin_nontemporal_load((const v4i*)(src + e0 + 4));
    v4i da = __builtin_nontemporal_load((const v4i*)(dst + e0));
    v4i db = __builtin_nontemporal_load((const v4i*)(dst + e0 + 4));
    int ss[8] = {sa[0], sa[1], sa[2], sa[3], sb[0], sb[1], sb[2], sb[3]};
    int dd[8] = {da[0], da[1], da[2], da[3], db[0], db[1], db[2], db[3]};
    int bb[8], pp[8];
    #pragma unroll
    for (int j = 0; j < 8; ++j) {
      bb[j] = rel * N_NODES + dd[j];
      pp[j] = atomicAdd(&cnt[bb[j]], 1);
    }
    #pragma unroll
    for (int j = 0; j < 8; ++j)
      if (pp[j] < CAP) slots[(size_t)bb[j] * CAP + pp[j]] = (unsigned short)ss[j];
  }
}

// ---------- aggregation: one wave/bucket ----------
// nt on the two pure streams (slot lines in, slab rows out) so the 30.7 MB
// x-slab stays resident in Infinity Cache for the random gathers.
__global__ __launch_bounds__(256)
void k_aggregate(const __bf16* __restrict__ xbf, const int* __restrict__ cnt,
                 const unsigned short* __restrict__ slots,
                 __bf16* __restrict__ out, int nBuckets) {
  int w = (blockIdx.x * blockDim.x + threadIdx.x) >> 6;
  int lane = threadIdx.x & 63;
  if (w >= nBuckets) return;
  const unsigned short* sl = slots + (size_t)w * CAP;
  u16x8 qs[4];                                      // one 64B line, issued up front
  qs[0] = __builtin_nontemporal_load((const u16x8*)(sl));
  qs[1] = __builtin_nontemporal_load((const u16x8*)(sl + 8));
  qs[2] = __builtin_nontemporal_load((const u16x8*)(sl + 16));
  qs[3] = __builtin_nontemporal_load((const u16x8*)(sl + 24));
  int c = cnt[w];
  int cc = c < CAP ? c : CAP;
  const __bf16* xb = xbf + (size_t)lane * 8;
  float acc[8] = {0.f,0.f,0.f,0.f,0.f,0.f,0.f,0.f};
  #pragma unroll
  for (int g = 0; g < 4; ++g) {
    if (cc > g * 8) {                               // wave-uniform branch
      int m = cc - g * 8;
      v8bf r[8];
      #pragma unroll
      for (int j = 0; j < 8; ++j)
        if (m > j) r[j] = *(const v8bf*)(xb + (size_t)qs[g][j] * FEAT);  // cached gather
      #pragma unroll
      for (int j = 0; j < 8; ++j)
        if (m > j) {
          #pragma unroll
          for (int t = 0; t < 8; ++t) acc[t] += (float)r[j][t];
        }
    }
  }
  float scale = 1.0f / (float)(c > 1 ? c : 1);
  v8bf o;
  #pragma unroll
  for (int t = 0; t < 8; ++t) o[t] = (__bf16)(acc[t] * scale);
  __builtin_nontemporal_store(o, (v8bf*)(out + (size_t)w * FEAT + lane * 8));
}

// ---------- GEMM: 128x128 tile, mfma 16x16x32 bf16, XOR-swizzled LDS ----------
// XCD-affine block map: the 4 ntile-siblings sharing an A-panel have
// blockIdx ≡ (mod 8) -> same XCD L2. LDS-staged fp32 epilogue, full-line
// float4 stores (nt when the output is never re-read).
template <bool ACCUM, bool FINAL>
__global__ __launch_bounds__(256, 4)
void k_gemm(const __bf16* __restrict__ A, size_t slabStride,
            const __bf16* __restrict__ Wt, int wtStride, int kTiles,
            const float* __restrict__ bias, float* __restrict__ C,
            int mtBase, int mtEnd) {
  __shared__ __align__(16) char smem[32768];
  __bf16* As = (__bf16*)smem;                  // 128x64 bf16 = 16 KB
  __bf16* Bs = (__bf16*)(smem + 16384);        // 128x64 bf16 = 16 KB

  const int tid  = threadIdx.x;
  const int wave = tid >> 6;
  const int lane = tid & 63;
  const int lr = lane >> 3, lc = lane & 7;     // staging: row-in-chunk, 16B slot
  const int gcs = (lc ^ lr) * 8;               // swizzled global chunk (elem offset)
  const int quad = lane >> 4, l15 = lane & 15; // mfma lane decomposition
  const int wRow = wave >> 1, wCol = wave & 1;

  const int panel = blockIdx.x >> 5;
  const int w32   = blockIdx.x & 31;
  const int mtile = mtBase + panel * 8 + (w32 & 7);
  const int ntile = w32 >> 3;
  if (mtile >= mtEnd) return;                  // uniform whole-block exit
  const int mBase = mtile * 128;
  const int nBase = ntile * 128;

  v4f acc[4][4];
  #pragma unroll
  for (int i = 0; i < 4; ++i)
    #pragma unroll
    for (int j = 0; j < 4; ++j) acc[i][j] = (v4f){0.f, 0.f, 0.f, 0.f};

  for (int kt = 0; kt < kTiles; ++kt) {
    const int kk = kt * 64;
    const __bf16* aT = A + (size_t)(kk >> 9) * slabStride + (kk & 511);
    #pragma unroll
    for (int t = 0; t < 4; ++t) {
      int chunk = wave * 4 + t;                 // 8 rows x 64 cols per chunk
      int row = mBase + chunk * 8 + lr;
      if (row > N_NODES - 1) row = N_NODES - 1; // clamp; masked at store
      load_lds16(aT + (size_t)row * FEAT + gcs, As + chunk * 512);
      int n = nBase + chunk * 8 + lr;
      load_lds16(Wt + (size_t)n * wtStride + kk + gcs, Bs + chunk * 512);
    }
    __syncthreads();
    #pragma unroll
    for (int ks = 0; ks < 2; ++ks) {
      const int q = ks * 4 + quad;              // 16B chunk wanted this phase
      v8bf af[4], bfr[4];
      #pragma unroll
      for (int mi = 0; mi < 4; ++mi) {
        int m = wRow * 64 + mi * 16 + l15;
        af[mi] = *(const v8bf*)(As + m * 64 + ((q ^ (m & 7)) * 8));
      }
      #pragma unroll
      for (int ni = 0; ni < 4; ++ni) {
        int n = wCol * 64 + ni * 16 + l15;
        bfr[ni] = *(const v8bf*)(Bs + n * 64 + ((q ^ (n & 7)) * 8));
      }
      #pragma unroll
      for (int mi = 0; mi < 4; ++mi)
        #pragma unroll
        for (int ni = 0; ni < 4; ++ni)
          acc[mi][ni] = __builtin_amdgcn_mfma_f32_16x16x32_bf16(af[mi], bfr[ni], acc[mi][ni], 0, 0, 0);
    }
    __syncthreads();
  }

  // ---- LDS-staged fp32 epilogue: two 64-row halves, full-line stores ----
  float* cbuf = (float*)smem;                  // 64 x 128 fp32 = 32 KB
  const int f4c  = tid & 31;                   // float4 column within the tile
  const int colg = nBase + f4c * 4;
  v4f bias4 = (v4f){0.f, 0.f, 0.f, 0.f};
  if (FINAL) bias4 = *(const v4f*)(bias + colg);
  #pragma unroll
  for (int h = 0; h < 2; ++h) {
    if (wRow == h) {                           // 2 waves own this 64-row half
      #pragma unroll
      for (int mi = 0; mi < 4; ++mi) {
        int r0 = mi * 16 + quad * 4;           // row within half
        #pragma unroll
        for (int ni = 0; ni < 4; ++ni) {
          int c = wCol * 64 + ni * 16 + l15;
          #pragma unroll
          for (int e = 0; e < 4; ++e)
            cbuf[(r0 + e) * 128 + c] = acc[mi][ni][e];
        }
      }
    }
    __syncthreads();
    #pragma unroll
    for (int i = 0; i < 8; ++i) {
      int rh  = (tid >> 5) + 8 * i;            // 8 rows per instruction, all waves
      int row = mBase + h * 64 + rh;
      if (row < N_NODES) {
        v4f v = *(const v4f*)(cbuf + rh * 128 + f4c * 4);
        size_t idx = (size_t)row * FEAT + colg;
        if (ACCUM) {
          v4f c0 = *(const v4f*)(C + idx);
          v += c0;
        }
        if (FINAL) {
          #pragma unroll
          for (int e = 0; e < 4; ++e) v[e] = fmaxf(v[e] + bias4[e], 0.f);
        }
        if (FINAL && !ACCUM)
          __builtin_nontemporal_store(v, (v4f*)(C + idx));   // never re-read
        else
          *(v4f*)(C + idx) = v;
      }
    }
    __syncthreads();
  }
}

extern "C" void kernel_launch(void* const* d_in, const int* in_sizes, int n_in,
                              void* d_out, int out_size, void* d_ws, size_t ws_size,
                              hipStream_t stream) {
  const float* x    = (const float*)d_in[0];
  const float* w    = (const float*)d_in[1];
  const float* lw   = (const float*)d_in[2];
  const float* bias = (const float*)d_in[3];
  const int*   src  = (const int*)d_in[4];
  const int*   dst  = (const int*)d_in[5];
  float* out = (float*)d_out;

  char* ws = (char*)d_ws;
  const size_t SLAB  = (size_t)N_NODES * FEAT;              // elems per slab
  const size_t slabB = SLAB * 2;                            // 30.72 MB
  const size_t wtB   = (size_t)FEAT * KTOT * 2;             // 4.72 MB
  const size_t cntB  = (size_t)N_REL * N_NODES * 4;         // 0.96 MB
  const size_t slotB = (size_t)N_REL * N_NODES * CAP * 2;   // 15.36 MB (u16)
  const size_t fixedB = wtB + cntB + slotB;                 // 21.04 MB

  __bf16*         Wt     = (__bf16*)ws;
  int*            cnt    = (int*)(ws + wtB);
  unsigned short* slots  = (unsigned short*)(ws + wtB + cntB);
  __bf16*         slabs  = (__bf16*)(ws + fixedB);          // 16B-aligned

  int nSlab = (int)((ws_size - fixedB) / slabB);            // total slots incl. x slot
  if (nSlab > 9) nSlab = 9;
  int g = nSlab - 1;                                        // agg slabs per GEMM pass
  if (g > 8) g = 8;
  if (g < 1) g = 1;
  __bf16* xbf = slabs + (size_t)g * SLAB;                   // last slot = x (bf16)

  hipMemsetAsync(cnt, 0, cntB, stream);
  k_prep<<<CONV_BLOCKS + TR_BLOCKS + CNT_BLOCKS, 256, 0, stream>>>(
      x, w, lw, src, dst, xbf, Wt, cnt, slots);

  const int nMtiles = (N_NODES + 127) / 128;                // 235

  if (g == 8) {
    // fused problem: agg slabs 0..7 + x at slot 8 -> K=4608, one aggregate
    // dispatch (240000 buckets), one GEMM dispatch (960 blocks).
    const int nB = N_REL * N_NODES;
    k_aggregate<<<nB / 4, 256, 0, stream>>>(xbf, cnt, slots, slabs, nB);
    const int grid = ((nMtiles + 7) / 8) * 32;              // 30 panels
    k_gemm<false, true><<<grid, 256, 0, stream>>>(slabs, SLAB, Wt, KTOT,
                                                  KTOT / 64, bias, out, 0, nMtiles);
  } else {
    const int gemmGrid = ((nMtiles + 7) / 8) * 32;
    for (int r0 = 0; r0 < N_REL; r0 += g) {
      int gc2 = (N_REL - r0) < g ? (N_REL - r0) : g;
      k_aggregate<<<(gc2 * N_NODES) / 4, 256, 0, stream>>>(
          xbf, cnt + r0 * N_NODES, slots + (size_t)r0 * N_NODES * CAP,
          slabs, gc2 * N_NODES);
      if (r0 == 0)
        k_gemm<false, false><<<gemmGrid, 256, 0, stream>>>(
            slabs, SLAB, Wt + r0 * 512, KTOT, gc2 * 8, bias, out, 0, nMtiles);
      else
        k_gemm<true, false><<<gemmGrid, 256, 0, stream>>>(
            slabs, SLAB, Wt + r0 * 512, KTOT, gc2 * 8, bias, out, 0, nMtiles);
    }
    k_gemm<true, true><<<gemmGrid, 256, 0, stream>>>(xbf, SLAB, Wt + 4096, KTOT,
                                                     8, bias, out, 0, nMtiles);
  }
}

// Round 4
// 546.065 us; speedup vs baseline: 1.0251x; 1.0251x over previous
//
#include <hip/hip_runtime.h>
#include <hip/hip_bf16.h>

#define N_NODES 30000
#define N_REL   8
#define N_EDGES 131072
#define FEAT    512
#define KTOT    4608   // 8*512 + 512
#define CAP     32

typedef __attribute__((ext_vector_type(8))) __bf16 v8bf;
typedef __attribute__((ext_vector_type(4))) __bf16 v4bf;
typedef __attribute__((ext_vector_type(4))) float  v4f;
typedef __attribute__((ext_vector_type(8))) unsigned short u16x8;

// ---------- async global->LDS (16B per lane, wave-uniform LDS base) ----------
static __device__ __forceinline__ void load_lds16(const void* g, void* l) {
  __builtin_amdgcn_global_load_lds(
      (const __attribute__((address_space(1))) void*)g,
      (__attribute__((address_space(3))) void*)l, 16, 0, 0);
}

// ---------- fused prep: convert x, transpose W, build buckets ----------
#define CONV_BLOCKS 15000
#define TR_BLOCKS   2304
#define CNT_BLOCKS  512
__global__ __launch_bounds__(256)
void k_prep(const float* __restrict__ x, const float* __restrict__ w,
            const float* __restrict__ lw, const int* __restrict__ src,
            const int* __restrict__ dst, __bf16* __restrict__ xbf,
            __bf16* __restrict__ Wt, int* __restrict__ cnt,
            unsigned short* __restrict__ slots) {
  __shared__ float t[32][33];
  const int b = blockIdx.x, tid = threadIdx.x;
  if (b < CONV_BLOCKS) {
    int i = b * 256 + tid;                          // 4 elems each
    float4 v = ((const float4*)x)[i];
    v4bf o;
    o[0] = (__bf16)v.x; o[1] = (__bf16)v.y; o[2] = (__bf16)v.z; o[3] = (__bf16)v.w;
    ((v4bf*)xbf)[i] = o;
  } else if (b < CONV_BLOCKS + TR_BLOCKS) {
    int tb = b - CONV_BLOCKS;
    int k0 = (tb % 144) * 32, n0 = (tb / 144) * 32;
    int tx = tid & 31, ty = tid >> 5;               // 32 x 8
    #pragma unroll
    for (int q = 0; q < 4; ++q) {
      int k = k0 + ty + q * 8, n = n0 + tx;
      float v = (k < 4096) ? w[(size_t)k * 512 + n] : lw[(size_t)(k - 4096) * 512 + n];
      t[ty + q * 8][tx] = v;
    }
    __syncthreads();
    #pragma unroll
    for (int q = 0; q < 4; ++q) {
      int n = n0 + ty + q * 8, k = k0 + tx;
      Wt[(size_t)n * KTOT + k] = (__bf16)t[tx][ty + q * 8];
    }
  } else {
    int cb  = b - CONV_BLOCKS - TR_BLOCKS;          // 0..511
    int rel = cb & 7;                               // XCD-affine rel
    int q   = cb >> 3;                              // 0..63 within rel
    int e0  = rel * N_EDGES + (q * 256 + tid) * 8;  // 8 edges, same rel
    int4 sa = *(const int4*)(src + e0), sb = *(const int4*)(src + e0 + 4);
    int4 da = *(const int4*)(dst + e0), db = *(const int4*)(dst + e0 + 4);
    int ss[8] = {sa.x, sa.y, sa.z, sa.w, sb.x, sb.y, sb.z, sb.w};
    int dd[8] = {da.x, da.y, da.z, da.w, db.x, db.y, db.z, db.w};
    int bb[8], pp[8];
    #pragma unroll
    for (int j = 0; j < 8; ++j) {
      bb[j] = rel * N_NODES + dd[j];
      pp[j] = atomicAdd(&cnt[bb[j]], 1);
    }
    #pragma unroll
    for (int j = 0; j < 8; ++j)
      if (pp[j] < CAP) slots[(size_t)bb[j] * CAP + pp[j]] = (unsigned short)ss[j];
  }
}

// ---------- aggregation: one wave/bucket ----------
__global__ __launch_bounds__(256)
void k_aggregate(const __bf16* __restrict__ xbf, const int* __restrict__ cnt,
                 const unsigned short* __restrict__ slots,
                 __bf16* __restrict__ out, int nBuckets) {
  int w = (blockIdx.x * blockDim.x + threadIdx.x) >> 6;
  int lane = threadIdx.x & 63;
  if (w >= nBuckets) return;
  const unsigned short* sl = slots + (size_t)w * CAP;
  u16x8 qs[4];                                      // one 64B line, issued up front
  qs[0] = *(const u16x8*)(sl);
  qs[1] = *(const u16x8*)(sl + 8);
  qs[2] = *(const u16x8*)(sl + 16);
  qs[3] = *(const u16x8*)(sl + 24);
  int c = cnt[w];
  int cc = c < CAP ? c : CAP;
  const __bf16* xb = xbf + (size_t)lane * 8;
  float acc[8] = {0.f,0.f,0.f,0.f,0.f,0.f,0.f,0.f};
  #pragma unroll
  for (int g = 0; g < 4; ++g) {
    if (cc > g * 8) {                               // wave-uniform branch
      int m = cc - g * 8;
      v8bf r[8];
      #pragma unroll
      for (int j = 0; j < 8; ++j)
        if (m > j) r[j] = *(const v8bf*)(xb + (size_t)qs[g][j] * FEAT);
      #pragma unroll
      for (int j = 0; j < 8; ++j)
        if (m > j) {
          #pragma unroll
          for (int t = 0; t < 8; ++t) acc[t] += (float)r[j][t];
        }
    }
  }
  float scale = 1.0f / (float)(c > 1 ? c : 1);
  v8bf o;
  #pragma unroll
  for (int t = 0; t < 8; ++t) o[t] = (__bf16)(acc[t] * scale);
  *(v8bf*)(out + (size_t)w * FEAT + lane * 8) = o;
}

// ---------- GEMM: 128x128 tile, mfma 16x16x32 bf16, XOR-swizzled LDS ----------
// XCD-affine block map: the 4 ntile-siblings sharing an A-panel have
// blockIdx ≡ (mod 8) -> same XCD L2. LDS-staged fp32 epilogue with stride-132
// cbuf (528B row pitch): quad writes alias only 2-way (free per m136), reads
// stay 16B-aligned for ds_read_b128. Full-line float4 global stores.
template <bool ACCUM, bool FINAL>
__global__ __launch_bounds__(256, 4)
void k_gemm(const __bf16* __restrict__ A, size_t slabStride,
            const __bf16* __restrict__ Wt, int wtStride, int kTiles,
            const float* __restrict__ bias, float* __restrict__ C,
            int mtBase, int mtEnd) {
  __shared__ __align__(16) char smem[33792];   // max(As+Bs 32768, cbuf 64x132x4)
  __bf16* As = (__bf16*)smem;                  // 128x64 bf16 = 16 KB
  __bf16* Bs = (__bf16*)(smem + 16384);        // 128x64 bf16 = 16 KB

  const int tid  = threadIdx.x;
  const int wave = tid >> 6;
  const int lane = tid & 63;
  const int lr = lane >> 3, lc = lane & 7;     // staging: row-in-chunk, 16B slot
  const int gcs = (lc ^ lr) * 8;               // swizzled global chunk (elem offset)
  const int quad = lane >> 4, l15 = lane & 15; // mfma lane decomposition
  const int wRow = wave >> 1, wCol = wave & 1;

  const int panel = blockIdx.x >> 5;
  const int w32   = blockIdx.x & 31;
  const int mtile = mtBase + panel * 8 + (w32 & 7);
  const int ntile = w32 >> 3;
  if (mtile >= mtEnd) return;                  // uniform whole-block exit
  const int mBase = mtile * 128;
  const int nBase = ntile * 128;

  v4f acc[4][4];
  #pragma unroll
  for (int i = 0; i < 4; ++i)
    #pragma unroll
    for (int j = 0; j < 4; ++j) acc[i][j] = (v4f){0.f, 0.f, 0.f, 0.f};

  for (int kt = 0; kt < kTiles; ++kt) {
    const int kk = kt * 64;
    const __bf16* aT = A + (size_t)(kk >> 9) * slabStride + (kk & 511);
    #pragma unroll
    for (int t = 0; t < 4; ++t) {
      int chunk = wave * 4 + t;                 // 8 rows x 64 cols per chunk
      int row = mBase + chunk * 8 + lr;
      if (row > N_NODES - 1) row = N_NODES - 1; // clamp; masked at store
      load_lds16(aT + (size_t)row * FEAT + gcs, As + chunk * 512);
      int n = nBase + chunk * 8 + lr;
      load_lds16(Wt + (size_t)n * wtStride + kk + gcs, Bs + chunk * 512);
    }
    __syncthreads();
    #pragma unroll
    for (int ks = 0; ks < 2; ++ks) {
      const int q = ks * 4 + quad;              // 16B chunk wanted this phase
      v8bf af[4], bfr[4];
      #pragma unroll
      for (int mi = 0; mi < 4; ++mi) {
        int m = wRow * 64 + mi * 16 + l15;
        af[mi] = *(const v8bf*)(As + m * 64 + ((q ^ (m & 7)) * 8));
      }
      #pragma unroll
      for (int ni = 0; ni < 4; ++ni) {
        int n = wCol * 64 + ni * 16 + l15;
        bfr[ni] = *(const v8bf*)(Bs + n * 64 + ((q ^ (n & 7)) * 8));
      }
      #pragma unroll
      for (int mi = 0; mi < 4; ++mi)
        #pragma unroll
        for (int ni = 0; ni < 4; ++ni)
          acc[mi][ni] = __builtin_amdgcn_mfma_f32_16x16x32_bf16(af[mi], bfr[ni], acc[mi][ni], 0, 0, 0);
    }
    __syncthreads();
  }

  // ---- LDS-staged fp32 epilogue: two 64-row halves, full-line stores ----
  float* cbuf = (float*)smem;                  // 64 x 132 fp32 = 33792 B
  const int f4c  = tid & 31;                   // float4 column within the tile
  const int colg = nBase + f4c * 4;
  v4f bias4 = (v4f){0.f, 0.f, 0.f, 0.f};
  if (FINAL) bias4 = *(const v4f*)(bias + colg);
  #pragma unroll
  for (int h = 0; h < 2; ++h) {
    if (wRow == h) {                           // 2 waves own this 64-row half
      #pragma unroll
      for (int mi = 0; mi < 4; ++mi) {
        int r0 = mi * 16 + quad * 4;           // row within half
        #pragma unroll
        for (int ni = 0; ni < 4; ++ni) {
          int c = wCol * 64 + ni * 16 + l15;
          #pragma unroll
          for (int e = 0; e < 4; ++e)
            cbuf[(r0 + e) * 132 + c] = acc[mi][ni][e];
        }
      }
    }
    __syncthreads();
    #pragma unroll
    for (int i = 0; i < 8; ++i) {
      int rh  = (tid >> 5) + 8 * i;            // 8 rows per instruction, all waves
      int row = mBase + h * 64 + rh;
      if (row < N_NODES) {
        v4f v = *(const v4f*)(cbuf + rh * 132 + f4c * 4);
        size_t idx = (size_t)row * FEAT + colg;
        if (ACCUM) {
          v4f c0 = *(const v4f*)(C + idx);
          v += c0;
        }
        if (FINAL) {
          #pragma unroll
          for (int e = 0; e < 4; ++e) v[e] = fmaxf(v[e] + bias4[e], 0.f);
        }
        *(v4f*)(C + idx) = v;
      }
    }
    __syncthreads();
  }
}

extern "C" void kernel_launch(void* const* d_in, const int* in_sizes, int n_in,
                              void* d_out, int out_size, void* d_ws, size_t ws_size,
                              hipStream_t stream) {
  const float* x    = (const float*)d_in[0];
  const float* w    = (const float*)d_in[1];
  const float* lw   = (const float*)d_in[2];
  const float* bias = (const float*)d_in[3];
  const int*   src  = (const int*)d_in[4];
  const int*   dst  = (const int*)d_in[5];
  float* out = (float*)d_out;

  char* ws = (char*)d_ws;
  const size_t SLAB  = (size_t)N_NODES * FEAT;              // elems per slab
  const size_t slabB = SLAB * 2;                            // 30.72 MB
  const size_t wtB   = (size_t)FEAT * KTOT * 2;             // 4.72 MB
  const size_t cntB  = (size_t)N_REL * N_NODES * 4;         // 0.96 MB
  const size_t slotB = (size_t)N_REL * N_NODES * CAP * 2;   // 15.36 MB (u16)
  const size_t fixedB = wtB + cntB + slotB;                 // 21.04 MB

  __bf16*         Wt     = (__bf16*)ws;
  int*            cnt    = (int*)(ws + wtB);
  unsigned short* slots  = (unsigned short*)(ws + wtB + cntB);
  __bf16*         slabs  = (__bf16*)(ws + fixedB);          // 16B-aligned

  int nSlab = (int)((ws_size - fixedB) / slabB);            // total slots incl. x slot
  if (nSlab > 9) nSlab = 9;
  int g = nSlab - 1;                                        // agg slabs per GEMM pass
  if (g > 8) g = 8;
  if (g < 1) g = 1;
  __bf16* xbf = slabs + (size_t)g * SLAB;                   // last slot = x (bf16)

  hipMemsetAsync(cnt, 0, cntB, stream);
  k_prep<<<CONV_BLOCKS + TR_BLOCKS + CNT_BLOCKS, 256, 0, stream>>>(
      x, w, lw, src, dst, xbf, Wt, cnt, slots);

  const int nMtiles = (N_NODES + 127) / 128;                // 235

  if (g == 8) {
    // fused GEMM problem: agg slabs 0..7 + x at slot 8 -> K = 4608.
    // Aggregate as TWO bucket-halves (r0-measured ~3x faster per bucket than
    // one 240K dispatch -- smaller concurrent gather working set); GEMM stays
    // merged (one 960-block dispatch, r1-measured -170us vs M-split).
    const int hB = (N_REL * N_NODES) / 2;                   // 120000 buckets each
    k_aggregate<<<hB / 4, 256, 0, stream>>>(xbf, cnt, slots, slabs, hB);
    k_aggregate<<<hB / 4, 256, 0, stream>>>(xbf, cnt + hB,
                                            slots + (size_t)hB * CAP,
                                            slabs + (size_t)hB * FEAT, hB);
    const int grid = ((nMtiles + 7) / 8) * 32;              // 30 panels
    k_gemm<false, true><<<grid, 256, 0, stream>>>(slabs, SLAB, Wt, KTOT,
                                                  KTOT / 64, bias, out, 0, nMtiles);
  } else {
    const int gemmGrid = ((nMtiles + 7) / 8) * 32;
    for (int r0 = 0; r0 < N_REL; r0 += g) {
      int gc2 = (N_REL - r0) < g ? (N_REL - r0) : g;
      k_aggregate<<<(gc2 * N_NODES) / 4, 256, 0, stream>>>(
          xbf, cnt + r0 * N_NODES, slots + (size_t)r0 * N_NODES * CAP,
          slabs, gc2 * N_NODES);
      if (r0 == 0)
        k_gemm<false, false><<<gemmGrid, 256, 0, stream>>>(
            slabs, SLAB, Wt + r0 * 512, KTOT, gc2 * 8, bias, out, 0, nMtiles);
      else
        k_gemm<true, false><<<gemmGrid, 256, 0, stream>>>(
            slabs, SLAB, Wt + r0 * 512, KTOT, gc2 * 8, bias, out, 0, nMtiles);
    }
    k_gemm<true, true><<<gemmGrid, 256, 0, stream>>>(xbf, SLAB, Wt + 4096, KTOT,
                                                     8, bias, out, 0, nMtiles);
  }
}

// Round 5
// 542.925 us; speedup vs baseline: 1.0310x; 1.0058x over previous
//
#include <hip/hip_runtime.h>
#include <hip/hip_bf16.h>

#define N_NODES 30000
#define N_REL   8
#define N_EDGES 131072
#define FEAT    512
#define KTOT    4608   // 8*512 + 512
#define CAP     32

typedef __attribute__((ext_vector_type(8))) __bf16 v8bf;
typedef __attribute__((ext_vector_type(4))) __bf16 v4bf;
typedef __attribute__((ext_vector_type(4))) float  v4f;
typedef __attribute__((ext_vector_type(8))) unsigned short u16x8;

// ---------- async global->LDS (16B per lane, wave-uniform LDS base) ----------
static __device__ __forceinline__ void load_lds16(const void* g, void* l) {
  __builtin_amdgcn_global_load_lds(
      (const __attribute__((address_space(1))) void*)g,
      (__attribute__((address_space(3))) void*)l, 16, 0, 0);
}

// ---------- fused prep: convert x, transpose W, build buckets ----------
#define CONV_BLOCKS 15000
#define TR_BLOCKS   2304
#define CNT_BLOCKS  512
__global__ __launch_bounds__(256)
void k_prep(const float* __restrict__ x, const float* __restrict__ w,
            const float* __restrict__ lw, const int* __restrict__ src,
            const int* __restrict__ dst, __bf16* __restrict__ xbf,
            __bf16* __restrict__ Wt, int* __restrict__ cnt,
            unsigned short* __restrict__ slots) {
  __shared__ float t[32][33];
  const int b = blockIdx.x, tid = threadIdx.x;
  if (b < CONV_BLOCKS) {
    int i = b * 256 + tid;                          // 4 elems each
    float4 v = ((const float4*)x)[i];
    v4bf o;
    o[0] = (__bf16)v.x; o[1] = (__bf16)v.y; o[2] = (__bf16)v.z; o[3] = (__bf16)v.w;
    ((v4bf*)xbf)[i] = o;
  } else if (b < CONV_BLOCKS + TR_BLOCKS) {
    int tb = b - CONV_BLOCKS;
    int k0 = (tb % 144) * 32, n0 = (tb / 144) * 32;
    int tx = tid & 31, ty = tid >> 5;               // 32 x 8
    #pragma unroll
    for (int q = 0; q < 4; ++q) {
      int k = k0 + ty + q * 8, n = n0 + tx;
      float v = (k < 4096) ? w[(size_t)k * 512 + n] : lw[(size_t)(k - 4096) * 512 + n];
      t[ty + q * 8][tx] = v;
    }
    __syncthreads();
    #pragma unroll
    for (int q = 0; q < 4; ++q) {
      int n = n0 + ty + q * 8, k = k0 + tx;
      Wt[(size_t)n * KTOT + k] = (__bf16)t[tx][ty + q * 8];
    }
  } else {
    int cb  = b - CONV_BLOCKS - TR_BLOCKS;          // 0..511
    int rel = cb & 7;                               // XCD-affine rel
    int q   = cb >> 3;                              // 0..63 within rel
    int e0  = rel * N_EDGES + (q * 256 + tid) * 8;  // 8 edges, same rel
    int4 sa = *(const int4*)(src + e0), sb = *(const int4*)(src + e0 + 4);
    int4 da = *(const int4*)(dst + e0), db = *(const int4*)(dst + e0 + 4);
    int ss[8] = {sa.x, sa.y, sa.z, sa.w, sb.x, sb.y, sb.z, sb.w};
    int dd[8] = {da.x, da.y, da.z, da.w, db.x, db.y, db.z, db.w};
    int bb[8], pp[8];
    #pragma unroll
    for (int j = 0; j < 8; ++j) {
      bb[j] = rel * N_NODES + dd[j];
      pp[j] = atomicAdd(&cnt[bb[j]], 1);
    }
    #pragma unroll
    for (int j = 0; j < 8; ++j)
      if (pp[j] < CAP) slots[(size_t)bb[j] * CAP + pp[j]] = (unsigned short)ss[j];
  }
}

// ---------- aggregation: one wave/bucket ----------
// nt on the zero-reuse streams ONLY (slot lines, cnt, out stores) so the
// 30.7 MB xbf gather working set stays resident in L2/Infinity Cache.
// Gather loads stay cached. (r3 bundled nt into gemm too -- not separable;
// this isolates the aggregate-side effect.)
__global__ __launch_bounds__(256)
void k_aggregate(const __bf16* __restrict__ xbf, const int* __restrict__ cnt,
                 const unsigned short* __restrict__ slots,
                 __bf16* __restrict__ out, int nBuckets) {
  int w = (blockIdx.x * blockDim.x + threadIdx.x) >> 6;
  int lane = threadIdx.x & 63;
  if (w >= nBuckets) return;
  const unsigned short* sl = slots + (size_t)w * CAP;
  u16x8 qs[4];                                      // one 64B line, issued up front
  qs[0] = __builtin_nontemporal_load((const u16x8*)(sl));
  qs[1] = __builtin_nontemporal_load((const u16x8*)(sl + 8));
  qs[2] = __builtin_nontemporal_load((const u16x8*)(sl + 16));
  qs[3] = __builtin_nontemporal_load((const u16x8*)(sl + 24));
  int c = __builtin_nontemporal_load(cnt + w);
  int cc = c < CAP ? c : CAP;
  const __bf16* xb = xbf + (size_t)lane * 8;
  float acc[8] = {0.f,0.f,0.f,0.f,0.f,0.f,0.f,0.f};
  #pragma unroll
  for (int g = 0; g < 4; ++g) {
    if (cc > g * 8) {                               // wave-uniform branch
      int m = cc - g * 8;
      v8bf r[8];
      #pragma unroll
      for (int j = 0; j < 8; ++j)
        if (m > j) r[j] = *(const v8bf*)(xb + (size_t)qs[g][j] * FEAT);  // cached gather
      #pragma unroll
      for (int j = 0; j < 8; ++j)
        if (m > j) {
          #pragma unroll
          for (int t = 0; t < 8; ++t) acc[t] += (float)r[j][t];
        }
    }
  }
  float scale = 1.0f / (float)(c > 1 ? c : 1);
  v8bf o;
  #pragma unroll
  for (int t = 0; t < 8; ++t) o[t] = (__bf16)(acc[t] * scale);
  __builtin_nontemporal_store(o, (v8bf*)(out + (size_t)w * FEAT + lane * 8));
}

// ---------- GEMM: 128x128 tile, mfma 16x16x32 bf16, XOR-swizzled LDS ----------
// XCD-affine block map: the 4 ntile-siblings sharing an A-panel have
// blockIdx ≡ (mod 8) -> same XCD L2. LDS-staged fp32 epilogue with stride-132
// cbuf (quad writes alias only 2-way = free per m136). Full-line float4 stores.
template <bool ACCUM, bool FINAL>
__global__ __launch_bounds__(256, 4)
void k_gemm(const __bf16* __restrict__ A, size_t slabStride,
            const __bf16* __restrict__ Wt, int wtStride, int kTiles,
            const float* __restrict__ bias, float* __restrict__ C,
            int mtBase, int mtEnd) {
  __shared__ __align__(16) char smem[33792];   // max(As+Bs 32768, cbuf 64x132x4)
  __bf16* As = (__bf16*)smem;                  // 128x64 bf16 = 16 KB
  __bf16* Bs = (__bf16*)(smem + 16384);        // 128x64 bf16 = 16 KB

  const int tid  = threadIdx.x;
  const int wave = tid >> 6;
  const int lane = tid & 63;
  const int lr = lane >> 3, lc = lane & 7;     // staging: row-in-chunk, 16B slot
  const int gcs = (lc ^ lr) * 8;               // swizzled global chunk (elem offset)
  const int quad = lane >> 4, l15 = lane & 15; // mfma lane decomposition
  const int wRow = wave >> 1, wCol = wave & 1;

  const int panel = blockIdx.x >> 5;
  const int w32   = blockIdx.x & 31;
  const int mtile = mtBase + panel * 8 + (w32 & 7);
  const int ntile = w32 >> 3;
  if (mtile >= mtEnd) return;                  // uniform whole-block exit
  const int mBase = mtile * 128;
  const int nBase = ntile * 128;

  v4f acc[4][4];
  #pragma unroll
  for (int i = 0; i < 4; ++i)
    #pragma unroll
    for (int j = 0; j < 4; ++j) acc[i][j] = (v4f){0.f, 0.f, 0.f, 0.f};

  for (int kt = 0; kt < kTiles; ++kt) {
    const int kk = kt * 64;
    const __bf16* aT = A + (size_t)(kk >> 9) * slabStride + (kk & 511);
    #pragma unroll
    for (int t = 0; t < 4; ++t) {
      int chunk = wave * 4 + t;                 // 8 rows x 64 cols per chunk
      int row = mBase + chunk * 8 + lr;
      if (row > N_NODES - 1) row = N_NODES - 1; // clamp; masked at store
      load_lds16(aT + (size_t)row * FEAT + gcs, As + chunk * 512);
      int n = nBase + chunk * 8 + lr;
      load_lds16(Wt + (size_t)n * wtStride + kk + gcs, Bs + chunk * 512);
    }
    __syncthreads();
    #pragma unroll
    for (int ks = 0; ks < 2; ++ks) {
      const int q = ks * 4 + quad;              // 16B chunk wanted this phase
      v8bf af[4], bfr[4];
      #pragma unroll
      for (int mi = 0; mi < 4; ++mi) {
        int m = wRow * 64 + mi * 16 + l15;
        af[mi] = *(const v8bf*)(As + m * 64 + ((q ^ (m & 7)) * 8));
      }
      #pragma unroll
      for (int ni = 0; ni < 4; ++ni) {
        int n = wCol * 64 + ni * 16 + l15;
        bfr[ni] = *(const v8bf*)(Bs + n * 64 + ((q ^ (n & 7)) * 8));
      }
      #pragma unroll
      for (int mi = 0; mi < 4; ++mi)
        #pragma unroll
        for (int ni = 0; ni < 4; ++ni)
          acc[mi][ni] = __builtin_amdgcn_mfma_f32_16x16x32_bf16(af[mi], bfr[ni], acc[mi][ni], 0, 0, 0);
    }
    __syncthreads();
  }

  // ---- LDS-staged fp32 epilogue: two 64-row halves, full-line stores ----
  float* cbuf = (float*)smem;                  // 64 x 132 fp32 = 33792 B
  const int f4c  = tid & 31;                   // float4 column within the tile
  const int colg = nBase + f4c * 4;
  v4f bias4 = (v4f){0.f, 0.f, 0.f, 0.f};
  if (FINAL) bias4 = *(const v4f*)(bias + colg);
  #pragma unroll
  for (int h = 0; h < 2; ++h) {
    if (wRow == h) {                           // 2 waves own this 64-row half
      #pragma unroll
      for (int mi = 0; mi < 4; ++mi) {
        int r0 = mi * 16 + quad * 4;           // row within half
        #pragma unroll
        for (int ni = 0; ni < 4; ++ni) {
          int c = wCol * 64 + ni * 16 + l15;
          #pragma unroll
          for (int e = 0; e < 4; ++e)
            cbuf[(r0 + e) * 132 + c] = acc[mi][ni][e];
        }
      }
    }
    __syncthreads();
    #pragma unroll
    for (int i = 0; i < 8; ++i) {
      int rh  = (tid >> 5) + 8 * i;            // 8 rows per instruction, all waves
      int row = mBase + h * 64 + rh;
      if (row < N_NODES) {
        v4f v = *(const v4f*)(cbuf + rh * 132 + f4c * 4);
        size_t idx = (size_t)row * FEAT + colg;
        if (ACCUM) {
          v4f c0 = *(const v4f*)(C + idx);
          v += c0;
        }
        if (FINAL) {
          #pragma unroll
          for (int e = 0; e < 4; ++e) v[e] = fmaxf(v[e] + bias4[e], 0.f);
        }
        *(v4f*)(C + idx) = v;
      }
    }
    __syncthreads();
  }
}

extern "C" void kernel_launch(void* const* d_in, const int* in_sizes, int n_in,
                              void* d_out, int out_size, void* d_ws, size_t ws_size,
                              hipStream_t stream) {
  const float* x    = (const float*)d_in[0];
  const float* w    = (const float*)d_in[1];
  const float* lw   = (const float*)d_in[2];
  const float* bias = (const float*)d_in[3];
  const int*   src  = (const int*)d_in[4];
  const int*   dst  = (const int*)d_in[5];
  float* out = (float*)d_out;

  char* ws = (char*)d_ws;
  const size_t SLAB  = (size_t)N_NODES * FEAT;              // elems per slab
  const size_t slabB = SLAB * 2;                            // 30.72 MB
  const size_t wtB   = (size_t)FEAT * KTOT * 2;             // 4.72 MB
  const size_t cntB  = (size_t)N_REL * N_NODES * 4;         // 0.96 MB
  const size_t slotB = (size_t)N_REL * N_NODES * CAP * 2;   // 15.36 MB (u16)
  const size_t fixedB = wtB + cntB + slotB;                 // 21.04 MB

  __bf16*         Wt     = (__bf16*)ws;
  int*            cnt    = (int*)(ws + wtB);
  unsigned short* slots  = (unsigned short*)(ws + wtB + cntB);
  __bf16*         slabs  = (__bf16*)(ws + fixedB);          // 16B-aligned

  int nSlab = (int)((ws_size - fixedB) / slabB);            // total slots incl. x slot
  // Measured reality (r4 counters): ws fits exactly 8 slabs -> g=7. The
  // whole schedule is built around that: 7 agg slabs + x slab.
  int g = nSlab - 1;                                        // agg slabs avail
  if (g > 7) g = 7;
  if (g < 1) g = 1;
  __bf16* xbf = slabs + (size_t)g * SLAB;                   // slot g = x (bf16)

  hipMemsetAsync(cnt, 0, cntB, stream);
  k_prep<<<CONV_BLOCKS + TR_BLOCKS + CNT_BLOCKS, 256, 0, stream>>>(
      x, w, lw, src, dst, xbf, Wt, cnt, slots);

  const int nMtiles = (N_NODES + 127) / 128;                // 235
  const int gemmGrid = ((nMtiles + 7) / 8) * 32;            // 960 blocks

  if (g == 7) {
    // pass1: rels 0..6 -> slots 0..6; K=3584 gemm (no C readback).
    k_aggregate<<<(7 * N_NODES) / 4, 256, 0, stream>>>(xbf, cnt, slots,
                                                       slabs, 7 * N_NODES);
    k_gemm<false, false><<<gemmGrid, 256, 0, stream>>>(
        slabs, SLAB, Wt, KTOT, 3584 / 64, bias, out, 0, nMtiles);
    // pass2: rel 7 -> slot 6 (dead after gemm1). Slots 6,7 = [rel7, x] are
    // contiguous in memory AND in Wt columns (3584..4607): one K=1024
    // ACCUM+FINAL gemm replaces the two K=512 gemms (-123 MB C traffic).
    k_aggregate<<<N_NODES / 4, 256, 0, stream>>>(
        xbf, cnt + 7 * N_NODES, slots + (size_t)7 * N_NODES * CAP,
        slabs + (size_t)6 * SLAB, N_NODES);
    k_gemm<true, true><<<gemmGrid, 256, 0, stream>>>(
        slabs + (size_t)6 * SLAB, SLAB, Wt + 3584, KTOT, 1024 / 64,
        bias, out, 0, nMtiles);
  } else {
    // defensive generic path (smaller workspace)
    for (int r0 = 0; r0 < N_REL; r0 += g) {
      int gc2 = (N_REL - r0) < g ? (N_REL - r0) : g;
      k_aggregate<<<(gc2 * N_NODES) / 4, 256, 0, stream>>>(
          xbf, cnt + r0 * N_NODES, slots + (size_t)r0 * N_NODES * CAP,
          slabs, gc2 * N_NODES);
      if (r0 == 0)
        k_gemm<false, false><<<gemmGrid, 256, 0, stream>>>(
            slabs, SLAB, Wt + r0 * 512, KTOT, gc2 * 8, bias, out, 0, nMtiles);
      else
        k_gemm<true, false><<<gemmGrid, 256, 0, stream>>>(
            slabs, SLAB, Wt + r0 * 512, KTOT, gc2 * 8, bias, out, 0, nMtiles);
    }
    k_gemm<true, true><<<gemmGrid, 256, 0, stream>>>(xbf, SLAB, Wt + 4096, KTOT,
                                                     8, bias, out, 0, nMtiles);
  }
}

// Round 6
// 528.155 us; speedup vs baseline: 1.0599x; 1.0280x over previous
//
#include <hip/hip_runtime.h>
#include <hip/hip_bf16.h>

#define N_NODES 30000
#define N_REL   8
#define N_EDGES 131072
#define FEAT    512
#define KTOT    4608   // 8*512 + 512
#define CAP     32

typedef __attribute__((ext_vector_type(8))) __bf16 v8bf;
typedef __attribute__((ext_vector_type(4))) __bf16 v4bf;
typedef __attribute__((ext_vector_type(4))) float  v4f;
typedef __attribute__((ext_vector_type(8))) unsigned short u16x8;

// ---------- async global->LDS (16B per lane, wave-uniform LDS base) ----------
static __device__ __forceinline__ void load_lds16(const void* g, void* l) {
  __builtin_amdgcn_global_load_lds(
      (const __attribute__((address_space(1))) void*)g,
      (__attribute__((address_space(3))) void*)l, 16, 0, 0);
}

// ---------- fused prep: convert x, transpose W, build buckets ----------
#define CONV_BLOCKS 15000
#define TR_BLOCKS   2304
#define CNT_BLOCKS  512
__global__ __launch_bounds__(256)
void k_prep(const float* __restrict__ x, const float* __restrict__ w,
            const float* __restrict__ lw, const int* __restrict__ src,
            const int* __restrict__ dst, __bf16* __restrict__ xbf,
            __bf16* __restrict__ Wt, int* __restrict__ cnt,
            unsigned short* __restrict__ slots) {
  __shared__ float t[32][33];
  const int b = blockIdx.x, tid = threadIdx.x;
  if (b < CONV_BLOCKS) {
    int i = b * 256 + tid;                          // 4 elems each
    float4 v = ((const float4*)x)[i];
    v4bf o;
    o[0] = (__bf16)v.x; o[1] = (__bf16)v.y; o[2] = (__bf16)v.z; o[3] = (__bf16)v.w;
    ((v4bf*)xbf)[i] = o;
  } else if (b < CONV_BLOCKS + TR_BLOCKS) {
    int tb = b - CONV_BLOCKS;
    int k0 = (tb % 144) * 32, n0 = (tb / 144) * 32;
    int tx = tid & 31, ty = tid >> 5;               // 32 x 8
    #pragma unroll
    for (int q = 0; q < 4; ++q) {
      int k = k0 + ty + q * 8, n = n0 + tx;
      float v = (k < 4096) ? w[(size_t)k * 512 + n] : lw[(size_t)(k - 4096) * 512 + n];
      t[ty + q * 8][tx] = v;
    }
    __syncthreads();
    #pragma unroll
    for (int q = 0; q < 4; ++q) {
      int n = n0 + ty + q * 8, k = k0 + tx;
      Wt[(size_t)n * KTOT + k] = (__bf16)t[tx][ty + q * 8];
    }
  } else {
    int cb  = b - CONV_BLOCKS - TR_BLOCKS;          // 0..511
    int rel = cb & 7;                               // XCD-affine rel
    int q   = cb >> 3;                              // 0..63 within rel
    int e0  = rel * N_EDGES + (q * 256 + tid) * 8;  // 8 edges, same rel
    int4 sa = *(const int4*)(src + e0), sb = *(const int4*)(src + e0 + 4);
    int4 da = *(const int4*)(dst + e0), db = *(const int4*)(dst + e0 + 4);
    int ss[8] = {sa.x, sa.y, sa.z, sa.w, sb.x, sb.y, sb.z, sb.w};
    int dd[8] = {da.x, da.y, da.z, da.w, db.x, db.y, db.z, db.w};
    int bb[8], pp[8];
    #pragma unroll
    for (int j = 0; j < 8; ++j) {
      bb[j] = rel * N_NODES + dd[j];
      pp[j] = atomicAdd(&cnt[bb[j]], 1);
    }
    #pragma unroll
    for (int j = 0; j < 8; ++j)
      if (pp[j] < CAP) slots[(size_t)bb[j] * CAP + pp[j]] = (unsigned short)ss[j];
  }
}

// ---------- aggregation: one wave/bucket (r4-proven: NO nt hints) ----------
__global__ __launch_bounds__(256)
void k_aggregate(const __bf16* __restrict__ xbf, const int* __restrict__ cnt,
                 const unsigned short* __restrict__ slots,
                 __bf16* __restrict__ out, int nBuckets) {
  int w = (blockIdx.x * blockDim.x + threadIdx.x) >> 6;
  int lane = threadIdx.x & 63;
  if (w >= nBuckets) return;
  const unsigned short* sl = slots + (size_t)w * CAP;
  u16x8 qs[4];                                      // one 64B line, issued up front
  qs[0] = *(const u16x8*)(sl);
  qs[1] = *(const u16x8*)(sl + 8);
  qs[2] = *(const u16x8*)(sl + 16);
  qs[3] = *(const u16x8*)(sl + 24);
  int c = cnt[w];
  int cc = c < CAP ? c : CAP;
  const __bf16* xb = xbf + (size_t)lane * 8;
  float acc[8] = {0.f,0.f,0.f,0.f,0.f,0.f,0.f,0.f};
  #pragma unroll
  for (int g = 0; g < 4; ++g) {
    if (cc > g * 8) {                               // wave-uniform branch
      int m = cc - g * 8;
      v8bf r[8];
      #pragma unroll
      for (int j = 0; j < 8; ++j)
        if (m > j) r[j] = *(const v8bf*)(xb + (size_t)qs[g][j] * FEAT);
      #pragma unroll
      for (int j = 0; j < 8; ++j)
        if (m > j) {
          #pragma unroll
          for (int t = 0; t < 8; ++t) acc[t] += (float)r[j][t];
        }
    }
  }
  float scale = 1.0f / (float)(c > 1 ? c : 1);
  v8bf o;
  #pragma unroll
  for (int t = 0; t < 8; ++t) o[t] = (__bf16)(acc[t] * scale);
  *(v8bf*)(out + (size_t)w * FEAT + lane * 8) = o;
}

// ---------- GEMM v3: 256x256 tile, BK=64, 8 waves, 8-phase counted-vmcnt ----
// m201-style schedule. Per K-tile: 4 phases = C-quadrants (0,0),(0,1),(1,1),
// (1,0); phase (R,C) reads only A-half R and B-half C. Stage order (one tile
// ahead, 1 half-tile = 2 global_load_lds per wave): p0->A0, p1->B0, p2->B1,
// p3->A1. vmcnt(4) (=2 half-tiles) before trailing barrier of p0/p1/p3;
// none needed at p2 (p3 reads nothing from LDS). Last tile: vmcnt(2)/vmcnt(0).
// LDS = 2 buf x (A 256x64 + B 256x64) bf16 = 131072 B (m201's exact size).
template <bool ACCUM, bool FINAL>
__global__ __launch_bounds__(512, 2)
void k_gemm3(const __bf16* __restrict__ A, size_t slabStride,
             const __bf16* __restrict__ Wt, int kTiles,
             const float* __restrict__ bias, float* __restrict__ C) {
  __shared__ __align__(16) char smem[131072];

  const int tid  = threadIdx.x;
  const int wave = tid >> 6, lane = tid & 63;
  const int lr = lane >> 3, lc = lane & 7;
  const int gcs = (lc ^ lr) * 8;               // pre-swizzled global chunk
  const int quad = lane >> 4, l15 = lane & 15;
  const int wR2 = wave >> 2;                   // row band (64) within quadrant
  const int wC4 = wave & 3;                    // col band (32) within quadrant

  // bijective XCD swizzle (m204)
  const int nwg = gridDim.x;
  const int qq = nwg >> 3, rr = nwg & 7;
  const int xcd = blockIdx.x & 7, oidx = blockIdx.x >> 3;
  const int wg = (xcd < rr ? xcd * (qq + 1) : rr * (qq + 1) + (xcd - rr) * qq) + oidx;
  const int mtile = wg >> 1, ntile = wg & 1;
  const int mBase = mtile * 256, nBase = ntile * 256;

  v4f acc[2][2][4][2];
  #pragma unroll
  for (int a = 0; a < 2; ++a)
    #pragma unroll
    for (int bq = 0; bq < 2; ++bq)
      #pragma unroll
      for (int mi = 0; mi < 4; ++mi)
        #pragma unroll
        for (int ni = 0; ni < 2; ++ni)
          acc[a][bq][mi][ni] = (v4f){0.f, 0.f, 0.f, 0.f};

  // stage one half-tile (128 rows x 64 k) = 2 global_load_lds per wave
  auto stageA = [&](int t, int h) {
    __bf16* dst = (__bf16*)(smem + (t & 1) * 65536);
    const int kk = t * 64;
    const __bf16* base = A + (size_t)(kk >> 9) * slabStride + (kk & 511);
    #pragma unroll
    for (int r2 = 0; r2 < 2; ++r2) {
      int rt = h * 128 + r2 * 64 + wave * 8;   // wave-uniform row base in tile
      int row = mBase + rt + lr;
      if (row > N_NODES - 1) row = N_NODES - 1;
      load_lds16(base + (size_t)row * FEAT + gcs, dst + rt * 64);
    }
  };
  auto stageB = [&](int t, int h) {
    __bf16* dst = (__bf16*)(smem + (t & 1) * 65536 + 32768);
    const int kk = t * 64;
    #pragma unroll
    for (int r2 = 0; r2 < 2; ++r2) {
      int rt = h * 128 + r2 * 64 + wave * 8;
      int n = nBase + rt + lr;
      load_lds16(Wt + (size_t)n * KTOT + kk + gcs, dst + rt * 64);
    }
  };

  // ---- prologue: tile 0's 4 halves in steady-state order; A0,B0 landed ----
  stageA(0, 0); stageB(0, 0); stageB(0, 1); stageA(0, 1);
  asm volatile("s_waitcnt vmcnt(4)" ::: "memory");
  __builtin_amdgcn_s_barrier();
  __builtin_amdgcn_sched_barrier(0);

  for (int t = 0; t < kTiles; ++t) {
    const __bf16* sA = (const __bf16*)(smem + (t & 1) * 65536);
    const __bf16* sB = sA + 16384;             // 32768 B = 16384 elems
    const bool pf = (t + 1) < kTiles;
    v8bf af[4][2], bf0[2][2], bf1[2][2];

    // ---- p0: quadrant (0,0); read A0,B0; stage A0(t+1) ----
    #pragma unroll
    for (int mi = 0; mi < 4; ++mi)
      #pragma unroll
      for (int ks = 0; ks < 2; ++ks) {
        int m = wR2 * 64 + mi * 16 + l15;
        int q = ks * 4 + quad;
        af[mi][ks] = *(const v8bf*)(sA + m * 64 + ((q ^ (m & 7)) * 8));
      }
    #pragma unroll
    for (int ni = 0; ni < 2; ++ni)
      #pragma unroll
      for (int ks = 0; ks < 2; ++ks) {
        int n = wC4 * 32 + ni * 16 + l15;
        int q = ks * 4 + quad;
        bf0[ni][ks] = *(const v8bf*)(sB + n * 64 + ((q ^ (n & 7)) * 8));
      }
    if (pf) stageA(t + 1, 0);
    __builtin_amdgcn_s_barrier();
    asm volatile("s_waitcnt lgkmcnt(0)" ::: "memory");
    __builtin_amdgcn_sched_barrier(0);
    __builtin_amdgcn_s_setprio(1);
    #pragma unroll
    for (int ks = 0; ks < 2; ++ks)
      #pragma unroll
      for (int mi = 0; mi < 4; ++mi)
        #pragma unroll
        for (int ni = 0; ni < 2; ++ni)
          acc[0][0][mi][ni] = __builtin_amdgcn_mfma_f32_16x16x32_bf16(
              af[mi][ks], bf0[ni][ks], acc[0][0][mi][ni], 0, 0, 0);
    __builtin_amdgcn_s_setprio(0);
    if (pf) asm volatile("s_waitcnt vmcnt(4)" ::: "memory");  // B1(t) landed
    else    asm volatile("s_waitcnt vmcnt(2)" ::: "memory");
    __builtin_amdgcn_s_barrier();
    __builtin_amdgcn_sched_barrier(0);

    // ---- p1: quadrant (0,1); read B1; stage B0(t+1) ----
    #pragma unroll
    for (int ni = 0; ni < 2; ++ni)
      #pragma unroll
      for (int ks = 0; ks < 2; ++ks) {
        int n = 128 + wC4 * 32 + ni * 16 + l15;
        int q = ks * 4 + quad;
        bf1[ni][ks] = *(const v8bf*)(sB + n * 64 + ((q ^ (n & 7)) * 8));
      }
    if (pf) stageB(t + 1, 0);
    __builtin_amdgcn_s_barrier();
    asm volatile("s_waitcnt lgkmcnt(0)" ::: "memory");
    __builtin_amdgcn_sched_barrier(0);
    __builtin_amdgcn_s_setprio(1);
    #pragma unroll
    for (int ks = 0; ks < 2; ++ks)
      #pragma unroll
      for (int mi = 0; mi < 4; ++mi)
        #pragma unroll
        for (int ni = 0; ni < 2; ++ni)
          acc[0][1][mi][ni] = __builtin_amdgcn_mfma_f32_16x16x32_bf16(
              af[mi][ks], bf1[ni][ks], acc[0][1][mi][ni], 0, 0, 0);
    __builtin_amdgcn_s_setprio(0);
    if (pf) asm volatile("s_waitcnt vmcnt(4)" ::: "memory");  // A1(t) landed
    else    asm volatile("s_waitcnt vmcnt(0)" ::: "memory");
    __builtin_amdgcn_s_barrier();
    __builtin_amdgcn_sched_barrier(0);

    // ---- p2: quadrant (1,1); read A1; stage B1(t+1) ----
    #pragma unroll
    for (int mi = 0; mi < 4; ++mi)
      #pragma unroll
      for (int ks = 0; ks < 2; ++ks) {
        int m = 128 + wR2 * 64 + mi * 16 + l15;
        int q = ks * 4 + quad;
        af[mi][ks] = *(const v8bf*)(sA + m * 64 + ((q ^ (m & 7)) * 8));
      }
    if (pf) stageB(t + 1, 1);
    __builtin_amdgcn_s_barrier();
    asm volatile("s_waitcnt lgkmcnt(0)" ::: "memory");
    __builtin_amdgcn_sched_barrier(0);
    __builtin_amdgcn_s_setprio(1);
    #pragma unroll
    for (int ks = 0; ks < 2; ++ks)
      #pragma unroll
      for (int mi = 0; mi < 4; ++mi)
        #pragma unroll
        for (int ni = 0; ni < 2; ++ni)
          acc[1][1][mi][ni] = __builtin_amdgcn_mfma_f32_16x16x32_bf16(
              af[mi][ks], bf1[ni][ks], acc[1][1][mi][ni], 0, 0, 0);
    __builtin_amdgcn_s_setprio(0);
    __builtin_amdgcn_s_barrier();                   // p3 reads no LDS: no vmcnt
    __builtin_amdgcn_sched_barrier(0);

    // ---- p3: quadrant (1,0); reuse af(R1), bf0; stage A1(t+1) ----
    if (pf) stageA(t + 1, 1);
    __builtin_amdgcn_s_barrier();
    __builtin_amdgcn_s_setprio(1);
    #pragma unroll
    for (int ks = 0; ks < 2; ++ks)
      #pragma unroll
      for (int mi = 0; mi < 4; ++mi)
        #pragma unroll
        for (int ni = 0; ni < 2; ++ni)
          acc[1][0][mi][ni] = __builtin_amdgcn_mfma_f32_16x16x32_bf16(
              af[mi][ks], bf0[ni][ks], acc[1][0][mi][ni], 0, 0, 0);
    __builtin_amdgcn_s_setprio(0);
    if (pf) asm volatile("s_waitcnt vmcnt(4)" ::: "memory");  // A0,B0(t+1) landed
    __builtin_amdgcn_s_barrier();
    __builtin_amdgcn_sched_barrier(0);
  }

  // ---- epilogue: 4 rounds of 64 rows via LDS (stride 260: 2-way = free),
  // full-line float4 stores ----
  asm volatile("s_waitcnt vmcnt(0)" ::: "memory");
  float* cbuf = (float*)smem;                       // 64 x 260 fp32 = 66560 B
  const int f4 = tid & 63;
  const int colg = nBase + f4 * 4;
  v4f bias4 = (v4f){0.f, 0.f, 0.f, 0.f};
  if (FINAL) bias4 = *(const v4f*)(bias + colg);
  #pragma unroll
  for (int h = 0; h < 4; ++h) {
    __syncthreads();
    if (wR2 == (h & 1)) {
      const int R = h >> 1;
      #pragma unroll
      for (int Cq = 0; Cq < 2; ++Cq)
        #pragma unroll
        for (int mi = 0; mi < 4; ++mi)
          #pragma unroll
          for (int ni = 0; ni < 2; ++ni)
            #pragma unroll
            for (int e = 0; e < 4; ++e)
              cbuf[(mi * 16 + quad * 4 + e) * 260 + Cq * 128 + wC4 * 32 + ni * 16 + l15] =
                  acc[R][Cq][mi][ni][e];
    }
    __syncthreads();
    #pragma unroll
    for (int i = 0; i < 8; ++i) {
      int rl  = i * 8 + (tid >> 6);
      int row = mBase + h * 64 + rl;
      if (row < N_NODES) {
        v4f v = *(const v4f*)(cbuf + rl * 260 + f4 * 4);
        size_t idx = (size_t)row * FEAT + colg;
        if (ACCUM) v += *(const v4f*)(C + idx);
        if (FINAL) {
          #pragma unroll
          for (int e = 0; e < 4; ++e) v[e] = fmaxf(v[e] + bias4[e], 0.f);
        }
        *(v4f*)(C + idx) = v;
      }
    }
  }
}

// ---------- legacy 128x128 GEMM (fallback path only) ----------
template <bool ACCUM, bool FINAL>
__global__ __launch_bounds__(256, 4)
void k_gemm(const __bf16* __restrict__ A, size_t slabStride,
            const __bf16* __restrict__ Wt, int wtStride, int kTiles,
            const float* __restrict__ bias, float* __restrict__ C,
            int mtBase, int mtEnd) {
  __shared__ __align__(16) char smem[33792];
  __bf16* As = (__bf16*)smem;
  __bf16* Bs = (__bf16*)(smem + 16384);

  const int tid  = threadIdx.x;
  const int wave = tid >> 6;
  const int lane = tid & 63;
  const int lr = lane >> 3, lc = lane & 7;
  const int gcs = (lc ^ lr) * 8;
  const int quad = lane >> 4, l15 = lane & 15;
  const int wRow = wave >> 1, wCol = wave & 1;

  const int panel = blockIdx.x >> 5;
  const int w32   = blockIdx.x & 31;
  const int mtile = mtBase + panel * 8 + (w32 & 7);
  const int ntile = w32 >> 3;
  if (mtile >= mtEnd) return;
  const int mBase = mtile * 128;
  const int nBase = ntile * 128;

  v4f acc[4][4];
  #pragma unroll
  for (int i = 0; i < 4; ++i)
    #pragma unroll
    for (int j = 0; j < 4; ++j) acc[i][j] = (v4f){0.f, 0.f, 0.f, 0.f};

  for (int kt = 0; kt < kTiles; ++kt) {
    const int kk = kt * 64;
    const __bf16* aT = A + (size_t)(kk >> 9) * slabStride + (kk & 511);
    #pragma unroll
    for (int t = 0; t < 4; ++t) {
      int chunk = wave * 4 + t;
      int row = mBase + chunk * 8 + lr;
      if (row > N_NODES - 1) row = N_NODES - 1;
      load_lds16(aT + (size_t)row * FEAT + gcs, As + chunk * 512);
      int n = nBase + chunk * 8 + lr;
      load_lds16(Wt + (size_t)n * wtStride + kk + gcs, Bs + chunk * 512);
    }
    __syncthreads();
    #pragma unroll
    for (int ks = 0; ks < 2; ++ks) {
      const int q = ks * 4 + quad;
      v8bf af[4], bfr[4];
      #pragma unroll
      for (int mi = 0; mi < 4; ++mi) {
        int m = wRow * 64 + mi * 16 + l15;
        af[mi] = *(const v8bf*)(As + m * 64 + ((q ^ (m & 7)) * 8));
      }
      #pragma unroll
      for (int ni = 0; ni < 4; ++ni) {
        int n = wCol * 64 + ni * 16 + l15;
        bfr[ni] = *(const v8bf*)(Bs + n * 64 + ((q ^ (n & 7)) * 8));
      }
      #pragma unroll
      for (int mi = 0; mi < 4; ++mi)
        #pragma unroll
        for (int ni = 0; ni < 4; ++ni)
          acc[mi][ni] = __builtin_amdgcn_mfma_f32_16x16x32_bf16(af[mi], bfr[ni], acc[mi][ni], 0, 0, 0);
    }
    __syncthreads();
  }

  float* cbuf = (float*)smem;
  const int f4c  = tid & 31;
  const int colg = nBase + f4c * 4;
  v4f bias4 = (v4f){0.f, 0.f, 0.f, 0.f};
  if (FINAL) bias4 = *(const v4f*)(bias + colg);
  #pragma unroll
  for (int h = 0; h < 2; ++h) {
    if (wRow == h) {
      #pragma unroll
      for (int mi = 0; mi < 4; ++mi) {
        int r0 = mi * 16 + quad * 4;
        #pragma unroll
        for (int ni = 0; ni < 4; ++ni) {
          int c = wCol * 64 + ni * 16 + l15;
          #pragma unroll
          for (int e = 0; e < 4; ++e)
            cbuf[(r0 + e) * 132 + c] = acc[mi][ni][e];
        }
      }
    }
    __syncthreads();
    #pragma unroll
    for (int i = 0; i < 8; ++i) {
      int rh  = (tid >> 5) + 8 * i;
      int row = mBase + h * 64 + rh;
      if (row < N_NODES) {
        v4f v = *(const v4f*)(cbuf + rh * 132 + f4c * 4);
        size_t idx = (size_t)row * FEAT + colg;
        if (ACCUM) v += *(const v4f*)(C + idx);
        if (FINAL) {
          #pragma unroll
          for (int e = 0; e < 4; ++e) v[e] = fmaxf(v[e] + bias4[e], 0.f);
        }
        *(v4f*)(C + idx) = v;
      }
    }
    __syncthreads();
  }
}

extern "C" void kernel_launch(void* const* d_in, const int* in_sizes, int n_in,
                              void* d_out, int out_size, void* d_ws, size_t ws_size,
                              hipStream_t stream) {
  const float* x    = (const float*)d_in[0];
  const float* w    = (const float*)d_in[1];
  const float* lw   = (const float*)d_in[2];
  const float* bias = (const float*)d_in[3];
  const int*   src  = (const int*)d_in[4];
  const int*   dst  = (const int*)d_in[5];
  float* out = (float*)d_out;

  char* ws = (char*)d_ws;
  const size_t SLAB  = (size_t)N_NODES * FEAT;              // elems per slab
  const size_t slabB = SLAB * 2;                            // 30.72 MB
  const size_t wtB   = (size_t)FEAT * KTOT * 2;             // 4.72 MB
  const size_t cntB  = (size_t)N_REL * N_NODES * 4;         // 0.96 MB
  const size_t slotB = (size_t)N_REL * N_NODES * CAP * 2;   // 15.36 MB (u16)
  const size_t fixedB = wtB + cntB + slotB;                 // 21.04 MB

  __bf16*         Wt     = (__bf16*)ws;
  int*            cnt    = (int*)(ws + wtB);
  unsigned short* slots  = (unsigned short*)(ws + wtB + cntB);
  __bf16*         slabs  = (__bf16*)(ws + fixedB);          // 16B-aligned

  int nSlab = (int)((ws_size - fixedB) / slabB);            // total slots incl. x slot
  int g = nSlab - 1;                                        // agg slabs avail
  if (g > 7) g = 7;
  if (g < 1) g = 1;
  __bf16* xbf = slabs + (size_t)g * SLAB;                   // slot g = x (bf16)

  hipMemsetAsync(cnt, 0, cntB, stream);
  k_prep<<<CONV_BLOCKS + TR_BLOCKS + CNT_BLOCKS, 256, 0, stream>>>(
      x, w, lw, src, dst, xbf, Wt, cnt, slots);

  if (g == 7) {
    const int mt256 = (N_NODES + 255) / 256;                // 118
    const int grid3 = mt256 * 2;                            // 236 blocks
    // pass1: rels 0..6 -> slots 0..6; K=3584 8-phase gemm (no C readback).
    k_aggregate<<<(7 * N_NODES) / 4, 256, 0, stream>>>(xbf, cnt, slots,
                                                       slabs, 7 * N_NODES);
    k_gemm3<false, false><<<grid3, 512, 0, stream>>>(
        slabs, SLAB, Wt, 3584 / 64, bias, out);
    // pass2: rel 7 -> slot 6 (dead after gemm1); slots 6,7 = [rel7, x]
    // contiguous in memory and in Wt columns -> one K=1024 ACCUM+FINAL gemm.
    k_aggregate<<<N_NODES / 4, 256, 0, stream>>>(
        xbf, cnt + 7 * N_NODES, slots + (size_t)7 * N_NODES * CAP,
        slabs + (size_t)6 * SLAB, N_NODES);
    k_gemm3<true, true><<<grid3, 512, 0, stream>>>(
        slabs + (size_t)6 * SLAB, SLAB, Wt + 3584, 1024 / 64, bias, out);
  } else {
    // defensive generic path (smaller workspace)
    const int nMtiles = (N_NODES + 127) / 128;
    const int gemmGrid = ((nMtiles + 7) / 8) * 32;
    for (int r0 = 0; r0 < N_REL; r0 += g) {
      int gc2 = (N_REL - r0) < g ? (N_REL - r0) : g;
      k_aggregate<<<(gc2 * N_NODES) / 4, 256, 0, stream>>>(
          xbf, cnt + r0 * N_NODES, slots + (size_t)r0 * N_NODES * CAP,
          slabs, gc2 * N_NODES);
      if (r0 == 0)
        k_gemm<false, false><<<gemmGrid, 256, 0, stream>>>(
            slabs, SLAB, Wt + r0 * 512, KTOT, gc2 * 8, bias, out, 0, nMtiles);
      else
        k_gemm<true, false><<<gemmGrid, 256, 0, stream>>>(
            slabs, SLAB, Wt + r0 * 512, KTOT, gc2 * 8, bias, out, 0, nMtiles);
    }
    k_gemm<true, true><<<gemmGrid, 256, 0, stream>>>(xbf, SLAB, Wt + 4096, KTOT,
                                                     8, bias, out, 0, nMtiles);
  }
}

// Round 7
// 527.663 us; speedup vs baseline: 1.0608x; 1.0009x over previous
//
#include <hip/hip_runtime.h>
#include <hip/hip_bf16.h>

#define N_NODES 30000
#define N_REL   8
#define N_EDGES 131072
#define FEAT    512
#define KTOT    4608   // 8*512 + 512
#define CAP     32

typedef __attribute__((ext_vector_type(8))) __bf16 v8bf;
typedef __attribute__((ext_vector_type(4))) __bf16 v4bf;
typedef __attribute__((ext_vector_type(4))) float  v4f;
typedef __attribute__((ext_vector_type(2))) float  f2;
typedef __attribute__((ext_vector_type(8))) unsigned short u16x8;

// ---------- async global->LDS (16B per lane, wave-uniform LDS base) ----------
static __device__ __forceinline__ void load_lds16(const void* g, void* l) {
  __builtin_amdgcn_global_load_lds(
      (const __attribute__((address_space(1))) void*)g,
      (__attribute__((address_space(3))) void*)l, 16, 0, 0);
}

// ---------- fused prep: convert x, transpose W, build buckets ----------
#define CONV_BLOCKS 15000
#define TR_BLOCKS   2304
#define CNT_BLOCKS  512
__global__ __launch_bounds__(256)
void k_prep(const float* __restrict__ x, const float* __restrict__ w,
            const float* __restrict__ lw, const int* __restrict__ src,
            const int* __restrict__ dst, __bf16* __restrict__ xbf,
            __bf16* __restrict__ Wt, int* __restrict__ cnt,
            unsigned short* __restrict__ slots) {
  __shared__ float t[32][33];
  const int b = blockIdx.x, tid = threadIdx.x;
  if (b < CONV_BLOCKS) {
    int i = b * 256 + tid;                          // 4 elems each
    float4 v = ((const float4*)x)[i];
    v4bf o;
    o[0] = (__bf16)v.x; o[1] = (__bf16)v.y; o[2] = (__bf16)v.z; o[3] = (__bf16)v.w;
    ((v4bf*)xbf)[i] = o;
  } else if (b < CONV_BLOCKS + TR_BLOCKS) {
    int tb = b - CONV_BLOCKS;
    int k0 = (tb % 144) * 32, n0 = (tb / 144) * 32;
    int tx = tid & 31, ty = tid >> 5;               // 32 x 8
    #pragma unroll
    for (int q = 0; q < 4; ++q) {
      int k = k0 + ty + q * 8, n = n0 + tx;
      float v = (k < 4096) ? w[(size_t)k * 512 + n] : lw[(size_t)(k - 4096) * 512 + n];
      t[ty + q * 8][tx] = v;
    }
    __syncthreads();
    #pragma unroll
    for (int q = 0; q < 4; ++q) {
      int n = n0 + ty + q * 8, k = k0 + tx;
      Wt[(size_t)n * KTOT + k] = (__bf16)t[tx][ty + q * 8];
    }
  } else {
    int cb  = b - CONV_BLOCKS - TR_BLOCKS;          // 0..511
    int rel = cb & 7;                               // XCD-affine rel
    int q   = cb >> 3;                              // 0..63 within rel
    int e0  = rel * N_EDGES + (q * 256 + tid) * 8;  // 8 edges, same rel
    int4 sa = *(const int4*)(src + e0), sb = *(const int4*)(src + e0 + 4);
    int4 da = *(const int4*)(dst + e0), db = *(const int4*)(dst + e0 + 4);
    int ss[8] = {sa.x, sa.y, sa.z, sa.w, sb.x, sb.y, sb.z, sb.w};
    int dd[8] = {da.x, da.y, da.z, da.w, db.x, db.y, db.z, db.w};
    int bb[8], pp[8];
    #pragma unroll
    for (int j = 0; j < 8; ++j) {
      bb[j] = rel * N_NODES + dd[j];
      pp[j] = atomicAdd(&cnt[bb[j]], 1);
    }
    #pragma unroll
    for (int j = 0; j < 8; ++j)
      if (pp[j] < CAP) slots[(size_t)bb[j] * CAP + pp[j]] = (unsigned short)ss[j];
  }
}

// ---------- aggregation: one wave/bucket ----------
// Accumulate loop reworked to cut VALU ~2x (it ran at 50% VALUBusy while
// BW-bound): widen bf16 pairs with shift/mask (bf16 is truncated f32) and
// accumulate in float2 -> v_pk_add_f32. 3 VALU per 2 elems vs ~4-6 before.
__global__ __launch_bounds__(256)
void k_aggregate(const __bf16* __restrict__ xbf, const int* __restrict__ cnt,
                 const unsigned short* __restrict__ slots,
                 __bf16* __restrict__ out, int nBuckets) {
  int w = (blockIdx.x * blockDim.x + threadIdx.x) >> 6;
  int lane = threadIdx.x & 63;
  if (w >= nBuckets) return;
  const unsigned short* sl = slots + (size_t)w * CAP;
  u16x8 qs[4];                                      // one 64B line, issued up front
  qs[0] = *(const u16x8*)(sl);
  qs[1] = *(const u16x8*)(sl + 8);
  qs[2] = *(const u16x8*)(sl + 16);
  qs[3] = *(const u16x8*)(sl + 24);
  int c = cnt[w];
  int cc = c < CAP ? c : CAP;
  const __bf16* xb = xbf + (size_t)lane * 8;
  f2 acc2[4];
  #pragma unroll
  for (int p = 0; p < 4; ++p) acc2[p] = (f2){0.f, 0.f};
  #pragma unroll
  for (int g = 0; g < 4; ++g) {
    if (cc > g * 8) {                               // wave-uniform branch
      int m = cc - g * 8;
      v8bf r[8];
      #pragma unroll
      for (int j = 0; j < 8; ++j)
        if (m > j) r[j] = *(const v8bf*)(xb + (size_t)qs[g][j] * FEAT);
      #pragma unroll
      for (int j = 0; j < 8; ++j)
        if (m > j) {
          const unsigned* ru = (const unsigned*)&r[j];
          #pragma unroll
          for (int p = 0; p < 4; ++p) {             // word p = elems 2p, 2p+1
            f2 v;
            v[0] = __uint_as_float(ru[p] << 16);            // lo bf16 -> f32
            v[1] = __uint_as_float(ru[p] & 0xffff0000u);    // hi bf16 -> f32
            acc2[p] += v;                                    // v_pk_add_f32
          }
        }
    }
  }
  float scale = 1.0f / (float)(c > 1 ? c : 1);
  v8bf o;
  #pragma unroll
  for (int p = 0; p < 4; ++p) {
    o[2 * p]     = (__bf16)(acc2[p][0] * scale);
    o[2 * p + 1] = (__bf16)(acc2[p][1] * scale);
  }
  *(v8bf*)(out + (size_t)w * FEAT + lane * 8) = o;
}

// ---------- GEMM v3: 256x256 tile, BK=64, 8 waves, 8-phase counted-vmcnt ----
// (r6-proven: passed, ~850 TF at this problem's 236-block grid.)
template <bool ACCUM, bool FINAL>
__global__ __launch_bounds__(512, 2)
void k_gemm3(const __bf16* __restrict__ A, size_t slabStride,
             const __bf16* __restrict__ Wt, int kTiles,
             const float* __restrict__ bias, float* __restrict__ C) {
  __shared__ __align__(16) char smem[131072];

  const int tid  = threadIdx.x;
  const int wave = tid >> 6, lane = tid & 63;
  const int lr = lane >> 3, lc = lane & 7;
  const int gcs = (lc ^ lr) * 8;               // pre-swizzled global chunk
  const int quad = lane >> 4, l15 = lane & 15;
  const int wR2 = wave >> 2;                   // row band (64) within quadrant
  const int wC4 = wave & 3;                    // col band (32) within quadrant

  // bijective XCD swizzle (m204)
  const int nwg = gridDim.x;
  const int qq = nwg >> 3, rr = nwg & 7;
  const int xcd = blockIdx.x & 7, oidx = blockIdx.x >> 3;
  const int wg = (xcd < rr ? xcd * (qq + 1) : rr * (qq + 1) + (xcd - rr) * qq) + oidx;
  const int mtile = wg >> 1, ntile = wg & 1;
  const int mBase = mtile * 256, nBase = ntile * 256;

  v4f acc[2][2][4][2];
  #pragma unroll
  for (int a = 0; a < 2; ++a)
    #pragma unroll
    for (int bq = 0; bq < 2; ++bq)
      #pragma unroll
      for (int mi = 0; mi < 4; ++mi)
        #pragma unroll
        for (int ni = 0; ni < 2; ++ni)
          acc[a][bq][mi][ni] = (v4f){0.f, 0.f, 0.f, 0.f};

  // stage one half-tile (128 rows x 64 k) = 2 global_load_lds per wave
  auto stageA = [&](int t, int h) {
    __bf16* dst = (__bf16*)(smem + (t & 1) * 65536);
    const int kk = t * 64;
    const __bf16* base = A + (size_t)(kk >> 9) * slabStride + (kk & 511);
    #pragma unroll
    for (int r2 = 0; r2 < 2; ++r2) {
      int rt = h * 128 + r2 * 64 + wave * 8;   // wave-uniform row base in tile
      int row = mBase + rt + lr;
      if (row > N_NODES - 1) row = N_NODES - 1;
      load_lds16(base + (size_t)row * FEAT + gcs, dst + rt * 64);
    }
  };
  auto stageB = [&](int t, int h) {
    __bf16* dst = (__bf16*)(smem + (t & 1) * 65536 + 32768);
    const int kk = t * 64;
    #pragma unroll
    for (int r2 = 0; r2 < 2; ++r2) {
      int rt = h * 128 + r2 * 64 + wave * 8;
      int n = nBase + rt + lr;
      load_lds16(Wt + (size_t)n * KTOT + kk + gcs, dst + rt * 64);
    }
  };

  // ---- prologue: tile 0's 4 halves in steady-state order; A0,B0 landed ----
  stageA(0, 0); stageB(0, 0); stageB(0, 1); stageA(0, 1);
  asm volatile("s_waitcnt vmcnt(4)" ::: "memory");
  __builtin_amdgcn_s_barrier();
  __builtin_amdgcn_sched_barrier(0);

  for (int t = 0; t < kTiles; ++t) {
    const __bf16* sA = (const __bf16*)(smem + (t & 1) * 65536);
    const __bf16* sB = sA + 16384;             // 32768 B = 16384 elems
    const bool pf = (t + 1) < kTiles;
    v8bf af[4][2], bf0[2][2], bf1[2][2];

    // ---- p0: quadrant (0,0); read A0,B0; stage A0(t+1) ----
    #pragma unroll
    for (int mi = 0; mi < 4; ++mi)
      #pragma unroll
      for (int ks = 0; ks < 2; ++ks) {
        int m = wR2 * 64 + mi * 16 + l15;
        int q = ks * 4 + quad;
        af[mi][ks] = *(const v8bf*)(sA + m * 64 + ((q ^ (m & 7)) * 8));
      }
    #pragma unroll
    for (int ni = 0; ni < 2; ++ni)
      #pragma unroll
      for (int ks = 0; ks < 2; ++ks) {
        int n = wC4 * 32 + ni * 16 + l15;
        int q = ks * 4 + quad;
        bf0[ni][ks] = *(const v8bf*)(sB + n * 64 + ((q ^ (n & 7)) * 8));
      }
    if (pf) stageA(t + 1, 0);
    __builtin_amdgcn_s_barrier();
    asm volatile("s_waitcnt lgkmcnt(0)" ::: "memory");
    __builtin_amdgcn_sched_barrier(0);
    __builtin_amdgcn_s_setprio(1);
    #pragma unroll
    for (int ks = 0; ks < 2; ++ks)
      #pragma unroll
      for (int mi = 0; mi < 4; ++mi)
        #pragma unroll
        for (int ni = 0; ni < 2; ++ni)
          acc[0][0][mi][ni] = __builtin_amdgcn_mfma_f32_16x16x32_bf16(
              af[mi][ks], bf0[ni][ks], acc[0][0][mi][ni], 0, 0, 0);
    __builtin_amdgcn_s_setprio(0);
    if (pf) asm volatile("s_waitcnt vmcnt(4)" ::: "memory");  // B1(t) landed
    else    asm volatile("s_waitcnt vmcnt(2)" ::: "memory");
    __builtin_amdgcn_s_barrier();
    __builtin_amdgcn_sched_barrier(0);

    // ---- p1: quadrant (0,1); read B1; stage B0(t+1) ----
    #pragma unroll
    for (int ni = 0; ni < 2; ++ni)
      #pragma unroll
      for (int ks = 0; ks < 2; ++ks) {
        int n = 128 + wC4 * 32 + ni * 16 + l15;
        int q = ks * 4 + quad;
        bf1[ni][ks] = *(const v8bf*)(sB + n * 64 + ((q ^ (n & 7)) * 8));
      }
    if (pf) stageB(t + 1, 0);
    __builtin_amdgcn_s_barrier();
    asm volatile("s_waitcnt lgkmcnt(0)" ::: "memory");
    __builtin_amdgcn_sched_barrier(0);
    __builtin_amdgcn_s_setprio(1);
    #pragma unroll
    for (int ks = 0; ks < 2; ++ks)
      #pragma unroll
      for (int mi = 0; mi < 4; ++mi)
        #pragma unroll
        for (int ni = 0; ni < 2; ++ni)
          acc[0][1][mi][ni] = __builtin_amdgcn_mfma_f32_16x16x32_bf16(
              af[mi][ks], bf1[ni][ks], acc[0][1][mi][ni], 0, 0, 0);
    __builtin_amdgcn_s_setprio(0);
    if (pf) asm volatile("s_waitcnt vmcnt(4)" ::: "memory");  // A1(t) landed
    else    asm volatile("s_waitcnt vmcnt(0)" ::: "memory");
    __builtin_amdgcn_s_barrier();
    __builtin_amdgcn_sched_barrier(0);

    // ---- p2: quadrant (1,1); read A1; stage B1(t+1) ----
    #pragma unroll
    for (int mi = 0; mi < 4; ++mi)
      #pragma unroll
      for (int ks = 0; ks < 2; ++ks) {
        int m = 128 + wR2 * 64 + mi * 16 + l15;
        int q = ks * 4 + quad;
        af[mi][ks] = *(const v8bf*)(sA + m * 64 + ((q ^ (m & 7)) * 8));
      }
    if (pf) stageB(t + 1, 1);
    __builtin_amdgcn_s_barrier();
    asm volatile("s_waitcnt lgkmcnt(0)" ::: "memory");
    __builtin_amdgcn_sched_barrier(0);
    __builtin_amdgcn_s_setprio(1);
    #pragma unroll
    for (int ks = 0; ks < 2; ++ks)
      #pragma unroll
      for (int mi = 0; mi < 4; ++mi)
        #pragma unroll
        for (int ni = 0; ni < 2; ++ni)
          acc[1][1][mi][ni] = __builtin_amdgcn_mfma_f32_16x16x32_bf16(
              af[mi][ks], bf1[ni][ks], acc[1][1][mi][ni], 0, 0, 0);
    __builtin_amdgcn_s_setprio(0);
    __builtin_amdgcn_s_barrier();                   // p3 reads no LDS: no vmcnt
    __builtin_amdgcn_sched_barrier(0);

    // ---- p3: quadrant (1,0); reuse af(R1), bf0; stage A1(t+1) ----
    if (pf) stageA(t + 1, 1);
    __builtin_amdgcn_s_barrier();
    __builtin_amdgcn_s_setprio(1);
    #pragma unroll
    for (int ks = 0; ks < 2; ++ks)
      #pragma unroll
      for (int mi = 0; mi < 4; ++mi)
        #pragma unroll
        for (int ni = 0; ni < 2; ++ni)
          acc[1][0][mi][ni] = __builtin_amdgcn_mfma_f32_16x16x32_bf16(
              af[mi][ks], bf0[ni][ks], acc[1][0][mi][ni], 0, 0, 0);
    __builtin_amdgcn_s_setprio(0);
    if (pf) asm volatile("s_waitcnt vmcnt(4)" ::: "memory");  // A0,B0(t+1) landed
    __builtin_amdgcn_s_barrier();
    __builtin_amdgcn_sched_barrier(0);
  }

  // ---- epilogue: 4 rounds of 64 rows via LDS (stride 260: 2-way = free),
  // full-line float4 stores ----
  asm volatile("s_waitcnt vmcnt(0)" ::: "memory");
  float* cbuf = (float*)smem;                       // 64 x 260 fp32 = 66560 B
  const int f4 = tid & 63;
  const int colg = nBase + f4 * 4;
  v4f bias4 = (v4f){0.f, 0.f, 0.f, 0.f};
  if (FINAL) bias4 = *(const v4f*)(bias + colg);
  #pragma unroll
  for (int h = 0; h < 4; ++h) {
    __syncthreads();
    if (wR2 == (h & 1)) {
      const int R = h >> 1;
      #pragma unroll
      for (int Cq = 0; Cq < 2; ++Cq)
        #pragma unroll
        for (int mi = 0; mi < 4; ++mi)
          #pragma unroll
          for (int ni = 0; ni < 2; ++ni)
            #pragma unroll
            for (int e = 0; e < 4; ++e)
              cbuf[(mi * 16 + quad * 4 + e) * 260 + Cq * 128 + wC4 * 32 + ni * 16 + l15] =
                  acc[R][Cq][mi][ni][e];
    }
    __syncthreads();
    #pragma unroll
    for (int i = 0; i < 8; ++i) {
      int rl  = i * 8 + (tid >> 6);
      int row = mBase + h * 64 + rl;
      if (row < N_NODES) {
        v4f v = *(const v4f*)(cbuf + rl * 260 + f4 * 4);
        size_t idx = (size_t)row * FEAT + colg;
        if (ACCUM) v += *(const v4f*)(C + idx);
        if (FINAL) {
          #pragma unroll
          for (int e = 0; e < 4; ++e) v[e] = fmaxf(v[e] + bias4[e], 0.f);
        }
        *(v4f*)(C + idx) = v;
      }
    }
  }
}

// ---------- legacy 128x128 GEMM (fallback path only) ----------
template <bool ACCUM, bool FINAL>
__global__ __launch_bounds__(256, 4)
void k_gemm(const __bf16* __restrict__ A, size_t slabStride,
            const __bf16* __restrict__ Wt, int wtStride, int kTiles,
            const float* __restrict__ bias, float* __restrict__ C,
            int mtBase, int mtEnd) {
  __shared__ __align__(16) char smem[33792];
  __bf16* As = (__bf16*)smem;
  __bf16* Bs = (__bf16*)(smem + 16384);

  const int tid  = threadIdx.x;
  const int wave = tid >> 6;
  const int lane = tid & 63;
  const int lr = lane >> 3, lc = lane & 7;
  const int gcs = (lc ^ lr) * 8;
  const int quad = lane >> 4, l15 = lane & 15;
  const int wRow = wave >> 1, wCol = wave & 1;

  const int panel = blockIdx.x >> 5;
  const int w32   = blockIdx.x & 31;
  const int mtile = mtBase + panel * 8 + (w32 & 7);
  const int ntile = w32 >> 3;
  if (mtile >= mtEnd) return;
  const int mBase = mtile * 128;
  const int nBase = ntile * 128;

  v4f acc[4][4];
  #pragma unroll
  for (int i = 0; i < 4; ++i)
    #pragma unroll
    for (int j = 0; j < 4; ++j) acc[i][j] = (v4f){0.f, 0.f, 0.f, 0.f};

  for (int kt = 0; kt < kTiles; ++kt) {
    const int kk = kt * 64;
    const __bf16* aT = A + (size_t)(kk >> 9) * slabStride + (kk & 511);
    #pragma unroll
    for (int t = 0; t < 4; ++t) {
      int chunk = wave * 4 + t;
      int row = mBase + chunk * 8 + lr;
      if (row > N_NODES - 1) row = N_NODES - 1;
      load_lds16(aT + (size_t)row * FEAT + gcs, As + chunk * 512);
      int n = nBase + chunk * 8 + lr;
      load_lds16(Wt + (size_t)n * wtStride + kk + gcs, Bs + chunk * 512);
    }
    __syncthreads();
    #pragma unroll
    for (int ks = 0; ks < 2; ++ks) {
      const int q = ks * 4 + quad;
      v8bf af[4], bfr[4];
      #pragma unroll
      for (int mi = 0; mi < 4; ++mi) {
        int m = wRow * 64 + mi * 16 + l15;
        af[mi] = *(const v8bf*)(As + m * 64 + ((q ^ (m & 7)) * 8));
      }
      #pragma unroll
      for (int ni = 0; ni < 4; ++ni) {
        int n = wCol * 64 + ni * 16 + l15;
        bfr[ni] = *(const v8bf*)(Bs + n * 64 + ((q ^ (n & 7)) * 8));
      }
      #pragma unroll
      for (int mi = 0; mi < 4; ++mi)
        #pragma unroll
        for (int ni = 0; ni < 4; ++ni)
          acc[mi][ni] = __builtin_amdgcn_mfma_f32_16x16x32_bf16(af[mi], bfr[ni], acc[mi][ni], 0, 0, 0);
    }
    __syncthreads();
  }

  float* cbuf = (float*)smem;
  const int f4c  = tid & 31;
  const int colg = nBase + f4c * 4;
  v4f bias4 = (v4f){0.f, 0.f, 0.f, 0.f};
  if (FINAL) bias4 = *(const v4f*)(bias + colg);
  #pragma unroll
  for (int h = 0; h < 2; ++h) {
    if (wRow == h) {
      #pragma unroll
      for (int mi = 0; mi < 4; ++mi) {
        int r0 = mi * 16 + quad * 4;
        #pragma unroll
        for (int ni = 0; ni < 4; ++ni) {
          int c = wCol * 64 + ni * 16 + l15;
          #pragma unroll
          for (int e = 0; e < 4; ++e)
            cbuf[(r0 + e) * 132 + c] = acc[mi][ni][e];
        }
      }
    }
    __syncthreads();
    #pragma unroll
    for (int i = 0; i < 8; ++i) {
      int rh  = (tid >> 5) + 8 * i;
      int row = mBase + h * 64 + rh;
      if (row < N_NODES) {
        v4f v = *(const v4f*)(cbuf + rh * 132 + f4c * 4);
        size_t idx = (size_t)row * FEAT + colg;
        if (ACCUM) v += *(const v4f*)(C + idx);
        if (FINAL) {
          #pragma unroll
          for (int e = 0; e < 4; ++e) v[e] = fmaxf(v[e] + bias4[e], 0.f);
        }
        *(v4f*)(C + idx) = v;
      }
    }
    __syncthreads();
  }
}

extern "C" void kernel_launch(void* const* d_in, const int* in_sizes, int n_in,
                              void* d_out, int out_size, void* d_ws, size_t ws_size,
                              hipStream_t stream) {
  const float* x    = (const float*)d_in[0];
  const float* w    = (const float*)d_in[1];
  const float* lw   = (const float*)d_in[2];
  const float* bias = (const float*)d_in[3];
  const int*   src  = (const int*)d_in[4];
  const int*   dst  = (const int*)d_in[5];
  float* out = (float*)d_out;

  char* ws = (char*)d_ws;
  const size_t SLAB  = (size_t)N_NODES * FEAT;              // elems per slab
  const size_t slabB = SLAB * 2;                            // 30.72 MB
  const size_t wtB   = (size_t)FEAT * KTOT * 2;             // 4.72 MB
  const size_t cntB  = (size_t)N_REL * N_NODES * 4;         // 0.96 MB
  const size_t slotB = (size_t)N_REL * N_NODES * CAP * 2;   // 15.36 MB (u16)
  const size_t fixedB = wtB + cntB + slotB;                 // 21.04 MB

  __bf16*         Wt     = (__bf16*)ws;
  int*            cnt    = (int*)(ws + wtB);
  unsigned short* slots  = (unsigned short*)(ws + wtB + cntB);
  __bf16*         slabs  = (__bf16*)(ws + fixedB);          // 16B-aligned

  int nSlab = (int)((ws_size - fixedB) / slabB);            // total slots incl. x slot
  int g = nSlab - 1;                                        // agg slabs avail
  if (g > 7) g = 7;
  if (g < 1) g = 1;
  __bf16* xbf = slabs + (size_t)g * SLAB;                   // slot g = x (bf16)

  hipMemsetAsync(cnt, 0, cntB, stream);
  k_prep<<<CONV_BLOCKS + TR_BLOCKS + CNT_BLOCKS, 256, 0, stream>>>(
      x, w, lw, src, dst, xbf, Wt, cnt, slots);

  if (g == 7) {
    const int mt256 = (N_NODES + 255) / 256;                // 118
    const int grid3 = mt256 * 2;                            // 236 blocks
    // pass1: rels 0..6 -> slots 0..6; K=3584 8-phase gemm (no C readback).
    k_aggregate<<<(7 * N_NODES) / 4, 256, 0, stream>>>(xbf, cnt, slots,
                                                       slabs, 7 * N_NODES);
    k_gemm3<false, false><<<grid3, 512, 0, stream>>>(
        slabs, SLAB, Wt, 3584 / 64, bias, out);
    // pass2: rel 7 -> slot 6 (dead after gemm1); slots 6,7 = [rel7, x]
    // contiguous in memory and in Wt columns -> one K=1024 ACCUM+FINAL gemm.
    k_aggregate<<<N_NODES / 4, 256, 0, stream>>>(
        xbf, cnt + 7 * N_NODES, slots + (size_t)7 * N_NODES * CAP,
        slabs + (size_t)6 * SLAB, N_NODES);
    k_gemm3<true, true><<<grid3, 512, 0, stream>>>(
        slabs + (size_t)6 * SLAB, SLAB, Wt + 3584, 1024 / 64, bias, out);
  } else {
    // defensive generic path (smaller workspace)
    const int nMtiles = (N_NODES + 127) / 128;
    const int gemmGrid = ((nMtiles + 7) / 8) * 32;
    for (int r0 = 0; r0 < N_REL; r0 += g) {
      int gc2 = (N_REL - r0) < g ? (N_REL - r0) : g;
      k_aggregate<<<(gc2 * N_NODES) / 4, 256, 0, stream>>>(
          xbf, cnt + r0 * N_NODES, slots + (size_t)r0 * N_NODES * CAP,
          slabs, gc2 * N_NODES);
      if (r0 == 0)
        k_gemm<false, false><<<gemmGrid, 256, 0, stream>>>(
            slabs, SLAB, Wt + r0 * 512, KTOT, gc2 * 8, bias, out, 0, nMtiles);
      else
        k_gemm<true, false><<<gemmGrid, 256, 0, stream>>>(
            slabs, SLAB, Wt + r0 * 512, KTOT, gc2 * 8, bias, out, 0, nMtiles);
    }
    k_gemm<true, true><<<gemmGrid, 256, 0, stream>>>(xbf, SLAB, Wt + 4096, KTOT,
                                                     8, bias, out, 0, nMtiles);
  }
}

// Round 8
// 499.064 us; speedup vs baseline: 1.1216x; 1.0573x over previous
//
#include <hip/hip_runtime.h>
#include <hip/hip_bf16.h>

#define N_NODES 30000
#define N_REL   8
#define N_EDGES 131072
#define FEAT    512
#define KTOT    4608   // 8*512 + 512
#define CAP     32

typedef __attribute__((ext_vector_type(8))) __bf16 v8bf;
typedef __attribute__((ext_vector_type(4))) __bf16 v4bf;
typedef __attribute__((ext_vector_type(4))) float  v4f;
typedef __attribute__((ext_vector_type(2))) float  f2;
typedef __attribute__((ext_vector_type(8))) unsigned short u16x8;

// ---------- async global->LDS (16B per lane, wave-uniform LDS base) ----------
static __device__ __forceinline__ void load_lds16(const void* g, void* l) {
  __builtin_amdgcn_global_load_lds(
      (const __attribute__((address_space(1))) void*)g,
      (__attribute__((address_space(3))) void*)l, 16, 0, 0);
}

// ---------- fused prep: convert x, transpose W, build buckets ----------
#define CONV_BLOCKS 15000
#define TR_BLOCKS   2304
#define CNT_BLOCKS  512
__global__ __launch_bounds__(256)
void k_prep(const float* __restrict__ x, const float* __restrict__ w,
            const float* __restrict__ lw, const int* __restrict__ src,
            const int* __restrict__ dst, __bf16* __restrict__ xbf,
            __bf16* __restrict__ Wt, int* __restrict__ cnt,
            unsigned short* __restrict__ slots) {
  __shared__ float t[32][33];
  const int b = blockIdx.x, tid = threadIdx.x;
  if (b < CONV_BLOCKS) {
    int i = b * 256 + tid;                          // 4 elems each
    float4 v = ((const float4*)x)[i];
    v4bf o;
    o[0] = (__bf16)v.x; o[1] = (__bf16)v.y; o[2] = (__bf16)v.z; o[3] = (__bf16)v.w;
    ((v4bf*)xbf)[i] = o;
  } else if (b < CONV_BLOCKS + TR_BLOCKS) {
    int tb = b - CONV_BLOCKS;
    int k0 = (tb % 144) * 32, n0 = (tb / 144) * 32;
    int tx = tid & 31, ty = tid >> 5;               // 32 x 8
    #pragma unroll
    for (int q = 0; q < 4; ++q) {
      int k = k0 + ty + q * 8, n = n0 + tx;
      float v = (k < 4096) ? w[(size_t)k * 512 + n] : lw[(size_t)(k - 4096) * 512 + n];
      t[ty + q * 8][tx] = v;
    }
    __syncthreads();
    #pragma unroll
    for (int q = 0; q < 4; ++q) {
      int n = n0 + ty + q * 8, k = k0 + tx;
      Wt[(size_t)n * KTOT + k] = (__bf16)t[tx][ty + q * 8];
    }
  } else {
    int cb  = b - CONV_BLOCKS - TR_BLOCKS;          // 0..511
    int rel = cb & 7;                               // XCD-affine rel
    int q   = cb >> 3;                              // 0..63 within rel
    int e0  = rel * N_EDGES + (q * 256 + tid) * 8;  // 8 edges, same rel
    int4 sa = *(const int4*)(src + e0), sb = *(const int4*)(src + e0 + 4);
    int4 da = *(const int4*)(dst + e0), db = *(const int4*)(dst + e0 + 4);
    int ss[8] = {sa.x, sa.y, sa.z, sa.w, sb.x, sb.y, sb.z, sb.w};
    int dd[8] = {da.x, da.y, da.z, da.w, db.x, db.y, db.z, db.w};
    int bb[8], pp[8];
    #pragma unroll
    for (int j = 0; j < 8; ++j) {
      bb[j] = rel * N_NODES + dd[j];
      pp[j] = atomicAdd(&cnt[bb[j]], 1);
    }
    #pragma unroll
    for (int j = 0; j < 8; ++j)
      if (pp[j] < CAP) slots[(size_t)bb[j] * CAP + pp[j]] = (unsigned short)ss[j];
  }
}

// ---------- slice aggregation: 8 feature-slices of 64 cols ----------
// During slice s every gather touches only x[:, s*64:(s+1)*64] = 3.84 MB --
// fits a single XCD's 4 MB L2 (vs 30.7 MB full-row working set, 13% L2 hit,
// 420 MB HBM fetch). Blocks are slice-major (slice = bid/bps) so the device
// sweeps slices as a wavefront; per slice the x-data is fetched ~once.
// Wave = 8 buckets x 8 lanes (128 B/bucket-slice, full lines). Divergent
// per-group counts handled by wave-max trip + per-lane predication (masked
// lanes issue no loads -> no extra traffic).
__global__ __launch_bounds__(256)
void k_agg_slice(const __bf16* __restrict__ xbf, const int* __restrict__ cnt,
                 const unsigned short* __restrict__ slots,
                 __bf16* __restrict__ out, int nBuckets, int bps) {
  const int bid   = blockIdx.x;
  const int slice = bid / bps;                      // 0..7
  const int ib    = bid - slice * bps;
  const int tid   = threadIdx.x;
  const int wave  = tid >> 6, lane = tid & 63;
  const int grp   = lane >> 3;                      // bucket group within wave
  const int li    = lane & 7;                       // lane within group
  const int w     = ib * 32 + wave * 8 + grp;
  const bool valid = (w < nBuckets);

  int c = 0;
  u16x8 qs[4];
  if (valid) {
    c = cnt[w];
    const unsigned short* sl = slots + (size_t)w * CAP;
    qs[0] = *(const u16x8*)(sl);                    // 64B line broadcast/group
    qs[1] = *(const u16x8*)(sl + 8);
    qs[2] = *(const u16x8*)(sl + 16);
    qs[3] = *(const u16x8*)(sl + 24);
  }
  int cc = c < CAP ? c : CAP;
  int cmax = cc;                                    // wave-max across groups
  cmax = max(cmax, __shfl_xor(cmax, 8));
  cmax = max(cmax, __shfl_xor(cmax, 16));
  cmax = max(cmax, __shfl_xor(cmax, 32));

  const __bf16* xb = xbf + slice * 64 + (size_t)li * 8;
  f2 acc2[4];
  #pragma unroll
  for (int p = 0; p < 4; ++p) acc2[p] = (f2){0.f, 0.f};
  #pragma unroll
  for (int g = 0; g < 4; ++g) {
    if (cmax > g * 8) {                             // wave-uniform
      v8bf r[8];
      #pragma unroll
      for (int j = 0; j < 8; ++j)
        if (cc > g * 8 + j)                         // group-predicated load
          r[j] = *(const v8bf*)(xb + (size_t)qs[g][j] * FEAT);
      #pragma unroll
      for (int j = 0; j < 8; ++j)
        if (cc > g * 8 + j) {
          const unsigned* ru = (const unsigned*)&r[j];
          #pragma unroll
          for (int p = 0; p < 4; ++p) {
            f2 v;
            v[0] = __uint_as_float(ru[p] << 16);           // lo bf16 -> f32
            v[1] = __uint_as_float(ru[p] & 0xffff0000u);   // hi bf16 -> f32
            acc2[p] += v;                                   // v_pk_add_f32
          }
        }
    }
  }
  if (valid) {
    float scale = 1.0f / (float)(c > 1 ? c : 1);
    v8bf o;
    #pragma unroll
    for (int p = 0; p < 4; ++p) {
      o[2 * p]     = (__bf16)(acc2[p][0] * scale);
      o[2 * p + 1] = (__bf16)(acc2[p][1] * scale);
    }
    *(v8bf*)(out + (size_t)w * FEAT + slice * 64 + (size_t)li * 8) = o;
  }
}

// ---------- legacy aggregation (fallback path only) ----------
__global__ __launch_bounds__(256)
void k_aggregate(const __bf16* __restrict__ xbf, const int* __restrict__ cnt,
                 const unsigned short* __restrict__ slots,
                 __bf16* __restrict__ out, int nBuckets) {
  int w = (blockIdx.x * blockDim.x + threadIdx.x) >> 6;
  int lane = threadIdx.x & 63;
  if (w >= nBuckets) return;
  const unsigned short* sl = slots + (size_t)w * CAP;
  u16x8 qs[4];
  qs[0] = *(const u16x8*)(sl);
  qs[1] = *(const u16x8*)(sl + 8);
  qs[2] = *(const u16x8*)(sl + 16);
  qs[3] = *(const u16x8*)(sl + 24);
  int c = cnt[w];
  int cc = c < CAP ? c : CAP;
  const __bf16* xb = xbf + (size_t)lane * 8;
  f2 acc2[4];
  #pragma unroll
  for (int p = 0; p < 4; ++p) acc2[p] = (f2){0.f, 0.f};
  #pragma unroll
  for (int g = 0; g < 4; ++g) {
    if (cc > g * 8) {
      int m = cc - g * 8;
      v8bf r[8];
      #pragma unroll
      for (int j = 0; j < 8; ++j)
        if (m > j) r[j] = *(const v8bf*)(xb + (size_t)qs[g][j] * FEAT);
      #pragma unroll
      for (int j = 0; j < 8; ++j)
        if (m > j) {
          const unsigned* ru = (const unsigned*)&r[j];
          #pragma unroll
          for (int p = 0; p < 4; ++p) {
            f2 v;
            v[0] = __uint_as_float(ru[p] << 16);
            v[1] = __uint_as_float(ru[p] & 0xffff0000u);
            acc2[p] += v;
          }
        }
    }
  }
  float scale = 1.0f / (float)(c > 1 ? c : 1);
  v8bf o;
  #pragma unroll
  for (int p = 0; p < 4; ++p) {
    o[2 * p]     = (__bf16)(acc2[p][0] * scale);
    o[2 * p + 1] = (__bf16)(acc2[p][1] * scale);
  }
  *(v8bf*)(out + (size_t)w * FEAT + lane * 8) = o;
}

// ---------- GEMM v3: 256x256 tile, BK=64, 8 waves, 8-phase counted-vmcnt ----
// (r6-proven; unchanged.)
template <bool ACCUM, bool FINAL>
__global__ __launch_bounds__(512, 2)
void k_gemm3(const __bf16* __restrict__ A, size_t slabStride,
             const __bf16* __restrict__ Wt, int kTiles,
             const float* __restrict__ bias, float* __restrict__ C) {
  __shared__ __align__(16) char smem[131072];

  const int tid  = threadIdx.x;
  const int wave = tid >> 6, lane = tid & 63;
  const int lr = lane >> 3, lc = lane & 7;
  const int gcs = (lc ^ lr) * 8;               // pre-swizzled global chunk
  const int quad = lane >> 4, l15 = lane & 15;
  const int wR2 = wave >> 2;                   // row band (64) within quadrant
  const int wC4 = wave & 3;                    // col band (32) within quadrant

  // bijective XCD swizzle (m204)
  const int nwg = gridDim.x;
  const int qq = nwg >> 3, rr = nwg & 7;
  const int xcd = blockIdx.x & 7, oidx = blockIdx.x >> 3;
  const int wg = (xcd < rr ? xcd * (qq + 1) : rr * (qq + 1) + (xcd - rr) * qq) + oidx;
  const int mtile = wg >> 1, ntile = wg & 1;
  const int mBase = mtile * 256, nBase = ntile * 256;

  v4f acc[2][2][4][2];
  #pragma unroll
  for (int a = 0; a < 2; ++a)
    #pragma unroll
    for (int bq = 0; bq < 2; ++bq)
      #pragma unroll
      for (int mi = 0; mi < 4; ++mi)
        #pragma unroll
        for (int ni = 0; ni < 2; ++ni)
          acc[a][bq][mi][ni] = (v4f){0.f, 0.f, 0.f, 0.f};

  // stage one half-tile (128 rows x 64 k) = 2 global_load_lds per wave
  auto stageA = [&](int t, int h) {
    __bf16* dst = (__bf16*)(smem + (t & 1) * 65536);
    const int kk = t * 64;
    const __bf16* base = A + (size_t)(kk >> 9) * slabStride + (kk & 511);
    #pragma unroll
    for (int r2 = 0; r2 < 2; ++r2) {
      int rt = h * 128 + r2 * 64 + wave * 8;   // wave-uniform row base in tile
      int row = mBase + rt + lr;
      if (row > N_NODES - 1) row = N_NODES - 1;
      load_lds16(base + (size_t)row * FEAT + gcs, dst + rt * 64);
    }
  };
  auto stageB = [&](int t, int h) {
    __bf16* dst = (__bf16*)(smem + (t & 1) * 65536 + 32768);
    const int kk = t * 64;
    #pragma unroll
    for (int r2 = 0; r2 < 2; ++r2) {
      int rt = h * 128 + r2 * 64 + wave * 8;
      int n = nBase + rt + lr;
      load_lds16(Wt + (size_t)n * KTOT + kk + gcs, dst + rt * 64);
    }
  };

  // ---- prologue: tile 0's 4 halves in steady-state order; A0,B0 landed ----
  stageA(0, 0); stageB(0, 0); stageB(0, 1); stageA(0, 1);
  asm volatile("s_waitcnt vmcnt(4)" ::: "memory");
  __builtin_amdgcn_s_barrier();
  __builtin_amdgcn_sched_barrier(0);

  for (int t = 0; t < kTiles; ++t) {
    const __bf16* sA = (const __bf16*)(smem + (t & 1) * 65536);
    const __bf16* sB = sA + 16384;             // 32768 B = 16384 elems
    const bool pf = (t + 1) < kTiles;
    v8bf af[4][2], bf0[2][2], bf1[2][2];

    // ---- p0: quadrant (0,0); read A0,B0; stage A0(t+1) ----
    #pragma unroll
    for (int mi = 0; mi < 4; ++mi)
      #pragma unroll
      for (int ks = 0; ks < 2; ++ks) {
        int m = wR2 * 64 + mi * 16 + l15;
        int q = ks * 4 + quad;
        af[mi][ks] = *(const v8bf*)(sA + m * 64 + ((q ^ (m & 7)) * 8));
      }
    #pragma unroll
    for (int ni = 0; ni < 2; ++ni)
      #pragma unroll
      for (int ks = 0; ks < 2; ++ks) {
        int n = wC4 * 32 + ni * 16 + l15;
        int q = ks * 4 + quad;
        bf0[ni][ks] = *(const v8bf*)(sB + n * 64 + ((q ^ (n & 7)) * 8));
      }
    if (pf) stageA(t + 1, 0);
    __builtin_amdgcn_s_barrier();
    asm volatile("s_waitcnt lgkmcnt(0)" ::: "memory");
    __builtin_amdgcn_sched_barrier(0);
    __builtin_amdgcn_s_setprio(1);
    #pragma unroll
    for (int ks = 0; ks < 2; ++ks)
      #pragma unroll
      for (int mi = 0; mi < 4; ++mi)
        #pragma unroll
        for (int ni = 0; ni < 2; ++ni)
          acc[0][0][mi][ni] = __builtin_amdgcn_mfma_f32_16x16x32_bf16(
              af[mi][ks], bf0[ni][ks], acc[0][0][mi][ni], 0, 0, 0);
    __builtin_amdgcn_s_setprio(0);
    if (pf) asm volatile("s_waitcnt vmcnt(4)" ::: "memory");  // B1(t) landed
    else    asm volatile("s_waitcnt vmcnt(2)" ::: "memory");
    __builtin_amdgcn_s_barrier();
    __builtin_amdgcn_sched_barrier(0);

    // ---- p1: quadrant (0,1); read B1; stage B0(t+1) ----
    #pragma unroll
    for (int ni = 0; ni < 2; ++ni)
      #pragma unroll
      for (int ks = 0; ks < 2; ++ks) {
        int n = 128 + wC4 * 32 + ni * 16 + l15;
        int q = ks * 4 + quad;
        bf1[ni][ks] = *(const v8bf*)(sB + n * 64 + ((q ^ (n & 7)) * 8));
      }
    if (pf) stageB(t + 1, 0);
    __builtin_amdgcn_s_barrier();
    asm volatile("s_waitcnt lgkmcnt(0)" ::: "memory");
    __builtin_amdgcn_sched_barrier(0);
    __builtin_amdgcn_s_setprio(1);
    #pragma unroll
    for (int ks = 0; ks < 2; ++ks)
      #pragma unroll
      for (int mi = 0; mi < 4; ++mi)
        #pragma unroll
        for (int ni = 0; ni < 2; ++ni)
          acc[0][1][mi][ni] = __builtin_amdgcn_mfma_f32_16x16x32_bf16(
              af[mi][ks], bf1[ni][ks], acc[0][1][mi][ni], 0, 0, 0);
    __builtin_amdgcn_s_setprio(0);
    if (pf) asm volatile("s_waitcnt vmcnt(4)" ::: "memory");  // A1(t) landed
    else    asm volatile("s_waitcnt vmcnt(0)" ::: "memory");
    __builtin_amdgcn_s_barrier();
    __builtin_amdgcn_sched_barrier(0);

    // ---- p2: quadrant (1,1); read A1; stage B1(t+1) ----
    #pragma unroll
    for (int mi = 0; mi < 4; ++mi)
      #pragma unroll
      for (int ks = 0; ks < 2; ++ks) {
        int m = 128 + wR2 * 64 + mi * 16 + l15;
        int q = ks * 4 + quad;
        af[mi][ks] = *(const v8bf*)(sA + m * 64 + ((q ^ (m & 7)) * 8));
      }
    if (pf) stageB(t + 1, 1);
    __builtin_amdgcn_s_barrier();
    asm volatile("s_waitcnt lgkmcnt(0)" ::: "memory");
    __builtin_amdgcn_sched_barrier(0);
    __builtin_amdgcn_s_setprio(1);
    #pragma unroll
    for (int ks = 0; ks < 2; ++ks)
      #pragma unroll
      for (int mi = 0; mi < 4; ++mi)
        #pragma unroll
        for (int ni = 0; ni < 2; ++ni)
          acc[1][1][mi][ni] = __builtin_amdgcn_mfma_f32_16x16x32_bf16(
              af[mi][ks], bf1[ni][ks], acc[1][1][mi][ni], 0, 0, 0);
    __builtin_amdgcn_s_setprio(0);
    __builtin_amdgcn_s_barrier();                   // p3 reads no LDS: no vmcnt
    __builtin_amdgcn_sched_barrier(0);

    // ---- p3: quadrant (1,0); reuse af(R1), bf0; stage A1(t+1) ----
    if (pf) stageA(t + 1, 1);
    __builtin_amdgcn_s_barrier();
    __builtin_amdgcn_s_setprio(1);
    #pragma unroll
    for (int ks = 0; ks < 2; ++ks)
      #pragma unroll
      for (int mi = 0; mi < 4; ++mi)
        #pragma unroll
        for (int ni = 0; ni < 2; ++ni)
          acc[1][0][mi][ni] = __builtin_amdgcn_mfma_f32_16x16x32_bf16(
              af[mi][ks], bf0[ni][ks], acc[1][0][mi][ni], 0, 0, 0);
    __builtin_amdgcn_s_setprio(0);
    if (pf) asm volatile("s_waitcnt vmcnt(4)" ::: "memory");  // A0,B0(t+1) landed
    __builtin_amdgcn_s_barrier();
    __builtin_amdgcn_sched_barrier(0);
  }

  // ---- epilogue: 4 rounds of 64 rows via LDS (stride 260: 2-way = free),
  // full-line float4 stores ----
  asm volatile("s_waitcnt vmcnt(0)" ::: "memory");
  float* cbuf = (float*)smem;                       // 64 x 260 fp32 = 66560 B
  const int f4 = tid & 63;
  const int colg = nBase + f4 * 4;
  v4f bias4 = (v4f){0.f, 0.f, 0.f, 0.f};
  if (FINAL) bias4 = *(const v4f*)(bias + colg);
  #pragma unroll
  for (int h = 0; h < 4; ++h) {
    __syncthreads();
    if (wR2 == (h & 1)) {
      const int R = h >> 1;
      #pragma unroll
      for (int Cq = 0; Cq < 2; ++Cq)
        #pragma unroll
        for (int mi = 0; mi < 4; ++mi)
          #pragma unroll
          for (int ni = 0; ni < 2; ++ni)
            #pragma unroll
            for (int e = 0; e < 4; ++e)
              cbuf[(mi * 16 + quad * 4 + e) * 260 + Cq * 128 + wC4 * 32 + ni * 16 + l15] =
                  acc[R][Cq][mi][ni][e];
    }
    __syncthreads();
    #pragma unroll
    for (int i = 0; i < 8; ++i) {
      int rl  = i * 8 + (tid >> 6);
      int row = mBase + h * 64 + rl;
      if (row < N_NODES) {
        v4f v = *(const v4f*)(cbuf + rl * 260 + f4 * 4);
        size_t idx = (size_t)row * FEAT + colg;
        if (ACCUM) v += *(const v4f*)(C + idx);
        if (FINAL) {
          #pragma unroll
          for (int e = 0; e < 4; ++e) v[e] = fmaxf(v[e] + bias4[e], 0.f);
        }
        *(v4f*)(C + idx) = v;
      }
    }
  }
}

// ---------- legacy 128x128 GEMM (fallback path only) ----------
template <bool ACCUM, bool FINAL>
__global__ __launch_bounds__(256, 4)
void k_gemm(const __bf16* __restrict__ A, size_t slabStride,
            const __bf16* __restrict__ Wt, int wtStride, int kTiles,
            const float* __restrict__ bias, float* __restrict__ C,
            int mtBase, int mtEnd) {
  __shared__ __align__(16) char smem[33792];
  __bf16* As = (__bf16*)smem;
  __bf16* Bs = (__bf16*)(smem + 16384);

  const int tid  = threadIdx.x;
  const int wave = tid >> 6;
  const int lane = tid & 63;
  const int lr = lane >> 3, lc = lane & 7;
  const int gcs = (lc ^ lr) * 8;
  const int quad = lane >> 4, l15 = lane & 15;
  const int wRow = wave >> 1, wCol = wave & 1;

  const int panel = blockIdx.x >> 5;
  const int w32   = blockIdx.x & 31;
  const int mtile = mtBase + panel * 8 + (w32 & 7);
  const int ntile = w32 >> 3;
  if (mtile >= mtEnd) return;
  const int mBase = mtile * 128;
  const int nBase = ntile * 128;

  v4f acc[4][4];
  #pragma unroll
  for (int i = 0; i < 4; ++i)
    #pragma unroll
    for (int j = 0; j < 4; ++j) acc[i][j] = (v4f){0.f, 0.f, 0.f, 0.f};

  for (int kt = 0; kt < kTiles; ++kt) {
    const int kk = kt * 64;
    const __bf16* aT = A + (size_t)(kk >> 9) * slabStride + (kk & 511);
    #pragma unroll
    for (int t = 0; t < 4; ++t) {
      int chunk = wave * 4 + t;
      int row = mBase + chunk * 8 + lr;
      if (row > N_NODES - 1) row = N_NODES - 1;
      load_lds16(aT + (size_t)row * FEAT + gcs, As + chunk * 512);
      int n = nBase + chunk * 8 + lr;
      load_lds16(Wt + (size_t)n * wtStride + kk + gcs, Bs + chunk * 512);
    }
    __syncthreads();
    #pragma unroll
    for (int ks = 0; ks < 2; ++ks) {
      const int q = ks * 4 + quad;
      v8bf af[4], bfr[4];
      #pragma unroll
      for (int mi = 0; mi < 4; ++mi) {
        int m = wRow * 64 + mi * 16 + l15;
        af[mi] = *(const v8bf*)(As + m * 64 + ((q ^ (m & 7)) * 8));
      }
      #pragma unroll
      for (int ni = 0; ni < 4; ++ni) {
        int n = wCol * 64 + ni * 16 + l15;
        bfr[ni] = *(const v8bf*)(Bs + n * 64 + ((q ^ (n & 7)) * 8));
      }
      #pragma unroll
      for (int mi = 0; mi < 4; ++mi)
        #pragma unroll
        for (int ni = 0; ni < 4; ++ni)
          acc[mi][ni] = __builtin_amdgcn_mfma_f32_16x16x32_bf16(af[mi], bfr[ni], acc[mi][ni], 0, 0, 0);
    }
    __syncthreads();
  }

  float* cbuf = (float*)smem;
  const int f4c  = tid & 31;
  const int colg = nBase + f4c * 4;
  v4f bias4 = (v4f){0.f, 0.f, 0.f, 0.f};
  if (FINAL) bias4 = *(const v4f*)(bias + colg);
  #pragma unroll
  for (int h = 0; h < 2; ++h) {
    if (wRow == h) {
      #pragma unroll
      for (int mi = 0; mi < 4; ++mi) {
        int r0 = mi * 16 + quad * 4;
        #pragma unroll
        for (int ni = 0; ni < 4; ++ni) {
          int c = wCol * 64 + ni * 16 + l15;
          #pragma unroll
          for (int e = 0; e < 4; ++e)
            cbuf[(r0 + e) * 132 + c] = acc[mi][ni][e];
        }
      }
    }
    __syncthreads();
    #pragma unroll
    for (int i = 0; i < 8; ++i) {
      int rh  = (tid >> 5) + 8 * i;
      int row = mBase + h * 64 + rh;
      if (row < N_NODES) {
        v4f v = *(const v4f*)(cbuf + rh * 132 + f4c * 4);
        size_t idx = (size_t)row * FEAT + colg;
        if (ACCUM) v += *(const v4f*)(C + idx);
        if (FINAL) {
          #pragma unroll
          for (int e = 0; e < 4; ++e) v[e] = fmaxf(v[e] + bias4[e], 0.f);
        }
        *(v4f*)(C + idx) = v;
      }
    }
    __syncthreads();
  }
}

extern "C" void kernel_launch(void* const* d_in, const int* in_sizes, int n_in,
                              void* d_out, int out_size, void* d_ws, size_t ws_size,
                              hipStream_t stream) {
  const float* x    = (const float*)d_in[0];
  const float* w    = (const float*)d_in[1];
  const float* lw   = (const float*)d_in[2];
  const float* bias = (const float*)d_in[3];
  const int*   src  = (const int*)d_in[4];
  const int*   dst  = (const int*)d_in[5];
  float* out = (float*)d_out;

  char* ws = (char*)d_ws;
  const size_t SLAB  = (size_t)N_NODES * FEAT;              // elems per slab
  const size_t slabB = SLAB * 2;                            // 30.72 MB
  const size_t wtB   = (size_t)FEAT * KTOT * 2;             // 4.72 MB
  const size_t cntB  = (size_t)N_REL * N_NODES * 4;         // 0.96 MB
  const size_t slotB = (size_t)N_REL * N_NODES * CAP * 2;   // 15.36 MB (u16)
  const size_t fixedB = wtB + cntB + slotB;                 // 21.04 MB

  __bf16*         Wt     = (__bf16*)ws;
  int*            cnt    = (int*)(ws + wtB);
  unsigned short* slots  = (unsigned short*)(ws + wtB + cntB);
  __bf16*         slabs  = (__bf16*)(ws + fixedB);          // 16B-aligned

  int nSlab = (int)((ws_size - fixedB) / slabB);            // total slots incl. x slot
  int g = nSlab - 1;                                        // agg slabs avail
  if (g > 7) g = 7;
  if (g < 1) g = 1;
  __bf16* xbf = slabs + (size_t)g * SLAB;                   // slot g = x (bf16)

  hipMemsetAsync(cnt, 0, cntB, stream);
  k_prep<<<CONV_BLOCKS + TR_BLOCKS + CNT_BLOCKS, 256, 0, stream>>>(
      x, w, lw, src, dst, xbf, Wt, cnt, slots);

  if (g == 7) {
    const int mt256 = (N_NODES + 255) / 256;                // 118
    const int grid3 = mt256 * 2;                            // 236 blocks
    // pass1: rels 0..6 -> slots 0..6 via slice-major aggregate; K=3584 gemm.
    const int bps1 = (7 * N_NODES + 31) / 32;               // 6563
    k_agg_slice<<<8 * bps1, 256, 0, stream>>>(xbf, cnt, slots,
                                              slabs, 7 * N_NODES, bps1);
    k_gemm3<false, false><<<grid3, 512, 0, stream>>>(
        slabs, SLAB, Wt, 3584 / 64, bias, out);
    // pass2: rel 7 -> slot 6 (dead after gemm1); slots 6,7 = [rel7, x]
    // contiguous in memory and in Wt columns -> one K=1024 ACCUM+FINAL gemm.
    const int bps2 = (N_NODES + 31) / 32;                   // 938
    k_agg_slice<<<8 * bps2, 256, 0, stream>>>(
        xbf, cnt + 7 * N_NODES, slots + (size_t)7 * N_NODES * CAP,
        slabs + (size_t)6 * SLAB, N_NODES, bps2);
    k_gemm3<true, true><<<grid3, 512, 0, stream>>>(
        slabs + (size_t)6 * SLAB, SLAB, Wt + 3584, 1024 / 64, bias, out);
  } else {
    // defensive generic path (smaller workspace)
    const int nMtiles = (N_NODES + 127) / 128;
    const int gemmGrid = ((nMtiles + 7) / 8) * 32;
    for (int r0 = 0; r0 < N_REL; r0 += g) {
      int gc2 = (N_REL - r0) < g ? (N_REL - r0) : g;
      k_aggregate<<<(gc2 * N_NODES) / 4, 256, 0, stream>>>(
          xbf, cnt + r0 * N_NODES, slots + (size_t)r0 * N_NODES * CAP,
          slabs, gc2 * N_NODES);
      if (r0 == 0)
        k_gemm<false, false><<<gemmGrid, 256, 0, stream>>>(
            slabs, SLAB, Wt + r0 * 512, KTOT, gc2 * 8, bias, out, 0, nMtiles);
      else
        k_gemm<true, false><<<gemmGrid, 256, 0, stream>>>(
            slabs, SLAB, Wt + r0 * 512, KTOT, gc2 * 8, bias, out, 0, nMtiles);
    }
    k_gemm<true, true><<<gemmGrid, 256, 0, stream>>>(xbf, SLAB, Wt + 4096, KTOT,
                                                     8, bias, out, 0, nMtiles);
  }
}

// Round 9
// 498.198 us; speedup vs baseline: 1.1236x; 1.0017x over previous
//
#include <hip/hip_runtime.h>
#include <hip/hip_bf16.h>

#define N_NODES 30000
#define N_REL   8
#define N_EDGES 131072
#define FEAT    512
#define KTOT    4608   // 8*512 + 512
#define CAP     32

typedef __attribute__((ext_vector_type(8))) __bf16 v8bf;
typedef __attribute__((ext_vector_type(4))) __bf16 v4bf;
typedef __attribute__((ext_vector_type(4))) float  v4f;
typedef __attribute__((ext_vector_type(2))) float  f2;
typedef __attribute__((ext_vector_type(8))) unsigned short u16x8;

// ---------- async global->LDS (16B per lane, wave-uniform LDS base) ----------
static __device__ __forceinline__ void load_lds16(const void* g, void* l) {
  __builtin_amdgcn_global_load_lds(
      (const __attribute__((address_space(1))) void*)g,
      (__attribute__((address_space(3))) void*)l, 16, 0, 0);
}

// ---------- fused prep: convert x, transpose W, build buckets ----------
#define CONV_BLOCKS 15000
#define TR_BLOCKS   2304
#define CNT_BLOCKS  512
__global__ __launch_bounds__(256)
void k_prep(const float* __restrict__ x, const float* __restrict__ w,
            const float* __restrict__ lw, const int* __restrict__ src,
            const int* __restrict__ dst, __bf16* __restrict__ xbf,
            __bf16* __restrict__ Wt, int* __restrict__ cnt,
            unsigned short* __restrict__ slots) {
  __shared__ float t[32][33];
  const int b = blockIdx.x, tid = threadIdx.x;
  if (b < CONV_BLOCKS) {
    int i = b * 256 + tid;                          // 4 elems each
    float4 v = ((const float4*)x)[i];
    v4bf o;
    o[0] = (__bf16)v.x; o[1] = (__bf16)v.y; o[2] = (__bf16)v.z; o[3] = (__bf16)v.w;
    ((v4bf*)xbf)[i] = o;
  } else if (b < CONV_BLOCKS + TR_BLOCKS) {
    int tb = b - CONV_BLOCKS;
    int k0 = (tb % 144) * 32, n0 = (tb / 144) * 32;
    int tx = tid & 31, ty = tid >> 5;               // 32 x 8
    #pragma unroll
    for (int q = 0; q < 4; ++q) {
      int k = k0 + ty + q * 8, n = n0 + tx;
      float v = (k < 4096) ? w[(size_t)k * 512 + n] : lw[(size_t)(k - 4096) * 512 + n];
      t[ty + q * 8][tx] = v;
    }
    __syncthreads();
    #pragma unroll
    for (int q = 0; q < 4; ++q) {
      int n = n0 + ty + q * 8, k = k0 + tx;
      Wt[(size_t)n * KTOT + k] = (__bf16)t[tx][ty + q * 8];
    }
  } else {
    int cb  = b - CONV_BLOCKS - TR_BLOCKS;          // 0..511
    int rel = cb & 7;                               // XCD-affine rel
    int q   = cb >> 3;                              // 0..63 within rel
    int e0  = rel * N_EDGES + (q * 256 + tid) * 8;  // 8 edges, same rel
    int4 sa = *(const int4*)(src + e0), sb = *(const int4*)(src + e0 + 4);
    int4 da = *(const int4*)(dst + e0), db = *(const int4*)(dst + e0 + 4);
    int ss[8] = {sa.x, sa.y, sa.z, sa.w, sb.x, sb.y, sb.z, sb.w};
    int dd[8] = {da.x, da.y, da.z, da.w, db.x, db.y, db.z, db.w};
    int bb[8], pp[8];
    #pragma unroll
    for (int j = 0; j < 8; ++j) {
      bb[j] = rel * N_NODES + dd[j];
      pp[j] = atomicAdd(&cnt[bb[j]], 1);
    }
    #pragma unroll
    for (int j = 0; j < 8; ++j)
      if (pp[j] < CAP) slots[(size_t)bb[j] * CAP + pp[j]] = (unsigned short)ss[j];
  }
}

// ---------- slice aggregation: 8 feature-slices of 64 cols (r8-proven) ----------
__global__ __launch_bounds__(256)
void k_agg_slice(const __bf16* __restrict__ xbf, const int* __restrict__ cnt,
                 const unsigned short* __restrict__ slots,
                 __bf16* __restrict__ out, int nBuckets, int bps) {
  const int bid   = blockIdx.x;
  const int slice = bid / bps;                      // 0..7
  const int ib    = bid - slice * bps;
  const int tid   = threadIdx.x;
  const int wave  = tid >> 6, lane = tid & 63;
  const int grp   = lane >> 3;                      // bucket group within wave
  const int li    = lane & 7;                       // lane within group
  const int w     = ib * 32 + wave * 8 + grp;
  const bool valid = (w < nBuckets);

  int c = 0;
  u16x8 qs[4];
  if (valid) {
    c = cnt[w];
    const unsigned short* sl = slots + (size_t)w * CAP;
    qs[0] = *(const u16x8*)(sl);                    // 64B line broadcast/group
    qs[1] = *(const u16x8*)(sl + 8);
    qs[2] = *(const u16x8*)(sl + 16);
    qs[3] = *(const u16x8*)(sl + 24);
  }
  int cc = c < CAP ? c : CAP;
  int cmax = cc;                                    // wave-max across groups
  cmax = max(cmax, __shfl_xor(cmax, 8));
  cmax = max(cmax, __shfl_xor(cmax, 16));
  cmax = max(cmax, __shfl_xor(cmax, 32));

  const __bf16* xb = xbf + slice * 64 + (size_t)li * 8;
  f2 acc2[4];
  #pragma unroll
  for (int p = 0; p < 4; ++p) acc2[p] = (f2){0.f, 0.f};
  #pragma unroll
  for (int g = 0; g < 4; ++g) {
    if (cmax > g * 8) {                             // wave-uniform
      v8bf r[8];
      #pragma unroll
      for (int j = 0; j < 8; ++j)
        if (cc > g * 8 + j)                         // group-predicated load
          r[j] = *(const v8bf*)(xb + (size_t)qs[g][j] * FEAT);
      #pragma unroll
      for (int j = 0; j < 8; ++j)
        if (cc > g * 8 + j) {
          const unsigned* ru = (const unsigned*)&r[j];
          #pragma unroll
          for (int p = 0; p < 4; ++p) {
            f2 v;
            v[0] = __uint_as_float(ru[p] << 16);           // lo bf16 -> f32
            v[1] = __uint_as_float(ru[p] & 0xffff0000u);   // hi bf16 -> f32
            acc2[p] += v;                                   // v_pk_add_f32
          }
        }
    }
  }
  if (valid) {
    float scale = 1.0f / (float)(c > 1 ? c : 1);
    v8bf o;
    #pragma unroll
    for (int p = 0; p < 4; ++p) {
      o[2 * p]     = (__bf16)(acc2[p][0] * scale);
      o[2 * p + 1] = (__bf16)(acc2[p][1] * scale);
    }
    *(v8bf*)(out + (size_t)w * FEAT + slice * 64 + (size_t)li * 8) = o;
  }
}

// ---------- legacy aggregation (fallback path only) ----------
__global__ __launch_bounds__(256)
void k_aggregate(const __bf16* __restrict__ xbf, const int* __restrict__ cnt,
                 const unsigned short* __restrict__ slots,
                 __bf16* __restrict__ out, int nBuckets) {
  int w = (blockIdx.x * blockDim.x + threadIdx.x) >> 6;
  int lane = threadIdx.x & 63;
  if (w >= nBuckets) return;
  const unsigned short* sl = slots + (size_t)w * CAP;
  u16x8 qs[4];
  qs[0] = *(const u16x8*)(sl);
  qs[1] = *(const u16x8*)(sl + 8);
  qs[2] = *(const u16x8*)(sl + 16);
  qs[3] = *(const u16x8*)(sl + 24);
  int c = cnt[w];
  int cc = c < CAP ? c : CAP;
  const __bf16* xb = xbf + (size_t)lane * 8;
  f2 acc2[4];
  #pragma unroll
  for (int p = 0; p < 4; ++p) acc2[p] = (f2){0.f, 0.f};
  #pragma unroll
  for (int g = 0; g < 4; ++g) {
    if (cc > g * 8) {
      int m = cc - g * 8;
      v8bf r[8];
      #pragma unroll
      for (int j = 0; j < 8; ++j)
        if (m > j) r[j] = *(const v8bf*)(xb + (size_t)qs[g][j] * FEAT);
      #pragma unroll
      for (int j = 0; j < 8; ++j)
        if (m > j) {
          const unsigned* ru = (const unsigned*)&r[j];
          #pragma unroll
          for (int p = 0; p < 4; ++p) {
            f2 v;
            v[0] = __uint_as_float(ru[p] << 16);
            v[1] = __uint_as_float(ru[p] & 0xffff0000u);
            acc2[p] += v;
          }
        }
    }
  }
  float scale = 1.0f / (float)(c > 1 ? c : 1);
  v8bf o;
  #pragma unroll
  for (int p = 0; p < 4; ++p) {
    o[2 * p]     = (__bf16)(acc2[p][0] * scale);
    o[2 * p + 1] = (__bf16)(acc2[p][1] * scale);
  }
  *(v8bf*)(out + (size_t)w * FEAT + lane * 8) = o;
}

// ---------- GEMM v3: 256x256 tile, BK=64, 8 waves, 8-phase counted-vmcnt ----
// r9: asymmetric prefetch depth. A (HBM, ~900cy) staged 2 tiles ahead into
// 3 rotating slots; B (Wt, L2-resident ~200cy) 1 ahead into 2 slots.
// LDS = 3*32KB A + 2*32KB B = 160 KiB exactly. Per-tile issue order is
// B(t+1) at p0/p1 then A(t+2) at p2/p3, so the per-wave FIFO has fast B
// loads ahead of slow A loads. Steady-state waits (derived from the FIFO
// ledger): W0 = vmcnt(6) (forces stB1(t), issued 3 phases prior);
// W3 = vmcnt(6) (forces A(t+1) issued 5-6 phases prior ~900-1200cy, and
// stB0(t+1)). Tail: W3 -> vmcnt(2) when no A(t+2) issued; W0 -> vmcnt(0)
// on the last tile. p1/p2 trailing barriers need no vmcnt (their reads are
// covered by the previous W3/W0 + barrier).
#define A_SLOT_E 16384   // 256x64 bf16 elems = 32 KB
#define B_BASE_E 49152   // after 3 A slots

template <bool ACCUM, bool FINAL>
__global__ __launch_bounds__(512, 2)
void k_gemm3(const __bf16* __restrict__ A, size_t slabStride,
             const __bf16* __restrict__ Wt, int kTiles,
             const float* __restrict__ bias, float* __restrict__ C) {
  __shared__ __align__(16) char smem[163840];       // full 160 KiB LDS
  __bf16* lds = (__bf16*)smem;

  const int tid  = threadIdx.x;
  const int wave = tid >> 6, lane = tid & 63;
  const int lr = lane >> 3, lc = lane & 7;
  const int gcs = (lc ^ lr) * 8;               // pre-swizzled global chunk
  const int quad = lane >> 4, l15 = lane & 15;
  const int wR2 = wave >> 2;                   // row band (64) within quadrant
  const int wC4 = wave & 3;                    // col band (32) within quadrant

  // bijective XCD swizzle (m204)
  const int nwg = gridDim.x;
  const int qq = nwg >> 3, rr = nwg & 7;
  const int xcd = blockIdx.x & 7, oidx = blockIdx.x >> 3;
  const int wg = (xcd < rr ? xcd * (qq + 1) : rr * (qq + 1) + (xcd - rr) * qq) + oidx;
  const int mtile = wg >> 1, ntile = wg & 1;
  const int mBase = mtile * 256, nBase = ntile * 256;

  v4f acc[2][2][4][2];
  #pragma unroll
  for (int a = 0; a < 2; ++a)
    #pragma unroll
    for (int bq = 0; bq < 2; ++bq)
      #pragma unroll
      for (int mi = 0; mi < 4; ++mi)
        #pragma unroll
        for (int ni = 0; ni < 2; ++ni)
          acc[a][bq][mi][ni] = (v4f){0.f, 0.f, 0.f, 0.f};

  // stage one half-tile (128 rows x 64 k) = 2 global_load_lds per wave
  auto stageA = [&](int t, int h) {
    __bf16* dst = lds + (t % 3) * A_SLOT_E;
    const int kk = t * 64;
    const __bf16* base = A + (size_t)(kk >> 9) * slabStride + (kk & 511);
    #pragma unroll
    for (int r2 = 0; r2 < 2; ++r2) {
      int rt = h * 128 + r2 * 64 + wave * 8;   // wave-uniform row base in tile
      int row = mBase + rt + lr;
      if (row > N_NODES - 1) row = N_NODES - 1;
      load_lds16(base + (size_t)row * FEAT + gcs, dst + rt * 64);
    }
  };
  auto stageB = [&](int t, int h) {
    __bf16* dst = lds + B_BASE_E + (t & 1) * A_SLOT_E;
    const int kk = t * 64;
    #pragma unroll
    for (int r2 = 0; r2 < 2; ++r2) {
      int rt = h * 128 + r2 * 64 + wave * 8;
      int n = nBase + rt + lr;
      load_lds16(Wt + (size_t)n * KTOT + kk + gcs, dst + rt * 64);
    }
  };

  // ---- prologue: A(0) pair, B(0) pair, A(1) pair; vmcnt(4) leaves A(1)
  // in flight and forces A(0),B(0). ----
  stageA(0, 0); stageA(0, 1);
  stageB(0, 0); stageB(0, 1);
  if (kTiles > 1) {
    stageA(1, 0); stageA(1, 1);
    asm volatile("s_waitcnt vmcnt(4)" ::: "memory");
  } else {
    asm volatile("s_waitcnt vmcnt(0)" ::: "memory");
  }
  __builtin_amdgcn_s_barrier();
  __builtin_amdgcn_sched_barrier(0);

  for (int t = 0; t < kTiles; ++t) {
    const __bf16* sA = lds + (t % 3) * A_SLOT_E;
    const __bf16* sB = lds + B_BASE_E + (t & 1) * A_SLOT_E;
    const bool pfB = (t + 1) < kTiles;
    const bool pfA = (t + 2) < kTiles;
    v8bf af[4][2], bf0[2][2], bf1[2][2];

    // ---- p0: quadrant (0,0); read A0(t),B0(t); stage B0(t+1) ----
    #pragma unroll
    for (int mi = 0; mi < 4; ++mi)
      #pragma unroll
      for (int ks = 0; ks < 2; ++ks) {
        int m = wR2 * 64 + mi * 16 + l15;
        int q = ks * 4 + quad;
        af[mi][ks] = *(const v8bf*)(sA + m * 64 + ((q ^ (m & 7)) * 8));
      }
    #pragma unroll
    for (int ni = 0; ni < 2; ++ni)
      #pragma unroll
      for (int ks = 0; ks < 2; ++ks) {
        int n = wC4 * 32 + ni * 16 + l15;
        int q = ks * 4 + quad;
        bf0[ni][ks] = *(const v8bf*)(sB + n * 64 + ((q ^ (n & 7)) * 8));
      }
    if (pfB) stageB(t + 1, 0);
    __builtin_amdgcn_s_barrier();
    asm volatile("s_waitcnt lgkmcnt(0)" ::: "memory");
    __builtin_amdgcn_sched_barrier(0);
    __builtin_amdgcn_s_setprio(1);
    #pragma unroll
    for (int ks = 0; ks < 2; ++ks)
      #pragma unroll
      for (int mi = 0; mi < 4; ++mi)
        #pragma unroll
        for (int ni = 0; ni < 2; ++ni)
          acc[0][0][mi][ni] = __builtin_amdgcn_mfma_f32_16x16x32_bf16(
              af[mi][ks], bf0[ni][ks], acc[0][0][mi][ni], 0, 0, 0);
    __builtin_amdgcn_s_setprio(0);
    if (pfB) asm volatile("s_waitcnt vmcnt(6)" ::: "memory");  // stB1(t) landed
    else     asm volatile("s_waitcnt vmcnt(0)" ::: "memory");  // last tile drain
    __builtin_amdgcn_s_barrier();
    __builtin_amdgcn_sched_barrier(0);

    // ---- p1: quadrant (0,1); read B1(t); stage B1(t+1) ----
    #pragma unroll
    for (int ni = 0; ni < 2; ++ni)
      #pragma unroll
      for (int ks = 0; ks < 2; ++ks) {
        int n = 128 + wC4 * 32 + ni * 16 + l15;
        int q = ks * 4 + quad;
        bf1[ni][ks] = *(const v8bf*)(sB + n * 64 + ((q ^ (n & 7)) * 8));
      }
    if (pfB) stageB(t + 1, 1);
    __builtin_amdgcn_s_barrier();
    asm volatile("s_waitcnt lgkmcnt(0)" ::: "memory");
    __builtin_amdgcn_sched_barrier(0);
    __builtin_amdgcn_s_setprio(1);
    #pragma unroll
    for (int ks = 0; ks < 2; ++ks)
      #pragma unroll
      for (int mi = 0; mi < 4; ++mi)
        #pragma unroll
        for (int ni = 0; ni < 2; ++ni)
          acc[0][1][mi][ni] = __builtin_amdgcn_mfma_f32_16x16x32_bf16(
              af[mi][ks], bf1[ni][ks], acc[0][1][mi][ni], 0, 0, 0);
    __builtin_amdgcn_s_setprio(0);
    __builtin_amdgcn_s_barrier();                   // no vmcnt: p2's A1(t)
    __builtin_amdgcn_sched_barrier(0);              // covered by prior W3

    // ---- p2: quadrant (1,1); read A1(t); stage A0(t+2) ----
    #pragma unroll
    for (int mi = 0; mi < 4; ++mi)
      #pragma unroll
      for (int ks = 0; ks < 2; ++ks) {
        int m = 128 + wR2 * 64 + mi * 16 + l15;
        int q = ks * 4 + quad;
        af[mi][ks] = *(const v8bf*)(sA + m * 64 + ((q ^ (m & 7)) * 8));
      }
    if (pfA) stageA(t + 2, 0);
    __builtin_amdgcn_s_barrier();
    asm volatile("s_waitcnt lgkmcnt(0)" ::: "memory");
    __builtin_amdgcn_sched_barrier(0);
    __builtin_amdgcn_s_setprio(1);
    #pragma unroll
    for (int ks = 0; ks < 2; ++ks)
      #pragma unroll
      for (int mi = 0; mi < 4; ++mi)
        #pragma unroll
        for (int ni = 0; ni < 2; ++ni)
          acc[1][1][mi][ni] = __builtin_amdgcn_mfma_f32_16x16x32_bf16(
              af[mi][ks], bf1[ni][ks], acc[1][1][mi][ni], 0, 0, 0);
    __builtin_amdgcn_s_setprio(0);
    __builtin_amdgcn_s_barrier();                   // p3 reads no LDS: no vmcnt
    __builtin_amdgcn_sched_barrier(0);

    // ---- p3: quadrant (1,0); reuse af(A1), bf0; stage A1(t+2) ----
    if (pfA) stageA(t + 2, 1);
    __builtin_amdgcn_s_barrier();
    __builtin_amdgcn_s_setprio(1);
    #pragma unroll
    for (int ks = 0; ks < 2; ++ks)
      #pragma unroll
      for (int mi = 0; mi < 4; ++mi)
        #pragma unroll
        for (int ni = 0; ni < 2; ++ni)
          acc[1][0][mi][ni] = __builtin_amdgcn_mfma_f32_16x16x32_bf16(
              af[mi][ks], bf0[ni][ks], acc[1][0][mi][ni], 0, 0, 0);
    __builtin_amdgcn_s_setprio(0);
    // W3: force A(t+1) (issued 5-6 phases ago) + stB0(t+1); leave youngest
    // {stB1(t+1), A(t+2)} in flight.
    if (pfA)      asm volatile("s_waitcnt vmcnt(6)" ::: "memory");
    else if (pfB) asm volatile("s_waitcnt vmcnt(2)" ::: "memory");
    __builtin_amdgcn_s_barrier();
    __builtin_amdgcn_sched_barrier(0);
  }

  // ---- epilogue: 4 rounds of 64 rows via LDS (stride 260: 2-way = free),
  // full-line float4 stores ----
  asm volatile("s_waitcnt vmcnt(0)" ::: "memory");
  float* cbuf = (float*)smem;                       // 64 x 260 fp32 = 66560 B
  const int f4 = tid & 63;
  const int colg = nBase + f4 * 4;
  v4f bias4 = (v4f){0.f, 0.f, 0.f, 0.f};
  if (FINAL) bias4 = *(const v4f*)(bias + colg);
  #pragma unroll
  for (int h = 0; h < 4; ++h) {
    __syncthreads();
    if (wR2 == (h & 1)) {
      const int R = h >> 1;
      #pragma unroll
      for (int Cq = 0; Cq < 2; ++Cq)
        #pragma unroll
        for (int mi = 0; mi < 4; ++mi)
          #pragma unroll
          for (int ni = 0; ni < 2; ++ni)
            #pragma unroll
            for (int e = 0; e < 4; ++e)
              cbuf[(mi * 16 + quad * 4 + e) * 260 + Cq * 128 + wC4 * 32 + ni * 16 + l15] =
                  acc[R][Cq][mi][ni][e];
    }
    __syncthreads();
    #pragma unroll
    for (int i = 0; i < 8; ++i) {
      int rl  = i * 8 + (tid >> 6);
      int row = mBase + h * 64 + rl;
      if (row < N_NODES) {
        v4f v = *(const v4f*)(cbuf + rl * 260 + f4 * 4);
        size_t idx = (size_t)row * FEAT + colg;
        if (ACCUM) v += *(const v4f*)(C + idx);
        if (FINAL) {
          #pragma unroll
          for (int e = 0; e < 4; ++e) v[e] = fmaxf(v[e] + bias4[e], 0.f);
        }
        *(v4f*)(C + idx) = v;
      }
    }
  }
}

// ---------- legacy 128x128 GEMM (fallback path only) ----------
template <bool ACCUM, bool FINAL>
__global__ __launch_bounds__(256, 4)
void k_gemm(const __bf16* __restrict__ A, size_t slabStride,
            const __bf16* __restrict__ Wt, int wtStride, int kTiles,
            const float* __restrict__ bias, float* __restrict__ C,
            int mtBase, int mtEnd) {
  __shared__ __align__(16) char smem[33792];
  __bf16* As = (__bf16*)smem;
  __bf16* Bs = (__bf16*)(smem + 16384);

  const int tid  = threadIdx.x;
  const int wave = tid >> 6;
  const int lane = tid & 63;
  const int lr = lane >> 3, lc = lane & 7;
  const int gcs = (lc ^ lr) * 8;
  const int quad = lane >> 4, l15 = lane & 15;
  const int wRow = wave >> 1, wCol = wave & 1;

  const int panel = blockIdx.x >> 5;
  const int w32   = blockIdx.x & 31;
  const int mtile = mtBase + panel * 8 + (w32 & 7);
  const int ntile = w32 >> 3;
  if (mtile >= mtEnd) return;
  const int mBase = mtile * 128;
  const int nBase = ntile * 128;

  v4f acc[4][4];
  #pragma unroll
  for (int i = 0; i < 4; ++i)
    #pragma unroll
    for (int j = 0; j < 4; ++j) acc[i][j] = (v4f){0.f, 0.f, 0.f, 0.f};

  for (int kt = 0; kt < kTiles; ++kt) {
    const int kk = kt * 64;
    const __bf16* aT = A + (size_t)(kk >> 9) * slabStride + (kk & 511);
    #pragma unroll
    for (int t = 0; t < 4; ++t) {
      int chunk = wave * 4 + t;
      int row = mBase + chunk * 8 + lr;
      if (row > N_NODES - 1) row = N_NODES - 1;
      load_lds16(aT + (size_t)row * FEAT + gcs, As + chunk * 512);
      int n = nBase + chunk * 8 + lr;
      load_lds16(Wt + (size_t)n * wtStride + kk + gcs, Bs + chunk * 512);
    }
    __syncthreads();
    #pragma unroll
    for (int ks = 0; ks < 2; ++ks) {
      const int q = ks * 4 + quad;
      v8bf af[4], bfr[4];
      #pragma unroll
      for (int mi = 0; mi < 4; ++mi) {
        int m = wRow * 64 + mi * 16 + l15;
        af[mi] = *(const v8bf*)(As + m * 64 + ((q ^ (m & 7)) * 8));
      }
      #pragma unroll
      for (int ni = 0; ni < 4; ++ni) {
        int n = wCol * 64 + ni * 16 + l15;
        bfr[ni] = *(const v8bf*)(Bs + n * 64 + ((q ^ (n & 7)) * 8));
      }
      #pragma unroll
      for (int mi = 0; mi < 4; ++mi)
        #pragma unroll
        for (int ni = 0; ni < 4; ++ni)
          acc[mi][ni] = __builtin_amdgcn_mfma_f32_16x16x32_bf16(af[mi], bfr[ni], acc[mi][ni], 0, 0, 0);
    }
    __syncthreads();
  }

  float* cbuf = (float*)smem;
  const int f4c  = tid & 31;
  const int colg = nBase + f4c * 4;
  v4f bias4 = (v4f){0.f, 0.f, 0.f, 0.f};
  if (FINAL) bias4 = *(const v4f*)(bias + colg);
  #pragma unroll
  for (int h = 0; h < 2; ++h) {
    if (wRow == h) {
      #pragma unroll
      for (int mi = 0; mi < 4; ++mi) {
        int r0 = mi * 16 + quad * 4;
        #pragma unroll
        for (int ni = 0; ni < 4; ++ni) {
          int c = wCol * 64 + ni * 16 + l15;
          #pragma unroll
          for (int e = 0; e < 4; ++e)
            cbuf[(r0 + e) * 132 + c] = acc[mi][ni][e];
        }
      }
    }
    __syncthreads();
    #pragma unroll
    for (int i = 0; i < 8; ++i) {
      int rh  = (tid >> 5) + 8 * i;
      int row = mBase + h * 64 + rh;
      if (row < N_NODES) {
        v4f v = *(const v4f*)(cbuf + rh * 132 + f4c * 4);
        size_t idx = (size_t)row * FEAT + colg;
        if (ACCUM) v += *(const v4f*)(C + idx);
        if (FINAL) {
          #pragma unroll
          for (int e = 0; e < 4; ++e) v[e] = fmaxf(v[e] + bias4[e], 0.f);
        }
        *(v4f*)(C + idx) = v;
      }
    }
    __syncthreads();
  }
}

extern "C" void kernel_launch(void* const* d_in, const int* in_sizes, int n_in,
                              void* d_out, int out_size, void* d_ws, size_t ws_size,
                              hipStream_t stream) {
  const float* x    = (const float*)d_in[0];
  const float* w    = (const float*)d_in[1];
  const float* lw   = (const float*)d_in[2];
  const float* bias = (const float*)d_in[3];
  const int*   src  = (const int*)d_in[4];
  const int*   dst  = (const int*)d_in[5];
  float* out = (float*)d_out;

  char* ws = (char*)d_ws;
  const size_t SLAB  = (size_t)N_NODES * FEAT;              // elems per slab
  const size_t slabB = SLAB * 2;                            // 30.72 MB
  const size_t wtB   = (size_t)FEAT * KTOT * 2;             // 4.72 MB
  const size_t cntB  = (size_t)N_REL * N_NODES * 4;         // 0.96 MB
  const size_t slotB = (size_t)N_REL * N_NODES * CAP * 2;   // 15.36 MB (u16)
  const size_t fixedB = wtB + cntB + slotB;                 // 21.04 MB

  __bf16*         Wt     = (__bf16*)ws;
  int*            cnt    = (int*)(ws + wtB);
  unsigned short* slots  = (unsigned short*)(ws + wtB + cntB);
  __bf16*         slabs  = (__bf16*)(ws + fixedB);          // 16B-aligned

  int nSlab = (int)((ws_size - fixedB) / slabB);            // total slots incl. x slot
  int g = nSlab - 1;                                        // agg slabs avail
  if (g > 7) g = 7;
  if (g < 1) g = 1;
  __bf16* xbf = slabs + (size_t)g * SLAB;                   // slot g = x (bf16)

  hipMemsetAsync(cnt, 0, cntB, stream);
  k_prep<<<CONV_BLOCKS + TR_BLOCKS + CNT_BLOCKS, 256, 0, stream>>>(
      x, w, lw, src, dst, xbf, Wt, cnt, slots);

  if (g == 7) {
    const int mt256 = (N_NODES + 255) / 256;                // 118
    const int grid3 = mt256 * 2;                            // 236 blocks
    // pass1: rels 0..6 -> slots 0..6 via slice-major aggregate; K=3584 gemm.
    const int bps1 = (7 * N_NODES + 31) / 32;               // 6563
    k_agg_slice<<<8 * bps1, 256, 0, stream>>>(xbf, cnt, slots,
                                              slabs, 7 * N_NODES, bps1);
    k_gemm3<false, false><<<grid3, 512, 0, stream>>>(
        slabs, SLAB, Wt, 3584 / 64, bias, out);
    // pass2: rel 7 -> slot 6 (dead after gemm1); slots 6,7 = [rel7, x]
    // contiguous in memory and in Wt columns -> one K=1024 ACCUM+FINAL gemm.
    const int bps2 = (N_NODES + 31) / 32;                   // 938
    k_agg_slice<<<8 * bps2, 256, 0, stream>>>(
        xbf, cnt + 7 * N_NODES, slots + (size_t)7 * N_NODES * CAP,
        slabs + (size_t)6 * SLAB, N_NODES, bps2);
    k_gemm3<true, true><<<grid3, 512, 0, stream>>>(
        slabs + (size_t)6 * SLAB, SLAB, Wt + 3584, 1024 / 64, bias, out);
  } else {
    // defensive generic path (smaller workspace)
    const int nMtiles = (N_NODES + 127) / 128;
    const int gemmGrid = ((nMtiles + 7) / 8) * 32;
    for (int r0 = 0; r0 < N_REL; r0 += g) {
      int gc2 = (N_REL - r0) < g ? (N_REL - r0) : g;
      k_aggregate<<<(gc2 * N_NODES) / 4, 256, 0, stream>>>(
          xbf, cnt + r0 * N_NODES, slots + (size_t)r0 * N_NODES * CAP,
          slabs, gc2 * N_NODES);
      if (r0 == 0)
        k_gemm<false, false><<<gemmGrid, 256, 0, stream>>>(
            slabs, SLAB, Wt + r0 * 512, KTOT, gc2 * 8, bias, out, 0, nMtiles);
      else
        k_gemm<true, false><<<gemmGrid, 256, 0, stream>>>(
            slabs, SLAB, Wt + r0 * 512, KTOT, gc2 * 8, bias, out, 0, nMtiles);
    }
    k_gemm<true, true><<<gemmGrid, 256, 0, stream>>>(xbf, SLAB, Wt + 4096, KTOT,
                                                     8, bias, out, 0, nMtiles);
  }
}

// Round 10
// 479.068 us; speedup vs baseline: 1.1685x; 1.0399x over previous
//
#include <hip/hip_runtime.h>
#include <hip/hip_bf16.h>

#define N_NODES 30000
#define N_REL   8
#define N_EDGES 131072
#define FEAT    512
#define KTOT    4608   // 8*512 + 512
#define CAP     32

typedef __attribute__((ext_vector_type(8))) __bf16 v8bf;
typedef __attribute__((ext_vector_type(4))) __bf16 v4bf;
typedef __attribute__((ext_vector_type(4))) float  v4f;
typedef __attribute__((ext_vector_type(2))) float  f2;
typedef __attribute__((ext_vector_type(8))) unsigned short u16x8;

// ---------- async global->LDS (16B per lane, wave-uniform LDS base) ----------
static __device__ __forceinline__ void load_lds16(const void* g, void* l) {
  __builtin_amdgcn_global_load_lds(
      (const __attribute__((address_space(1))) void*)g,
      (__attribute__((address_space(3))) void*)l, 16, 0, 0);
}

// ---------- fused prep: convert x, transpose W, build buckets ----------
#define CONV_BLOCKS 15000
#define TR_BLOCKS   2304
#define CNT_BLOCKS  512
__global__ __launch_bounds__(256)
void k_prep(const float* __restrict__ x, const float* __restrict__ w,
            const float* __restrict__ lw, const int* __restrict__ src,
            const int* __restrict__ dst, __bf16* __restrict__ xbf,
            __bf16* __restrict__ Wt, int* __restrict__ cnt,
            unsigned short* __restrict__ slots) {
  __shared__ float t[32][33];
  const int b = blockIdx.x, tid = threadIdx.x;
  if (b < CONV_BLOCKS) {
    int i = b * 256 + tid;                          // 4 elems each
    float4 v = ((const float4*)x)[i];
    v4bf o;
    o[0] = (__bf16)v.x; o[1] = (__bf16)v.y; o[2] = (__bf16)v.z; o[3] = (__bf16)v.w;
    ((v4bf*)xbf)[i] = o;
  } else if (b < CONV_BLOCKS + TR_BLOCKS) {
    int tb = b - CONV_BLOCKS;
    int k0 = (tb % 144) * 32, n0 = (tb / 144) * 32;
    int tx = tid & 31, ty = tid >> 5;               // 32 x 8
    #pragma unroll
    for (int q = 0; q < 4; ++q) {
      int k = k0 + ty + q * 8, n = n0 + tx;
      float v = (k < 4096) ? w[(size_t)k * 512 + n] : lw[(size_t)(k - 4096) * 512 + n];
      t[ty + q * 8][tx] = v;
    }
    __syncthreads();
    #pragma unroll
    for (int q = 0; q < 4; ++q) {
      int n = n0 + ty + q * 8, k = k0 + tx;
      Wt[(size_t)n * KTOT + k] = (__bf16)t[tx][ty + q * 8];
    }
  } else {
    int cb  = b - CONV_BLOCKS - TR_BLOCKS;          // 0..511
    int rel = cb & 7;                               // XCD-affine rel
    int q   = cb >> 3;                              // 0..63 within rel
    int e0  = rel * N_EDGES + (q * 256 + tid) * 8;  // 8 edges, same rel
    int4 sa = *(const int4*)(src + e0), sb = *(const int4*)(src + e0 + 4);
    int4 da = *(const int4*)(dst + e0), db = *(const int4*)(dst + e0 + 4);
    int ss[8] = {sa.x, sa.y, sa.z, sa.w, sb.x, sb.y, sb.z, sb.w};
    int dd[8] = {da.x, da.y, da.z, da.w, db.x, db.y, db.z, db.w};
    int bb[8], pp[8];
    #pragma unroll
    for (int j = 0; j < 8; ++j) {
      bb[j] = rel * N_NODES + dd[j];
      pp[j] = atomicAdd(&cnt[bb[j]], 1);
    }
    #pragma unroll
    for (int j = 0; j < 8; ++j)
      if (pp[j] < CAP) slots[(size_t)bb[j] * CAP + pp[j]] = (unsigned short)ss[j];
  }
}

// ---------- slice aggregation: 8 feature-slices of 64 cols (r8-proven) ----------
__global__ __launch_bounds__(256)
void k_agg_slice(const __bf16* __restrict__ xbf, const int* __restrict__ cnt,
                 const unsigned short* __restrict__ slots,
                 __bf16* __restrict__ out, int nBuckets, int bps) {
  const int bid   = blockIdx.x;
  const int slice = bid / bps;                      // 0..7
  const int ib    = bid - slice * bps;
  const int tid   = threadIdx.x;
  const int wave  = tid >> 6, lane = tid & 63;
  const int grp   = lane >> 3;                      // bucket group within wave
  const int li    = lane & 7;                       // lane within group
  const int w     = ib * 32 + wave * 8 + grp;
  const bool valid = (w < nBuckets);

  int c = 0;
  u16x8 qs[4];
  if (valid) {
    c = cnt[w];
    const unsigned short* sl = slots + (size_t)w * CAP;
    qs[0] = *(const u16x8*)(sl);                    // 64B line broadcast/group
    qs[1] = *(const u16x8*)(sl + 8);
    qs[2] = *(const u16x8*)(sl + 16);
    qs[3] = *(const u16x8*)(sl + 24);
  }
  int cc = c < CAP ? c : CAP;
  int cmax = cc;                                    // wave-max across groups
  cmax = max(cmax, __shfl_xor(cmax, 8));
  cmax = max(cmax, __shfl_xor(cmax, 16));
  cmax = max(cmax, __shfl_xor(cmax, 32));

  const __bf16* xb = xbf + slice * 64 + (size_t)li * 8;
  f2 acc2[4];
  #pragma unroll
  for (int p = 0; p < 4; ++p) acc2[p] = (f2){0.f, 0.f};
  #pragma unroll
  for (int g = 0; g < 4; ++g) {
    if (cmax > g * 8) {                             // wave-uniform
      v8bf r[8];
      #pragma unroll
      for (int j = 0; j < 8; ++j)
        if (cc > g * 8 + j)                         // group-predicated load
          r[j] = *(const v8bf*)(xb + (size_t)qs[g][j] * FEAT);
      #pragma unroll
      for (int j = 0; j < 8; ++j)
        if (cc > g * 8 + j) {
          const unsigned* ru = (const unsigned*)&r[j];
          #pragma unroll
          for (int p = 0; p < 4; ++p) {
            f2 v;
            v[0] = __uint_as_float(ru[p] << 16);           // lo bf16 -> f32
            v[1] = __uint_as_float(ru[p] & 0xffff0000u);   // hi bf16 -> f32
            acc2[p] += v;                                   // v_pk_add_f32
          }
        }
    }
  }
  if (valid) {
    float scale = 1.0f / (float)(c > 1 ? c : 1);
    v8bf o;
    #pragma unroll
    for (int p = 0; p < 4; ++p) {
      o[2 * p]     = (__bf16)(acc2[p][0] * scale);
      o[2 * p + 1] = (__bf16)(acc2[p][1] * scale);
    }
    *(v8bf*)(out + (size_t)w * FEAT + slice * 64 + (size_t)li * 8) = o;
  }
}

// ---------- legacy aggregation (fallback path only) ----------
__global__ __launch_bounds__(256)
void k_aggregate(const __bf16* __restrict__ xbf, const int* __restrict__ cnt,
                 const unsigned short* __restrict__ slots,
                 __bf16* __restrict__ out, int nBuckets) {
  int w = (blockIdx.x * blockDim.x + threadIdx.x) >> 6;
  int lane = threadIdx.x & 63;
  if (w >= nBuckets) return;
  const unsigned short* sl = slots + (size_t)w * CAP;
  u16x8 qs[4];
  qs[0] = *(const u16x8*)(sl);
  qs[1] = *(const u16x8*)(sl + 8);
  qs[2] = *(const u16x8*)(sl + 16);
  qs[3] = *(const u16x8*)(sl + 24);
  int c = cnt[w];
  int cc = c < CAP ? c : CAP;
  const __bf16* xb = xbf + (size_t)lane * 8;
  f2 acc2[4];
  #pragma unroll
  for (int p = 0; p < 4; ++p) acc2[p] = (f2){0.f, 0.f};
  #pragma unroll
  for (int g = 0; g < 4; ++g) {
    if (cc > g * 8) {
      int m = cc - g * 8;
      v8bf r[8];
      #pragma unroll
      for (int j = 0; j < 8; ++j)
        if (m > j) r[j] = *(const v8bf*)(xb + (size_t)qs[g][j] * FEAT);
      #pragma unroll
      for (int j = 0; j < 8; ++j)
        if (m > j) {
          const unsigned* ru = (const unsigned*)&r[j];
          #pragma unroll
          for (int p = 0; p < 4; ++p) {
            f2 v;
            v[0] = __uint_as_float(ru[p] << 16);
            v[1] = __uint_as_float(ru[p] & 0xffff0000u);
            acc2[p] += v;
          }
        }
    }
  }
  float scale = 1.0f / (float)(c > 1 ? c : 1);
  v8bf o;
  #pragma unroll
  for (int p = 0; p < 4; ++p) {
    o[2 * p]     = (__bf16)(acc2[p][0] * scale);
    o[2 * p + 1] = (__bf16)(acc2[p][1] * scale);
  }
  *(v8bf*)(out + (size_t)w * FEAT + lane * 8) = o;
}

// ---------- GEMM v3 (r10): 256x256 tile, BK=64, 8 waves, ONE barrier/tile ----
// r9's 8-barrier phase lockstep globally serialized LDS-read and MFMA periods
// (all waves read together, then all MFMA together -> MfmaUtil stuck at 36%).
// Within a tile sA/sB are read-only and all staging targets OTHER slots, so
// the only required sync is one {counted vmcnt; s_barrier} per tile boundary.
// Free-running tile body lets the compiler interleave ds_read<->MFMA and lets
// the 2 waves/SIMD drift (m114 overlap). Cross-tile prefetch unchanged from
// r9: A (HBM) 2 tiles ahead in 3 slots, B (L2-resident Wt) 1 ahead in 2.
// Per-wave FIFO ledger (issue order: B(t+1)x4 then A(t+2)x4 per body):
// end-of-tile vmcnt(4) forces A(t+1) (issued last tile, ~1.5 bodies in
// flight) + B(t+1); leaves A(t+2). Tails: vmcnt(0).
#define A_SLOT_E 16384   // 256x64 bf16 elems = 32 KB
#define B_BASE_E 49152   // after 3 A slots

template <bool ACCUM, bool FINAL>
__global__ __launch_bounds__(512, 2)
void k_gemm3(const __bf16* __restrict__ A, size_t slabStride,
             const __bf16* __restrict__ Wt, int kTiles,
             const float* __restrict__ bias, float* __restrict__ C) {
  __shared__ __align__(16) char smem[163840];       // full 160 KiB LDS
  __bf16* lds = (__bf16*)smem;

  const int tid  = threadIdx.x;
  const int wave = tid >> 6, lane = tid & 63;
  const int lr = lane >> 3, lc = lane & 7;
  const int gcs = (lc ^ lr) * 8;               // pre-swizzled global chunk
  const int quad = lane >> 4, l15 = lane & 15;
  const int wR2 = wave >> 2;                   // row band (64) within quadrant
  const int wC4 = wave & 3;                    // col band (32) within quadrant

  // bijective XCD swizzle (m204)
  const int nwg = gridDim.x;
  const int qq = nwg >> 3, rr = nwg & 7;
  const int xcd = blockIdx.x & 7, oidx = blockIdx.x >> 3;
  const int wg = (xcd < rr ? xcd * (qq + 1) : rr * (qq + 1) + (xcd - rr) * qq) + oidx;
  const int mtile = wg >> 1, ntile = wg & 1;
  const int mBase = mtile * 256, nBase = ntile * 256;

  v4f acc[2][2][4][2];
  #pragma unroll
  for (int a = 0; a < 2; ++a)
    #pragma unroll
    for (int bq = 0; bq < 2; ++bq)
      #pragma unroll
      for (int mi = 0; mi < 4; ++mi)
        #pragma unroll
        for (int ni = 0; ni < 2; ++ni)
          acc[a][bq][mi][ni] = (v4f){0.f, 0.f, 0.f, 0.f};

  // stage one half-tile (128 rows x 64 k) = 2 global_load_lds per wave
  auto stageA = [&](int t, int h) {
    __bf16* dst = lds + (t % 3) * A_SLOT_E;
    const int kk = t * 64;
    const __bf16* base = A + (size_t)(kk >> 9) * slabStride + (kk & 511);
    #pragma unroll
    for (int r2 = 0; r2 < 2; ++r2) {
      int rt = h * 128 + r2 * 64 + wave * 8;   // wave-uniform row base in tile
      int row = mBase + rt + lr;
      if (row > N_NODES - 1) row = N_NODES - 1;
      load_lds16(base + (size_t)row * FEAT + gcs, dst + rt * 64);
    }
  };
  auto stageB = [&](int t, int h) {
    __bf16* dst = lds + B_BASE_E + (t & 1) * A_SLOT_E;
    const int kk = t * 64;
    #pragma unroll
    for (int r2 = 0; r2 < 2; ++r2) {
      int rt = h * 128 + r2 * 64 + wave * 8;
      int n = nBase + rt + lr;
      load_lds16(Wt + (size_t)n * KTOT + kk + gcs, dst + rt * 64);
    }
  };
  auto rdA = [&](const __bf16* sA, int half, int mi, int ks) -> v8bf {
    int m = half * 128 + wR2 * 64 + mi * 16 + l15;
    int q = ks * 4 + quad;
    return *(const v8bf*)(sA + m * 64 + ((q ^ (m & 7)) * 8));
  };
  auto rdB = [&](const __bf16* sB, int half, int ni, int ks) -> v8bf {
    int n = half * 128 + wC4 * 32 + ni * 16 + l15;
    int q = ks * 4 + quad;
    return *(const v8bf*)(sB + n * 64 + ((q ^ (n & 7)) * 8));
  };

  // ---- prologue: A(0), B(0), A(1); vmcnt(4) forces A(0),B(0) ----
  stageA(0, 0); stageA(0, 1);
  stageB(0, 0); stageB(0, 1);
  if (kTiles > 1) {
    stageA(1, 0); stageA(1, 1);
    asm volatile("s_waitcnt vmcnt(4)" ::: "memory");
  } else {
    asm volatile("s_waitcnt vmcnt(0)" ::: "memory");
  }
  __builtin_amdgcn_s_barrier();

  for (int t = 0; t < kTiles; ++t) {
    const __bf16* sA = lds + (t % 3) * A_SLOT_E;
    const __bf16* sB = lds + B_BASE_E + (t & 1) * A_SLOT_E;
    const bool pfB = (t + 1) < kTiles;
    const bool pfA = (t + 2) < kTiles;

    // issue B(t+1) first (FIFO: fast B loads ahead of slow A loads)
    if (pfB) { stageB(t + 1, 0); stageB(t + 1, 1); }

    v8bf a0[4][2], a1[4][2], b0[2][2], b1[2][2];
    #pragma unroll
    for (int mi = 0; mi < 4; ++mi)
      #pragma unroll
      for (int ks = 0; ks < 2; ++ks) a0[mi][ks] = rdA(sA, 0, mi, ks);
    #pragma unroll
    for (int ni = 0; ni < 2; ++ni)
      #pragma unroll
      for (int ks = 0; ks < 2; ++ks) {
        b0[ni][ks] = rdB(sB, 0, ni, ks);
        b1[ni][ks] = rdB(sB, 1, ni, ks);
      }
    #pragma unroll
    for (int ks = 0; ks < 2; ++ks)
      #pragma unroll
      for (int mi = 0; mi < 4; ++mi)
        #pragma unroll
        for (int ni = 0; ni < 2; ++ni) {
          acc[0][0][mi][ni] = __builtin_amdgcn_mfma_f32_16x16x32_bf16(
              a0[mi][ks], b0[ni][ks], acc[0][0][mi][ni], 0, 0, 0);
          acc[0][1][mi][ni] = __builtin_amdgcn_mfma_f32_16x16x32_bf16(
              a0[mi][ks], b1[ni][ks], acc[0][1][mi][ni], 0, 0, 0);
        }

    if (pfA) { stageA(t + 2, 0); stageA(t + 2, 1); }

    #pragma unroll
    for (int mi = 0; mi < 4; ++mi)
      #pragma unroll
      for (int ks = 0; ks < 2; ++ks) a1[mi][ks] = rdA(sA, 1, mi, ks);
    #pragma unroll
    for (int ks = 0; ks < 2; ++ks)
      #pragma unroll
      for (int mi = 0; mi < 4; ++mi)
        #pragma unroll
        for (int ni = 0; ni < 2; ++ni) {
          acc[1][1][mi][ni] = __builtin_amdgcn_mfma_f32_16x16x32_bf16(
              a1[mi][ks], b1[ni][ks], acc[1][1][mi][ni], 0, 0, 0);
          acc[1][0][mi][ni] = __builtin_amdgcn_mfma_f32_16x16x32_bf16(
              a1[mi][ks], b0[ni][ks], acc[1][0][mi][ni], 0, 0, 0);
        }

    // one boundary sync per tile: force A(t+1)+B(t+1); leave A(t+2) in flight
    if (pfA) asm volatile("s_waitcnt vmcnt(4)" ::: "memory");
    else     asm volatile("s_waitcnt vmcnt(0)" ::: "memory");
    __builtin_amdgcn_s_barrier();
  }

  // ---- epilogue: 4 rounds of 64 rows via LDS (stride 260: 2-way = free),
  // full-line float4 stores ----
  float* cbuf = (float*)smem;                       // 64 x 260 fp32 = 66560 B
  const int f4 = tid & 63;
  const int colg = nBase + f4 * 4;
  v4f bias4 = (v4f){0.f, 0.f, 0.f, 0.f};
  if (FINAL) bias4 = *(const v4f*)(bias + colg);
  #pragma unroll
  for (int h = 0; h < 4; ++h) {
    __syncthreads();
    if (wR2 == (h & 1)) {
      const int R = h >> 1;
      #pragma unroll
      for (int Cq = 0; Cq < 2; ++Cq)
        #pragma unroll
        for (int mi = 0; mi < 4; ++mi)
          #pragma unroll
          for (int ni = 0; ni < 2; ++ni)
            #pragma unroll
            for (int e = 0; e < 4; ++e)
              cbuf[(mi * 16 + quad * 4 + e) * 260 + Cq * 128 + wC4 * 32 + ni * 16 + l15] =
                  acc[R][Cq][mi][ni][e];
    }
    __syncthreads();
    #pragma unroll
    for (int i = 0; i < 8; ++i) {
      int rl  = i * 8 + (tid >> 6);
      int row = mBase + h * 64 + rl;
      if (row < N_NODES) {
        v4f v = *(const v4f*)(cbuf + rl * 260 + f4 * 4);
        size_t idx = (size_t)row * FEAT + colg;
        if (ACCUM) v += *(const v4f*)(C + idx);
        if (FINAL) {
          #pragma unroll
          for (int e = 0; e < 4; ++e) v[e] = fmaxf(v[e] + bias4[e], 0.f);
        }
        *(v4f*)(C + idx) = v;
      }
    }
  }
}

// ---------- legacy 128x128 GEMM (fallback path only) ----------
template <bool ACCUM, bool FINAL>
__global__ __launch_bounds__(256, 4)
void k_gemm(const __bf16* __restrict__ A, size_t slabStride,
            const __bf16* __restrict__ Wt, int wtStride, int kTiles,
            const float* __restrict__ bias, float* __restrict__ C,
            int mtBase, int mtEnd) {
  __shared__ __align__(16) char smem[33792];
  __bf16* As = (__bf16*)smem;
  __bf16* Bs = (__bf16*)(smem + 16384);

  const int tid  = threadIdx.x;
  const int wave = tid >> 6;
  const int lane = tid & 63;
  const int lr = lane >> 3, lc = lane & 7;
  const int gcs = (lc ^ lr) * 8;
  const int quad = lane >> 4, l15 = lane & 15;
  const int wRow = wave >> 1, wCol = wave & 1;

  const int panel = blockIdx.x >> 5;
  const int w32   = blockIdx.x & 31;
  const int mtile = mtBase + panel * 8 + (w32 & 7);
  const int ntile = w32 >> 3;
  if (mtile >= mtEnd) return;
  const int mBase = mtile * 128;
  const int nBase = ntile * 128;

  v4f acc[4][4];
  #pragma unroll
  for (int i = 0; i < 4; ++i)
    #pragma unroll
    for (int j = 0; j < 4; ++j) acc[i][j] = (v4f){0.f, 0.f, 0.f, 0.f};

  for (int kt = 0; kt < kTiles; ++kt) {
    const int kk = kt * 64;
    const __bf16* aT = A + (size_t)(kk >> 9) * slabStride + (kk & 511);
    #pragma unroll
    for (int t = 0; t < 4; ++t) {
      int chunk = wave * 4 + t;
      int row = mBase + chunk * 8 + lr;
      if (row > N_NODES - 1) row = N_NODES - 1;
      load_lds16(aT + (size_t)row * FEAT + gcs, As + chunk * 512);
      int n = nBase + chunk * 8 + lr;
      load_lds16(Wt + (size_t)n * wtStride + kk + gcs, Bs + chunk * 512);
    }
    __syncthreads();
    #pragma unroll
    for (int ks = 0; ks < 2; ++ks) {
      const int q = ks * 4 + quad;
      v8bf af[4], bfr[4];
      #pragma unroll
      for (int mi = 0; mi < 4; ++mi) {
        int m = wRow * 64 + mi * 16 + l15;
        af[mi] = *(const v8bf*)(As + m * 64 + ((q ^ (m & 7)) * 8));
      }
      #pragma unroll
      for (int ni = 0; ni < 4; ++ni) {
        int n = wCol * 64 + ni * 16 + l15;
        bfr[ni] = *(const v8bf*)(Bs + n * 64 + ((q ^ (n & 7)) * 8));
      }
      #pragma unroll
      for (int mi = 0; mi < 4; ++mi)
        #pragma unroll
        for (int ni = 0; ni < 4; ++ni)
          acc[mi][ni] = __builtin_amdgcn_mfma_f32_16x16x32_bf16(af[mi], bfr[ni], acc[mi][ni], 0, 0, 0);
    }
    __syncthreads();
  }

  float* cbuf = (float*)smem;
  const int f4c  = tid & 31;
  const int colg = nBase + f4c * 4;
  v4f bias4 = (v4f){0.f, 0.f, 0.f, 0.f};
  if (FINAL) bias4 = *(const v4f*)(bias + colg);
  #pragma unroll
  for (int h = 0; h < 2; ++h) {
    if (wRow == h) {
      #pragma unroll
      for (int mi = 0; mi < 4; ++mi) {
        int r0 = mi * 16 + quad * 4;
        #pragma unroll
        for (int ni = 0; ni < 4; ++ni) {
          int c = wCol * 64 + ni * 16 + l15;
          #pragma unroll
          for (int e = 0; e < 4; ++e)
            cbuf[(r0 + e) * 132 + c] = acc[mi][ni][e];
        }
      }
    }
    __syncthreads();
    #pragma unroll
    for (int i = 0; i < 8; ++i) {
      int rh  = (tid >> 5) + 8 * i;
      int row = mBase + h * 64 + rh;
      if (row < N_NODES) {
        v4f v = *(const v4f*)(cbuf + rh * 132 + f4c * 4);
        size_t idx = (size_t)row * FEAT + colg;
        if (ACCUM) v += *(const v4f*)(C + idx);
        if (FINAL) {
          #pragma unroll
          for (int e = 0; e < 4; ++e) v[e] = fmaxf(v[e] + bias4[e], 0.f);
        }
        *(v4f*)(C + idx) = v;
      }
    }
    __syncthreads();
  }
}

extern "C" void kernel_launch(void* const* d_in, const int* in_sizes, int n_in,
                              void* d_out, int out_size, void* d_ws, size_t ws_size,
                              hipStream_t stream) {
  const float* x    = (const float*)d_in[0];
  const float* w    = (const float*)d_in[1];
  const float* lw   = (const float*)d_in[2];
  const float* bias = (const float*)d_in[3];
  const int*   src  = (const int*)d_in[4];
  const int*   dst  = (const int*)d_in[5];
  float* out = (float*)d_out;

  char* ws = (char*)d_ws;
  const size_t SLAB  = (size_t)N_NODES * FEAT;              // elems per slab
  const size_t slabB = SLAB * 2;                            // 30.72 MB
  const size_t wtB   = (size_t)FEAT * KTOT * 2;             // 4.72 MB
  const size_t cntB  = (size_t)N_REL * N_NODES * 4;         // 0.96 MB
  const size_t slotB = (size_t)N_REL * N_NODES * CAP * 2;   // 15.36 MB (u16)
  const size_t fixedB = wtB + cntB + slotB;                 // 21.04 MB

  __bf16*         Wt     = (__bf16*)ws;
  int*            cnt    = (int*)(ws + wtB);
  unsigned short* slots  = (unsigned short*)(ws + wtB + cntB);
  __bf16*         slabs  = (__bf16*)(ws + fixedB);          // 16B-aligned

  int nSlab = (int)((ws_size - fixedB) / slabB);            // total slots incl. x slot
  int g = nSlab - 1;                                        // agg slabs avail
  if (g > 7) g = 7;
  if (g < 1) g = 1;
  __bf16* xbf = slabs + (size_t)g * SLAB;                   // slot g = x (bf16)

  hipMemsetAsync(cnt, 0, cntB, stream);
  k_prep<<<CONV_BLOCKS + TR_BLOCKS + CNT_BLOCKS, 256, 0, stream>>>(
      x, w, lw, src, dst, xbf, Wt, cnt, slots);

  if (g == 7) {
    const int mt256 = (N_NODES + 255) / 256;                // 118
    const int grid3 = mt256 * 2;                            // 236 blocks
    // pass1: rels 0..6 -> slots 0..6 via slice-major aggregate; K=3584 gemm.
    const int bps1 = (7 * N_NODES + 31) / 32;               // 6563
    k_agg_slice<<<8 * bps1, 256, 0, stream>>>(xbf, cnt, slots,
                                              slabs, 7 * N_NODES, bps1);
    k_gemm3<false, false><<<grid3, 512, 0, stream>>>(
        slabs, SLAB, Wt, 3584 / 64, bias, out);
    // pass2: rel 7 -> slot 6 (dead after gemm1); slots 6,7 = [rel7, x]
    // contiguous in memory and in Wt columns -> one K=1024 ACCUM+FINAL gemm.
    const int bps2 = (N_NODES + 31) / 32;                   // 938
    k_agg_slice<<<8 * bps2, 256, 0, stream>>>(
        xbf, cnt + 7 * N_NODES, slots + (size_t)7 * N_NODES * CAP,
        slabs + (size_t)6 * SLAB, N_NODES, bps2);
    k_gemm3<true, true><<<grid3, 512, 0, stream>>>(
        slabs + (size_t)6 * SLAB, SLAB, Wt + 3584, 1024 / 64, bias, out);
  } else {
    // defensive generic path (smaller workspace)
    const int nMtiles = (N_NODES + 127) / 128;
    const int gemmGrid = ((nMtiles + 7) / 8) * 32;
    for (int r0 = 0; r0 < N_REL; r0 += g) {
      int gc2 = (N_REL - r0) < g ? (N_REL - r0) : g;
      k_aggregate<<<(gc2 * N_NODES) / 4, 256, 0, stream>>>(
          xbf, cnt + r0 * N_NODES, slots + (size_t)r0 * N_NODES * CAP,
          slabs, gc2 * N_NODES);
      if (r0 == 0)
        k_gemm<false, false><<<gemmGrid, 256, 0, stream>>>(
            slabs, SLAB, Wt + r0 * 512, KTOT, gc2 * 8, bias, out, 0, nMtiles);
      else
        k_gemm<true, false><<<gemmGrid, 256, 0, stream>>>(
            slabs, SLAB, Wt + r0 * 512, KTOT, gc2 * 8, bias, out, 0, nMtiles);
    }
    k_gemm<true, true><<<gemmGrid, 256, 0, stream>>>(xbf, SLAB, Wt + 4096, KTOT,
                                                     8, bias, out, 0, nMtiles);
  }
}

// Round 11
// 468.038 us; speedup vs baseline: 1.1960x; 1.0236x over previous
//
#include <hip/hip_runtime.h>
#include <hip/hip_bf16.h>

#define N_NODES 30000
#define N_REL   8
#define N_EDGES 131072
#define FEAT    512
#define KTOT    4608   // 8*512 + 512
#define CAP     32

typedef __attribute__((ext_vector_type(8))) __bf16 v8bf;
typedef __attribute__((ext_vector_type(4))) __bf16 v4bf;
typedef __attribute__((ext_vector_type(4))) float  v4f;
typedef __attribute__((ext_vector_type(2))) float  f2;
typedef __attribute__((ext_vector_type(8))) unsigned short u16x8;

// ---------- async global->LDS (16B per lane, wave-uniform LDS base) ----------
static __device__ __forceinline__ void load_lds16(const void* g, void* l) {
  __builtin_amdgcn_global_load_lds(
      (const __attribute__((address_space(1))) void*)g,
      (__attribute__((address_space(3))) void*)l, 16, 0, 0);
}

// ---------- fused prep: convert x, transpose W, build buckets ----------
#define CONV_BLOCKS 15000
#define TR_BLOCKS   2304
#define CNT_BLOCKS  512
__global__ __launch_bounds__(256)
void k_prep(const float* __restrict__ x, const float* __restrict__ w,
            const float* __restrict__ lw, const int* __restrict__ src,
            const int* __restrict__ dst, __bf16* __restrict__ xbf,
            __bf16* __restrict__ Wt, int* __restrict__ cnt,
            unsigned short* __restrict__ slots) {
  __shared__ float t[32][33];
  const int b = blockIdx.x, tid = threadIdx.x;
  if (b < CONV_BLOCKS) {
    int i = b * 256 + tid;                          // 4 elems each
    float4 v = ((const float4*)x)[i];
    v4bf o;
    o[0] = (__bf16)v.x; o[1] = (__bf16)v.y; o[2] = (__bf16)v.z; o[3] = (__bf16)v.w;
    ((v4bf*)xbf)[i] = o;
  } else if (b < CONV_BLOCKS + TR_BLOCKS) {
    int tb = b - CONV_BLOCKS;
    int k0 = (tb % 144) * 32, n0 = (tb / 144) * 32;
    int tx = tid & 31, ty = tid >> 5;               // 32 x 8
    #pragma unroll
    for (int q = 0; q < 4; ++q) {
      int k = k0 + ty + q * 8, n = n0 + tx;
      float v = (k < 4096) ? w[(size_t)k * 512 + n] : lw[(size_t)(k - 4096) * 512 + n];
      t[ty + q * 8][tx] = v;
    }
    __syncthreads();
    #pragma unroll
    for (int q = 0; q < 4; ++q) {
      int n = n0 + ty + q * 8, k = k0 + tx;
      Wt[(size_t)n * KTOT + k] = (__bf16)t[tx][ty + q * 8];
    }
  } else {
    int cb  = b - CONV_BLOCKS - TR_BLOCKS;          // 0..511
    int rel = cb & 7;                               // XCD-affine rel
    int q   = cb >> 3;                              // 0..63 within rel
    int e0  = rel * N_EDGES + (q * 256 + tid) * 8;  // 8 edges, same rel
    int4 sa = *(const int4*)(src + e0), sb = *(const int4*)(src + e0 + 4);
    int4 da = *(const int4*)(dst + e0), db = *(const int4*)(dst + e0 + 4);
    int ss[8] = {sa.x, sa.y, sa.z, sa.w, sb.x, sb.y, sb.z, sb.w};
    int dd[8] = {da.x, da.y, da.z, da.w, db.x, db.y, db.z, db.w};
    int bb[8], pp[8];
    #pragma unroll
    for (int j = 0; j < 8; ++j) {
      bb[j] = rel * N_NODES + dd[j];
      pp[j] = atomicAdd(&cnt[bb[j]], 1);
    }
    #pragma unroll
    for (int j = 0; j < 8; ++j)
      if (pp[j] < CAP) slots[(size_t)bb[j] * CAP + pp[j]] = (unsigned short)ss[j];
  }
}

// ---------- slice aggregation: 8 feature-slices of 64 cols, XCD-affine ----------
// r11: slice = blockIdx.x & 7. Under round-robin block->XCD dispatch, XCD k
// processes ONLY slice k, so its 3.84 MB x-slice stays resident in that XCD's
// private 4 MB L2 for the whole kernel (r10 counters: slice-major spread each
// slice across all 8 XCDs -> 8x duplicate HBM fills, FETCH 240 MB ~= 3.84MB
// x 8 slices x 8 XCDs). Slot lines sweep in the same bucket order on all
// XCDs -> L3 temporal sharing (already absorbed, r10). Everything else
// byte-identical to r10's k_agg_slice.
__global__ __launch_bounds__(256)
void k_agg_slice(const __bf16* __restrict__ xbf, const int* __restrict__ cnt,
                 const unsigned short* __restrict__ slots,
                 __bf16* __restrict__ out, int nBuckets, int bps) {
  const int bid   = blockIdx.x;
  const int slice = bid & 7;                        // XCD-affine slice
  const int ib    = bid >> 3;
  const int tid   = threadIdx.x;
  const int wave  = tid >> 6, lane = tid & 63;
  const int grp   = lane >> 3;                      // bucket group within wave
  const int li    = lane & 7;                       // lane within group
  const int w     = ib * 32 + wave * 8 + grp;
  const bool valid = (w < nBuckets);

  int c = 0;
  u16x8 qs[4];
  if (valid) {
    c = cnt[w];
    const unsigned short* sl = slots + (size_t)w * CAP;
    qs[0] = *(const u16x8*)(sl);                    // 64B line broadcast/group
    qs[1] = *(const u16x8*)(sl + 8);
    qs[2] = *(const u16x8*)(sl + 16);
    qs[3] = *(const u16x8*)(sl + 24);
  }
  int cc = c < CAP ? c : CAP;
  int cmax = cc;                                    // wave-max across groups
  cmax = max(cmax, __shfl_xor(cmax, 8));
  cmax = max(cmax, __shfl_xor(cmax, 16));
  cmax = max(cmax, __shfl_xor(cmax, 32));

  const __bf16* xb = xbf + slice * 64 + (size_t)li * 8;
  f2 acc2[4];
  #pragma unroll
  for (int p = 0; p < 4; ++p) acc2[p] = (f2){0.f, 0.f};
  #pragma unroll
  for (int g = 0; g < 4; ++g) {
    if (cmax > g * 8) {                             // wave-uniform
      v8bf r[8];
      #pragma unroll
      for (int j = 0; j < 8; ++j)
        if (cc > g * 8 + j)                         // group-predicated load
          r[j] = *(const v8bf*)(xb + (size_t)qs[g][j] * FEAT);
      #pragma unroll
      for (int j = 0; j < 8; ++j)
        if (cc > g * 8 + j) {
          const unsigned* ru = (const unsigned*)&r[j];
          #pragma unroll
          for (int p = 0; p < 4; ++p) {
            f2 v;
            v[0] = __uint_as_float(ru[p] << 16);           // lo bf16 -> f32
            v[1] = __uint_as_float(ru[p] & 0xffff0000u);   // hi bf16 -> f32
            acc2[p] += v;                                   // v_pk_add_f32
          }
        }
    }
  }
  if (valid) {
    float scale = 1.0f / (float)(c > 1 ? c : 1);
    v8bf o;
    #pragma unroll
    for (int p = 0; p < 4; ++p) {
      o[2 * p]     = (__bf16)(acc2[p][0] * scale);
      o[2 * p + 1] = (__bf16)(acc2[p][1] * scale);
    }
    *(v8bf*)(out + (size_t)w * FEAT + slice * 64 + (size_t)li * 8) = o;
  }
}

// ---------- legacy aggregation (fallback path only) ----------
__global__ __launch_bounds__(256)
void k_aggregate(const __bf16* __restrict__ xbf, const int* __restrict__ cnt,
                 const unsigned short* __restrict__ slots,
                 __bf16* __restrict__ out, int nBuckets) {
  int w = (blockIdx.x * blockDim.x + threadIdx.x) >> 6;
  int lane = threadIdx.x & 63;
  if (w >= nBuckets) return;
  const unsigned short* sl = slots + (size_t)w * CAP;
  u16x8 qs[4];
  qs[0] = *(const u16x8*)(sl);
  qs[1] = *(const u16x8*)(sl + 8);
  qs[2] = *(const u16x8*)(sl + 16);
  qs[3] = *(const u16x8*)(sl + 24);
  int c = cnt[w];
  int cc = c < CAP ? c : CAP;
  const __bf16* xb = xbf + (size_t)lane * 8;
  f2 acc2[4];
  #pragma unroll
  for (int p = 0; p < 4; ++p) acc2[p] = (f2){0.f, 0.f};
  #pragma unroll
  for (int g = 0; g < 4; ++g) {
    if (cc > g * 8) {
      int m = cc - g * 8;
      v8bf r[8];
      #pragma unroll
      for (int j = 0; j < 8; ++j)
        if (m > j) r[j] = *(const v8bf*)(xb + (size_t)qs[g][j] * FEAT);
      #pragma unroll
      for (int j = 0; j < 8; ++j)
        if (m > j) {
          const unsigned* ru = (const unsigned*)&r[j];
          #pragma unroll
          for (int p = 0; p < 4; ++p) {
            f2 v;
            v[0] = __uint_as_float(ru[p] << 16);
            v[1] = __uint_as_float(ru[p] & 0xffff0000u);
            acc2[p] += v;
          }
        }
    }
  }
  float scale = 1.0f / (float)(c > 1 ? c : 1);
  v8bf o;
  #pragma unroll
  for (int p = 0; p < 4; ++p) {
    o[2 * p]     = (__bf16)(acc2[p][0] * scale);
    o[2 * p + 1] = (__bf16)(acc2[p][1] * scale);
  }
  *(v8bf*)(out + (size_t)w * FEAT + lane * 8) = o;
}

// ---------- GEMM v3 (r10-proven): 256x256, BK=64, one barrier/tile ----------
#define A_SLOT_E 16384   // 256x64 bf16 elems = 32 KB
#define B_BASE_E 49152   // after 3 A slots

template <bool ACCUM, bool FINAL>
__global__ __launch_bounds__(512, 2)
void k_gemm3(const __bf16* __restrict__ A, size_t slabStride,
             const __bf16* __restrict__ Wt, int kTiles,
             const float* __restrict__ bias, float* __restrict__ C) {
  __shared__ __align__(16) char smem[163840];       // full 160 KiB LDS
  __bf16* lds = (__bf16*)smem;

  const int tid  = threadIdx.x;
  const int wave = tid >> 6, lane = tid & 63;
  const int lr = lane >> 3, lc = lane & 7;
  const int gcs = (lc ^ lr) * 8;               // pre-swizzled global chunk
  const int quad = lane >> 4, l15 = lane & 15;
  const int wR2 = wave >> 2;                   // row band (64) within quadrant
  const int wC4 = wave & 3;                    // col band (32) within quadrant

  // bijective XCD swizzle (m204)
  const int nwg = gridDim.x;
  const int qq = nwg >> 3, rr = nwg & 7;
  const int xcd = blockIdx.x & 7, oidx = blockIdx.x >> 3;
  const int wg = (xcd < rr ? xcd * (qq + 1) : rr * (qq + 1) + (xcd - rr) * qq) + oidx;
  const int mtile = wg >> 1, ntile = wg & 1;
  const int mBase = mtile * 256, nBase = ntile * 256;

  v4f acc[2][2][4][2];
  #pragma unroll
  for (int a = 0; a < 2; ++a)
    #pragma unroll
    for (int bq = 0; bq < 2; ++bq)
      #pragma unroll
      for (int mi = 0; mi < 4; ++mi)
        #pragma unroll
        for (int ni = 0; ni < 2; ++ni)
          acc[a][bq][mi][ni] = (v4f){0.f, 0.f, 0.f, 0.f};

  // stage one half-tile (128 rows x 64 k) = 2 global_load_lds per wave
  auto stageA = [&](int t, int h) {
    __bf16* dst = lds + (t % 3) * A_SLOT_E;
    const int kk = t * 64;
    const __bf16* base = A + (size_t)(kk >> 9) * slabStride + (kk & 511);
    #pragma unroll
    for (int r2 = 0; r2 < 2; ++r2) {
      int rt = h * 128 + r2 * 64 + wave * 8;   // wave-uniform row base in tile
      int row = mBase + rt + lr;
      if (row > N_NODES - 1) row = N_NODES - 1;
      load_lds16(base + (size_t)row * FEAT + gcs, dst + rt * 64);
    }
  };
  auto stageB = [&](int t, int h) {
    __bf16* dst = lds + B_BASE_E + (t & 1) * A_SLOT_E;
    const int kk = t * 64;
    #pragma unroll
    for (int r2 = 0; r2 < 2; ++r2) {
      int rt = h * 128 + r2 * 64 + wave * 8;
      int n = nBase + rt + lr;
      load_lds16(Wt + (size_t)n * KTOT + kk + gcs, dst + rt * 64);
    }
  };
  auto rdA = [&](const __bf16* sA, int half, int mi, int ks) -> v8bf {
    int m = half * 128 + wR2 * 64 + mi * 16 + l15;
    int q = ks * 4 + quad;
    return *(const v8bf*)(sA + m * 64 + ((q ^ (m & 7)) * 8));
  };
  auto rdB = [&](const __bf16* sB, int half, int ni, int ks) -> v8bf {
    int n = half * 128 + wC4 * 32 + ni * 16 + l15;
    int q = ks * 4 + quad;
    return *(const v8bf*)(sB + n * 64 + ((q ^ (n & 7)) * 8));
  };

  // ---- prologue: A(0), B(0), A(1); vmcnt(4) forces A(0),B(0) ----
  stageA(0, 0); stageA(0, 1);
  stageB(0, 0); stageB(0, 1);
  if (kTiles > 1) {
    stageA(1, 0); stageA(1, 1);
    asm volatile("s_waitcnt vmcnt(4)" ::: "memory");
  } else {
    asm volatile("s_waitcnt vmcnt(0)" ::: "memory");
  }
  __builtin_amdgcn_s_barrier();

  for (int t = 0; t < kTiles; ++t) {
    const __bf16* sA = lds + (t % 3) * A_SLOT_E;
    const __bf16* sB = lds + B_BASE_E + (t & 1) * A_SLOT_E;
    const bool pfB = (t + 1) < kTiles;
    const bool pfA = (t + 2) < kTiles;

    // issue B(t+1) first (FIFO: fast B loads ahead of slow A loads)
    if (pfB) { stageB(t + 1, 0); stageB(t + 1, 1); }

    v8bf a0[4][2], a1[4][2], b0[2][2], b1[2][2];
    #pragma unroll
    for (int mi = 0; mi < 4; ++mi)
      #pragma unroll
      for (int ks = 0; ks < 2; ++ks) a0[mi][ks] = rdA(sA, 0, mi, ks);
    #pragma unroll
    for (int ni = 0; ni < 2; ++ni)
      #pragma unroll
      for (int ks = 0; ks < 2; ++ks) {
        b0[ni][ks] = rdB(sB, 0, ni, ks);
        b1[ni][ks] = rdB(sB, 1, ni, ks);
      }
    #pragma unroll
    for (int ks = 0; ks < 2; ++ks)
      #pragma unroll
      for (int mi = 0; mi < 4; ++mi)
        #pragma unroll
        for (int ni = 0; ni < 2; ++ni) {
          acc[0][0][mi][ni] = __builtin_amdgcn_mfma_f32_16x16x32_bf16(
              a0[mi][ks], b0[ni][ks], acc[0][0][mi][ni], 0, 0, 0);
          acc[0][1][mi][ni] = __builtin_amdgcn_mfma_f32_16x16x32_bf16(
              a0[mi][ks], b1[ni][ks], acc[0][1][mi][ni], 0, 0, 0);
        }

    if (pfA) { stageA(t + 2, 0); stageA(t + 2, 1); }

    #pragma unroll
    for (int mi = 0; mi < 4; ++mi)
      #pragma unroll
      for (int ks = 0; ks < 2; ++ks) a1[mi][ks] = rdA(sA, 1, mi, ks);
    #pragma unroll
    for (int ks = 0; ks < 2; ++ks)
      #pragma unroll
      for (int mi = 0; mi < 4; ++mi)
        #pragma unroll
        for (int ni = 0; ni < 2; ++ni) {
          acc[1][1][mi][ni] = __builtin_amdgcn_mfma_f32_16x16x32_bf16(
              a1[mi][ks], b1[ni][ks], acc[1][1][mi][ni], 0, 0, 0);
          acc[1][0][mi][ni] = __builtin_amdgcn_mfma_f32_16x16x32_bf16(
              a1[mi][ks], b0[ni][ks], acc[1][0][mi][ni], 0, 0, 0);
        }

    // one boundary sync per tile: force A(t+1)+B(t+1); leave A(t+2) in flight
    if (pfA) asm volatile("s_waitcnt vmcnt(4)" ::: "memory");
    else     asm volatile("s_waitcnt vmcnt(0)" ::: "memory");
    __builtin_amdgcn_s_barrier();
  }

  // ---- epilogue: 4 rounds of 64 rows via LDS (stride 260: 2-way = free),
  // full-line float4 stores ----
  float* cbuf = (float*)smem;                       // 64 x 260 fp32 = 66560 B
  const int f4 = tid & 63;
  const int colg = nBase + f4 * 4;
  v4f bias4 = (v4f){0.f, 0.f, 0.f, 0.f};
  if (FINAL) bias4 = *(const v4f*)(bias + colg);
  #pragma unroll
  for (int h = 0; h < 4; ++h) {
    __syncthreads();
    if (wR2 == (h & 1)) {
      const int R = h >> 1;
      #pragma unroll
      for (int Cq = 0; Cq < 2; ++Cq)
        #pragma unroll
        for (int mi = 0; mi < 4; ++mi)
          #pragma unroll
          for (int ni = 0; ni < 2; ++ni)
            #pragma unroll
            for (int e = 0; e < 4; ++e)
              cbuf[(mi * 16 + quad * 4 + e) * 260 + Cq * 128 + wC4 * 32 + ni * 16 + l15] =
                  acc[R][Cq][mi][ni][e];
    }
    __syncthreads();
    #pragma unroll
    for (int i = 0; i < 8; ++i) {
      int rl  = i * 8 + (tid >> 6);
      int row = mBase + h * 64 + rl;
      if (row < N_NODES) {
        v4f v = *(const v4f*)(cbuf + rl * 260 + f4 * 4);
        size_t idx = (size_t)row * FEAT + colg;
        if (ACCUM) v += *(const v4f*)(C + idx);
        if (FINAL) {
          #pragma unroll
          for (int e = 0; e < 4; ++e) v[e] = fmaxf(v[e] + bias4[e], 0.f);
        }
        *(v4f*)(C + idx) = v;
      }
    }
  }
}

// ---------- legacy 128x128 GEMM (fallback path only) ----------
template <bool ACCUM, bool FINAL>
__global__ __launch_bounds__(256, 4)
void k_gemm(const __bf16* __restrict__ A, size_t slabStride,
            const __bf16* __restrict__ Wt, int wtStride, int kTiles,
            const float* __restrict__ bias, float* __restrict__ C,
            int mtBase, int mtEnd) {
  __shared__ __align__(16) char smem[33792];
  __bf16* As = (__bf16*)smem;
  __bf16* Bs = (__bf16*)(smem + 16384);

  const int tid  = threadIdx.x;
  const int wave = tid >> 6;
  const int lane = tid & 63;
  const int lr = lane >> 3, lc = lane & 7;
  const int gcs = (lc ^ lr) * 8;
  const int quad = lane >> 4, l15 = lane & 15;
  const int wRow = wave >> 1, wCol = wave & 1;

  const int panel = blockIdx.x >> 5;
  const int w32   = blockIdx.x & 31;
  const int mtile = mtBase + panel * 8 + (w32 & 7);
  const int ntile = w32 >> 3;
  if (mtile >= mtEnd) return;
  const int mBase = mtile * 128;
  const int nBase = ntile * 128;

  v4f acc[4][4];
  #pragma unroll
  for (int i = 0; i < 4; ++i)
    #pragma unroll
    for (int j = 0; j < 4; ++j) acc[i][j] = (v4f){0.f, 0.f, 0.f, 0.f};

  for (int kt = 0; kt < kTiles; ++kt) {
    const int kk = kt * 64;
    const __bf16* aT = A + (size_t)(kk >> 9) * slabStride + (kk & 511);
    #pragma unroll
    for (int t = 0; t < 4; ++t) {
      int chunk = wave * 4 + t;
      int row = mBase + chunk * 8 + lr;
      if (row > N_NODES - 1) row = N_NODES - 1;
      load_lds16(aT + (size_t)row * FEAT + gcs, As + chunk * 512);
      int n = nBase + chunk * 8 + lr;
      load_lds16(Wt + (size_t)n * wtStride + kk + gcs, Bs + chunk * 512);
    }
    __syncthreads();
    #pragma unroll
    for (int ks = 0; ks < 2; ++ks) {
      const int q = ks * 4 + quad;
      v8bf af[4], bfr[4];
      #pragma unroll
      for (int mi = 0; mi < 4; ++mi) {
        int m = wRow * 64 + mi * 16 + l15;
        af[mi] = *(const v8bf*)(As + m * 64 + ((q ^ (m & 7)) * 8));
      }
      #pragma unroll
      for (int ni = 0; ni < 4; ++ni) {
        int n = wCol * 64 + ni * 16 + l15;
        bfr[ni] = *(const v8bf*)(Bs + n * 64 + ((q ^ (n & 7)) * 8));
      }
      #pragma unroll
      for (int mi = 0; mi < 4; ++mi)
        #pragma unroll
        for (int ni = 0; ni < 4; ++ni)
          acc[mi][ni] = __builtin_amdgcn_mfma_f32_16x16x32_bf16(af[mi], bfr[ni], acc[mi][ni], 0, 0, 0);
    }
    __syncthreads();
  }

  float* cbuf = (float*)smem;
  const int f4c  = tid & 31;
  const int colg = nBase + f4c * 4;
  v4f bias4 = (v4f){0.f, 0.f, 0.f, 0.f};
  if (FINAL) bias4 = *(const v4f*)(bias + colg);
  #pragma unroll
  for (int h = 0; h < 2; ++h) {
    if (wRow == h) {
      #pragma unroll
      for (int mi = 0; mi < 4; ++mi) {
        int r0 = mi * 16 + quad * 4;
        #pragma unroll
        for (int ni = 0; ni < 4; ++ni) {
          int c = wCol * 64 + ni * 16 + l15;
          #pragma unroll
          for (int e = 0; e < 4; ++e)
            cbuf[(r0 + e) * 132 + c] = acc[mi][ni][e];
        }
      }
    }
    __syncthreads();
    #pragma unroll
    for (int i = 0; i < 8; ++i) {
      int rh  = (tid >> 5) + 8 * i;
      int row = mBase + h * 64 + rh;
      if (row < N_NODES) {
        v4f v = *(const v4f*)(cbuf + rh * 132 + f4c * 4);
        size_t idx = (size_t)row * FEAT + colg;
        if (ACCUM) v += *(const v4f*)(C + idx);
        if (FINAL) {
          #pragma unroll
          for (int e = 0; e < 4; ++e) v[e] = fmaxf(v[e] + bias4[e], 0.f);
        }
        *(v4f*)(C + idx) = v;
      }
    }
    __syncthreads();
  }
}

extern "C" void kernel_launch(void* const* d_in, const int* in_sizes, int n_in,
                              void* d_out, int out_size, void* d_ws, size_t ws_size,
                              hipStream_t stream) {
  const float* x    = (const float*)d_in[0];
  const float* w    = (const float*)d_in[1];
  const float* lw   = (const float*)d_in[2];
  const float* bias = (const float*)d_in[3];
  const int*   src  = (const int*)d_in[4];
  const int*   dst  = (const int*)d_in[5];
  float* out = (float*)d_out;

  char* ws = (char*)d_ws;
  const size_t SLAB  = (size_t)N_NODES * FEAT;              // elems per slab
  const size_t slabB = SLAB * 2;                            // 30.72 MB
  const size_t wtB   = (size_t)FEAT * KTOT * 2;             // 4.72 MB
  const size_t cntB  = (size_t)N_REL * N_NODES * 4;         // 0.96 MB
  const size_t slotB = (size_t)N_REL * N_NODES * CAP * 2;   // 15.36 MB (u16)
  const size_t fixedB = wtB + cntB + slotB;                 // 21.04 MB

  __bf16*         Wt     = (__bf16*)ws;
  int*            cnt    = (int*)(ws + wtB);
  unsigned short* slots  = (unsigned short*)(ws + wtB + cntB);
  __bf16*         slabs  = (__bf16*)(ws + fixedB);          // 16B-aligned

  int nSlab = (int)((ws_size - fixedB) / slabB);            // total slots incl. x slot
  int g = nSlab - 1;                                        // agg slabs avail
  if (g > 7) g = 7;
  if (g < 1) g = 1;
  __bf16* xbf = slabs + (size_t)g * SLAB;                   // slot g = x (bf16)

  hipMemsetAsync(cnt, 0, cntB, stream);
  k_prep<<<CONV_BLOCKS + TR_BLOCKS + CNT_BLOCKS, 256, 0, stream>>>(
      x, w, lw, src, dst, xbf, Wt, cnt, slots);

  if (g == 7) {
    const int mt256 = (N_NODES + 255) / 256;                // 118
    const int grid3 = mt256 * 2;                            // 236 blocks
    // pass1: rels 0..6 -> slots 0..6 via XCD-affine slice aggregate; K=3584.
    const int bps1 = (7 * N_NODES + 31) / 32;               // 6563
    k_agg_slice<<<8 * bps1, 256, 0, stream>>>(xbf, cnt, slots,
                                              slabs, 7 * N_NODES, bps1);
    k_gemm3<false, false><<<grid3, 512, 0, stream>>>(
        slabs, SLAB, Wt, 3584 / 64, bias, out);
    // pass2: rel 7 -> slot 6 (dead after gemm1); slots 6,7 = [rel7, x]
    // contiguous in memory and in Wt columns -> one K=1024 ACCUM+FINAL gemm.
    const int bps2 = (N_NODES + 31) / 32;                   // 938
    k_agg_slice<<<8 * bps2, 256, 0, stream>>>(
        xbf, cnt + 7 * N_NODES, slots + (size_t)7 * N_NODES * CAP,
        slabs + (size_t)6 * SLAB, N_NODES, bps2);
    k_gemm3<true, true><<<grid3, 512, 0, stream>>>(
        slabs + (size_t)6 * SLAB, SLAB, Wt + 3584, 1024 / 64, bias, out);
  } else {
    // defensive generic path (smaller workspace)
    const int nMtiles = (N_NODES + 127) / 128;
    const int gemmGrid = ((nMtiles + 7) / 8) * 32;
    for (int r0 = 0; r0 < N_REL; r0 += g) {
      int gc2 = (N_REL - r0) < g ? (N_REL - r0) : g;
      k_aggregate<<<(gc2 * N_NODES) / 4, 256, 0, stream>>>(
          xbf, cnt + r0 * N_NODES, slots + (size_t)r0 * N_NODES * CAP,
          slabs, gc2 * N_NODES);
      if (r0 == 0)
        k_gemm<false, false><<<gemmGrid, 256, 0, stream>>>(
            slabs, SLAB, Wt + r0 * 512, KTOT, gc2 * 8, bias, out, 0, nMtiles);
      else
        k_gemm<true, false><<<gemmGrid, 256, 0, stream>>>(
            slabs, SLAB, Wt + r0 * 512, KTOT, gc2 * 8, bias, out, 0, nMtiles);
    }
    k_gemm<true, true><<<gemmGrid, 256, 0, stream>>>(xbf, SLAB, Wt + 4096, KTOT,
                                                     8, bias, out, 0, nMtiles);
  }
}